// Round 10
// baseline (389.233 us; speedup 1.0000x reference)
//
#include <hip/hip_runtime.h>
#include <cstdint>
#include <cstddef>
#include <math.h>

typedef __attribute__((ext_vector_type(8))) short short8;
typedef __attribute__((ext_vector_type(4))) float f32x4;
typedef __attribute__((ext_vector_type(16))) float f32x16;
typedef __attribute__((ext_vector_type(2))) unsigned uint2v;

#define D_MODEL 1024
#define NHEADS 16
#define DHEAD 64
#define BATCH 4
#define SEQ 2048
#define MTOK (BATCH * SEQ)

__device__ __forceinline__ unsigned short f2bf(float f) {
  union { float f; unsigned u; } v; v.f = f;
  unsigned r = v.u + 0x7fffu + ((v.u >> 16) & 1u);
  return (unsigned short)(r >> 16);
}
__device__ __forceinline__ float bf2f(unsigned short u) {
  union { unsigned u; float f; } v; v.u = ((unsigned)u) << 16;
  return v.f;
}
__device__ __forceinline__ unsigned cvt_pk_bf16(float a, float b) {
  unsigned u;
  asm("v_cvt_pk_bf16_f32 %0, %1, %2" : "=v"(u) : "v"(a), "v"(b));
  return u;
}
// raw v_exp_f32 (2^x). Safe for x in [-126, 127]; our args are in [-62, 0].
__device__ __forceinline__ float exp2_fast(float x) {
  float r;
  asm("v_exp_f32 %0, %1" : "=v"(r) : "v"(x));
  return r;
}

typedef const __attribute__((address_space(1))) unsigned int* gas1_t;
typedef __attribute__((address_space(3))) unsigned int* las3_t;
// async global->LDS, 16B per lane; LDS dest must be wave-uniform base (HW adds lane*16B)
__device__ __forceinline__ void gload16(const unsigned short* g, unsigned short* l) {
  __builtin_amdgcn_global_load_lds((gas1_t)g, (las3_t)l, 16, 0, 0);
}

#define MFMA32(a, b, c) __builtin_amdgcn_mfma_f32_32x32x16_bf16(a, b, c, 0, 0, 0)

// ---------------- fp32 -> bf16 conversion, all 4 weights in one launch ----------------
__global__ __launch_bounds__(256) void f32_to_bf16_all(const float* __restrict__ s0,
                                                       const float* __restrict__ s1,
                                                       const float* __restrict__ s2,
                                                       const float* __restrict__ s3,
                                                       unsigned short* __restrict__ d0,
                                                       unsigned short* __restrict__ d1,
                                                       unsigned short* __restrict__ d2,
                                                       unsigned short* __restrict__ d3) {
  int j = blockIdx.x * 256 + threadIdx.x;  // float4 index over concatenated ranges
  const float* s;
  unsigned short* d;
  if (j < 786432) { s = s0; d = d0; }
  else if ((j -= 786432) < 262144) { s = s1; d = d1; }
  else if ((j -= 262144) < 524288) { s = s2; d = d2; }
  else { j -= 524288; s = s3; d = d3; }
  float4 v = ((const float4*)s)[j];
  ushort4 o;
  o.x = f2bf(v.x); o.y = f2bf(v.y); o.z = f2bf(v.z); o.w = f2bf(v.w);
  ((ushort4*)d)[j] = o;
}

// ---------------- LayerNorm: fp32 in -> bf16 out ----------------
__global__ __launch_bounds__(256) void ln_fwd(const float* __restrict__ x, const float* __restrict__ g,
                                              const float* __restrict__ b,
                                              unsigned short* __restrict__ out) {
  const int row = blockIdx.x, t = threadIdx.x;
  float4 v = *(const float4*)(x + (size_t)row * D_MODEL + t * 4);
  float s = v.x + v.y + v.z + v.w;
  float s2 = v.x * v.x + v.y * v.y + v.z * v.z + v.w * v.w;
#pragma unroll
  for (int m = 1; m < 64; m <<= 1) { s += __shfl_xor(s, m); s2 += __shfl_xor(s2, m); }
  __shared__ float red[8];
  int wv = t >> 6;
  if ((t & 63) == 0) { red[wv] = s; red[4 + wv] = s2; }
  __syncthreads();
  s = red[0] + red[1] + red[2] + red[3];
  s2 = red[4] + red[5] + red[6] + red[7];
  float mu = s * (1.f / D_MODEL);
  float var = s2 * (1.f / D_MODEL) - mu * mu;
  float rs = rsqrtf(var + 1e-5f);
  float4 gg = *(const float4*)(g + t * 4);
  float4 bb = *(const float4*)(b + t * 4);
  ushort4 o;
  o.x = f2bf((v.x - mu) * rs * gg.x + bb.x);
  o.y = f2bf((v.y - mu) * rs * gg.y + bb.y);
  o.z = f2bf((v.z - mu) * rs * gg.z + bb.z);
  o.w = f2bf((v.w - mu) * rs * gg.w + bb.w);
  *(ushort4*)(out + (size_t)row * D_MODEL + t * 4) = o;
}

// ---------------- GEMM v3: 8-phase 256x128 tile, 32x32 MFMA, counted vmcnt ----------------
// C[M,N] = A[M,K]*B[N,K]^T. 512 threads = 8 waves (4Mx2N), wave tile 64x64 = 2x2 f32x16 accs.
// BK=64; triple-buffered LDS (144KB), prefetch depth 2, vmcnt(6) at K-tile boundaries only.
// T2 swizzle: LDS[row][u16B] = G[row][u ^ (row&7)] via inverse-swizzled global source with
// linear gload_lds dest; reads XOR the same involution. Raw s_barrier (no vmcnt drain).
// EPI: 0 bf16, 1 fp32 R+acc, 2 bf16 relu, 3 qkv-fused per-head l2norm (q also x log2e/T).
template <int EPI>
__global__ __launch_bounds__(512) void gemm_bt3(const unsigned short* __restrict__ A,
                                                const unsigned short* __restrict__ B,
                                                const float* __restrict__ R,
                                                const float* __restrict__ Tptr,
                                                void* __restrict__ Cout, int M, int N, int K) {
  constexpr int BM = 256, BN = 128, BK = 64;
  __shared__ unsigned short lA[3][BM * BK];  // 3 x 32KB
  __shared__ unsigned short lB[3][BN * BK];  // 3 x 16KB
  const int tid = threadIdx.x, lane = tid & 63, wave = tid >> 6;
  const int l31 = lane & 31, l5 = lane >> 5;
  const int wm = wave >> 1, wn = wave & 1;
  // XCD-chunked swizzle (nwg % 8 == 0 for all our grids)
  const int nbx = gridDim.x;
  const int o = blockIdx.y * nbx + blockIdx.x;
  const int cpx = (nbx * gridDim.y) >> 3;
  const int w = (o & 7) * cpx + (o >> 3);
  const int bx = w % nbx, by = w / nbx;
  const int bm = by * BM, bn = bx * BN;
  // staging source pointers (per-lane, inverse-swizzled column slot)
  const int srow8 = lane >> 3;                 // row within the wave's 8-row group
  const int sslot = (lane & 7) ^ srow8;        // source 16B slot (involution)
  const unsigned short* sA0 = A + (size_t)(bm + wave * 8 + srow8) * K + sslot * 8;
  const unsigned short* sA1 = sA0 + (size_t)64 * K;
  const unsigned short* sA2 = sA0 + (size_t)128 * K;
  const unsigned short* sA3 = sA0 + (size_t)192 * K;
  const unsigned short* sB0 = B + (size_t)(bn + wave * 8 + srow8) * K + sslot * 8;
  const unsigned short* sB1 = sB0 + (size_t)64 * K;
  // LDS read offsets (shorts): row*64 + ((kk*2+l5) ^ (row&7))*8
  const int sx = l31 & 7;
  const int ar0 = (wm * 64 + l31) * 64, ar1 = ar0 + 32 * 64;
  const int br0 = (wn * 64 + l31) * 64, br1 = br0 + 32 * 64;
  const int k0 = ((0 + l5) ^ sx) * 8, k1 = ((2 + l5) ^ sx) * 8;
  const int k2 = ((4 + l5) ^ sx) * 8, k3 = ((6 + l5) ^ sx) * 8;
  f32x16 acc00 = {}, acc01 = {}, acc10 = {}, acc11 = {};
  const int NK = K / BK;
  // prologue: stage tiles 0,1; ensure tile 0 complete across all waves
  {
    gload16(sA0, &lA[0][(wave * 8) * 64]);
    gload16(sA1, &lA[0][(64 + wave * 8) * 64]);
    gload16(sA2, &lA[0][(128 + wave * 8) * 64]);
    gload16(sA3, &lA[0][(192 + wave * 8) * 64]);
    gload16(sB0, &lB[0][(wave * 8) * 64]);
    gload16(sB1, &lB[0][(64 + wave * 8) * 64]);
    gload16(sA0 + 64, &lA[1][(wave * 8) * 64]);
    gload16(sA1 + 64, &lA[1][(64 + wave * 8) * 64]);
    gload16(sA2 + 64, &lA[1][(128 + wave * 8) * 64]);
    gload16(sA3 + 64, &lA[1][(192 + wave * 8) * 64]);
    gload16(sB0 + 64, &lB[1][(wave * 8) * 64]);
    gload16(sB1 + 64, &lB[1][(64 + wave * 8) * 64]);
    asm volatile("s_waitcnt vmcnt(6)" ::: "memory");
    asm volatile("s_barrier" ::: "memory");
  }
  for (int t = 0; t < NK; ++t) {
    const unsigned short* La = &lA[t % 3][0];
    const unsigned short* Lb = &lB[t % 3][0];
    const int bufn = (t + 2) % 3;
    const bool pre = (t + 2 < NK);
    const size_t ko = (size_t)(t + 2) * 64;
    // ---- phase 0: acc00 ; stage A sweeps 0,1 for tile t+2 ----
    {
      short8 a0 = *(const short8*)(La + ar0 + k0), a1 = *(const short8*)(La + ar0 + k1);
      short8 a2 = *(const short8*)(La + ar0 + k2), a3 = *(const short8*)(La + ar0 + k3);
      short8 b0 = *(const short8*)(Lb + br0 + k0), b1 = *(const short8*)(Lb + br0 + k1);
      short8 b2 = *(const short8*)(Lb + br0 + k2), b3 = *(const short8*)(Lb + br0 + k3);
      if (pre) {
        gload16(sA0 + ko, &lA[bufn][(wave * 8) * 64]);
        gload16(sA1 + ko, &lA[bufn][(64 + wave * 8) * 64]);
      }
      asm volatile("s_barrier" ::: "memory");
      __builtin_amdgcn_s_setprio(1);
      acc00 = MFMA32(a0, b0, acc00); acc00 = MFMA32(a1, b1, acc00);
      acc00 = MFMA32(a2, b2, acc00); acc00 = MFMA32(a3, b3, acc00);
      __builtin_amdgcn_s_setprio(0);
      asm volatile("s_barrier" ::: "memory");
    }
    // ---- phase 1: acc01 ; stage A sweeps 2,3 ----
    {
      short8 a0 = *(const short8*)(La + ar0 + k0), a1 = *(const short8*)(La + ar0 + k1);
      short8 a2 = *(const short8*)(La + ar0 + k2), a3 = *(const short8*)(La + ar0 + k3);
      short8 b0 = *(const short8*)(Lb + br1 + k0), b1 = *(const short8*)(Lb + br1 + k1);
      short8 b2 = *(const short8*)(Lb + br1 + k2), b3 = *(const short8*)(Lb + br1 + k3);
      if (pre) {
        gload16(sA2 + ko, &lA[bufn][(128 + wave * 8) * 64]);
        gload16(sA3 + ko, &lA[bufn][(192 + wave * 8) * 64]);
      }
      asm volatile("s_barrier" ::: "memory");
      __builtin_amdgcn_s_setprio(1);
      acc01 = MFMA32(a0, b0, acc01); acc01 = MFMA32(a1, b1, acc01);
      acc01 = MFMA32(a2, b2, acc01); acc01 = MFMA32(a3, b3, acc01);
      __builtin_amdgcn_s_setprio(0);
      asm volatile("s_barrier" ::: "memory");
    }
    // ---- phase 2: acc10 ; stage B sweep 0 ----
    {
      short8 a0 = *(const short8*)(La + ar1 + k0), a1 = *(const short8*)(La + ar1 + k1);
      short8 a2 = *(const short8*)(La + ar1 + k2), a3 = *(const short8*)(La + ar1 + k3);
      short8 b0 = *(const short8*)(Lb + br0 + k0), b1 = *(const short8*)(Lb + br0 + k1);
      short8 b2 = *(const short8*)(Lb + br0 + k2), b3 = *(const short8*)(Lb + br0 + k3);
      if (pre) gload16(sB0 + ko, &lB[bufn][(wave * 8) * 64]);
      asm volatile("s_barrier" ::: "memory");
      __builtin_amdgcn_s_setprio(1);
      acc10 = MFMA32(a0, b0, acc10); acc10 = MFMA32(a1, b1, acc10);
      acc10 = MFMA32(a2, b2, acc10); acc10 = MFMA32(a3, b3, acc10);
      __builtin_amdgcn_s_setprio(0);
      asm volatile("s_barrier" ::: "memory");
    }
    // ---- phase 3: acc11 ; stage B sweep 1 ; K-tile boundary vmcnt ----
    {
      short8 a0 = *(const short8*)(La + ar1 + k0), a1 = *(const short8*)(La + ar1 + k1);
      short8 a2 = *(const short8*)(La + ar1 + k2), a3 = *(const short8*)(La + ar1 + k3);
      short8 b0 = *(const short8*)(Lb + br1 + k0), b1 = *(const short8*)(Lb + br1 + k1);
      short8 b2 = *(const short8*)(Lb + br1 + k2), b3 = *(const short8*)(Lb + br1 + k3);
      if (pre) gload16(sB1 + ko, &lB[bufn][(64 + wave * 8) * 64]);
      asm volatile("s_barrier" ::: "memory");
      __builtin_amdgcn_s_setprio(1);
      acc11 = MFMA32(a0, b0, acc11); acc11 = MFMA32(a1, b1, acc11);
      acc11 = MFMA32(a2, b2, acc11); acc11 = MFMA32(a3, b3, acc11);
      __builtin_amdgcn_s_setprio(0);
      if (pre) asm volatile("s_waitcnt vmcnt(6)" ::: "memory");
      else if (t + 1 < NK) asm volatile("s_waitcnt vmcnt(0)" ::: "memory");
      asm volatile("s_barrier" ::: "memory");
    }
  }
  // ---- epilogue: C row = bm + wm*64 + i*32 + (reg&3)+8*(reg>>2)+4*l5, col = bn + wn*64 + j*32 + l31
  const int r0 = bm + wm * 64 + 4 * l5;
  const int c0 = bn + wn * 64;
  if (EPI == 3) {
    const bool isq = c0 < 1024, isk = (c0 >= 1024) && (c0 < 2048);
    const float qs = 1.44269504088896f / Tptr[0];  // log2(e)/T folded into q
#pragma unroll
    for (int i = 0; i < 2; ++i) {
      const f32x16 va = (i == 0) ? acc00 : acc10;
      const f32x16 vb = (i == 0) ? acc01 : acc11;
#pragma unroll
      for (int reg = 0; reg < 16; ++reg) {
        float a0 = va[reg], a1 = vb[reg];
        float sc = 1.0f;
        if (isq || isk) {
          float ss = a0 * a0 + a1 * a1;
          ss += __shfl_xor(ss, 1);
          ss += __shfl_xor(ss, 2);
          ss += __shfl_xor(ss, 4);
          ss += __shfl_xor(ss, 8);
          ss += __shfl_xor(ss, 16);
          sc = 1.0f / fmaxf(sqrtf(ss), 1e-12f);
          if (isq) sc *= qs;
        }
        const int row = r0 + i * 32 + (reg & 3) + 8 * (reg >> 2);
        ((unsigned short*)Cout)[(size_t)row * N + (c0 + l31)] = f2bf(a0 * sc);
        ((unsigned short*)Cout)[(size_t)row * N + (c0 + 32 + l31)] = f2bf(a1 * sc);
      }
    }
  } else {
#pragma unroll
    for (int i = 0; i < 2; ++i) {
      const f32x16 va = (i == 0) ? acc00 : acc10;
      const f32x16 vb = (i == 0) ? acc01 : acc11;
#pragma unroll
      for (int reg = 0; reg < 16; ++reg) {
        const int row = r0 + i * 32 + (reg & 3) + 8 * (reg >> 2);
        size_t off0 = (size_t)row * N + (c0 + l31);
        size_t off1 = (size_t)row * N + (c0 + 32 + l31);
        float v0 = va[reg], v1 = vb[reg];
        if (EPI == 0) {
          ((unsigned short*)Cout)[off0] = f2bf(v0);
          ((unsigned short*)Cout)[off1] = f2bf(v1);
        } else if (EPI == 1) {
          ((float*)Cout)[off0] = R[off0] + v0;
          ((float*)Cout)[off1] = R[off1] + v1;
        } else {
          ((unsigned short*)Cout)[off0] = f2bf(fmaxf(v0, 0.f));
          ((unsigned short*)Cout)[off1] = f2bf(fmaxf(v1, 0.f));
        }
      }
    }
  }
}

// ---------------- transpose v -> Vt[b,h,d,n] ----------------
__global__ __launch_bounds__(256) void transpose_v(const unsigned short* __restrict__ qkv,
                                                   unsigned short* __restrict__ vt) {
  __shared__ unsigned short tile[64][80];
  const int blk = blockIdx.x;
  const int ntile = blk & 31, h = (blk >> 5) & 15, b = blk >> 9;
  const int t = threadIdx.x;
  const int tt = t >> 2, c4 = t & 3;
  size_t rowbase = (size_t)(b * SEQ + ntile * 64 + tt) * 3072 + h * 64 + c4 * 16;
  const unsigned short* pv = qkv + rowbase + 2048;
  *(short8*)&tile[tt][c4 * 16] = *(const short8*)pv;
  *(short8*)&tile[tt][c4 * 16 + 8] = *(const short8*)(pv + 8);
  __syncthreads();
  const int d = tt;
  short8 o0, o1;
#pragma unroll
  for (int j = 0; j < 8; ++j) o0[j] = (short)tile[c4 * 16 + j][d];
#pragma unroll
  for (int j = 0; j < 8; ++j) o1[j] = (short)tile[c4 * 16 + 8 + j][d];
  size_t vr = (size_t)((b * NHEADS + h) * DHEAD + d) * SEQ + ntile * 64 + c4 * 16;
  *(short8*)(vt + vr) = o0;
  *(short8*)(vt + vr + 8) = o1;
}

// ---------------- flash attention v9: 32x32 MFMA, in-register P, raw v_exp_f32 ----------------
__global__ __launch_bounds__(256) void attn_fwd9(const unsigned short* __restrict__ qkv,
                                                 const unsigned short* __restrict__ vt,
                                                 unsigned short* __restrict__ out,
                                                 const float* __restrict__ temp) {
  __shared__ unsigned short lK[2][64 * 64];
  __shared__ unsigned short lV[2][64 * 64];
  const int blk = blockIdx.x;
  const int bh = blk & 63, qt = blk >> 6;
  const int b = bh >> 4, h = bh & 15;
  const int tid = threadIdx.x, lane = tid & 63, wave = tid >> 6;
  const int l5 = lane >> 5, l31 = lane & 31;
  const int qr0 = qt * 128 + wave * 32;
  const float M0 = 1.05f * 1.44269504088896f / temp[0];  // bound on folded scores
  f32x16 minit;
#pragma unroll
  for (int r = 0; r < 16; ++r) minit[r] = -M0;
  const unsigned short* qrow = qkv + (size_t)(b * SEQ + qr0 + l31) * 3072 + h * 64 + l5 * 8;
  short8 qf[4];
#pragma unroll
  for (int t = 0; t < 4; ++t) qf[t] = *(const short8*)(qrow + t * 16);
  const int srow = tid >> 3, slot = tid & 7;
  const int sw0 = ((slot ^ (srow & 7)) * 8);
  const unsigned short* gK = qkv + (size_t)(b * SEQ + srow) * 3072 + 1024 + h * 64 + slot * 8;
  const unsigned short* gV = vt + ((size_t)(bh * 64) + srow) * SEQ + slot * 8;
  short8 rk0 = *(const short8*)gK;
  short8 rk1 = *(const short8*)(gK + (size_t)32 * 3072);
  short8 rv0 = *(const short8*)gV;
  short8 rv1 = *(const short8*)(gV + (size_t)32 * SEQ);
  *(short8*)&lK[0][srow * 64 + sw0] = rk0;
  *(short8*)&lK[0][(srow + 32) * 64 + sw0] = rk1;
  *(short8*)&lV[0][srow * 64 + sw0] = rv0;
  *(short8*)&lV[0][(srow + 32) * 64 + sw0] = rv1;
  f32x16 o0 = {}, o1 = {};
  float lsum = 0.f;
  constexpr int NT = SEQ / 64;
  for (int t = 0; t < NT; ++t) {
    __syncthreads();
    const unsigned short* Kb = &lK[t & 1][0];
    const unsigned short* Vb = &lV[t & 1][0];
    if (t + 1 < NT) {
      rk0 = *(const short8*)(gK + (size_t)(t + 1) * 64 * 3072);
      rk1 = *(const short8*)(gK + (size_t)((t + 1) * 64 + 32) * 3072);
      rv0 = *(const short8*)(gV + (t + 1) * 64);
      rv1 = *(const short8*)(gV + (size_t)32 * SEQ + (t + 1) * 64);
    }
#pragma unroll
    for (int tile = 0; tile < 2; ++tile) {
      f32x16 s = minit;
      __builtin_amdgcn_s_setprio(1);
#pragma unroll
      for (int td = 0; td < 4; ++td) {
        const int row = tile * 32 + l31;
        const int sl = ((2 * td + l5) ^ (row & 7)) * 8;
        short8 kf = *(const short8*)(Kb + row * 64 + sl);
        s = MFMA32(kf, qf[td], s);
      }
      __builtin_amdgcn_s_setprio(0);
      float p[16];
#pragma unroll
      for (int r = 0; r < 16; ++r) p[r] = exp2_fast(s[r]);
      float q01 = p[0] + p[1], q23 = p[2] + p[3], q45 = p[4] + p[5], q67 = p[6] + p[7];
      float q89 = p[8] + p[9], qab = p[10] + p[11], qcd = p[12] + p[13], qef = p[14] + p[15];
      lsum += ((q01 + q23) + (q45 + q67)) + ((q89 + qab) + (qcd + qef));
      unsigned a0 = cvt_pk_bf16(p[0], p[1]), a1 = cvt_pk_bf16(p[2], p[3]);
      unsigned a2 = cvt_pk_bf16(p[4], p[5]), a3 = cvt_pk_bf16(p[6], p[7]);
      unsigned c0 = cvt_pk_bf16(p[8], p[9]), c1 = cvt_pk_bf16(p[10], p[11]);
      unsigned c2 = cvt_pk_bf16(p[12], p[13]), c3 = cvt_pk_bf16(p[14], p[15]);
      uint2v w0 = __builtin_amdgcn_permlane32_swap(a0, a2, false, false);
      uint2v w1 = __builtin_amdgcn_permlane32_swap(a1, a3, false, false);
      uint2v w2 = __builtin_amdgcn_permlane32_swap(c0, c2, false, false);
      uint2v w3 = __builtin_amdgcn_permlane32_swap(c1, c3, false, false);
      union { unsigned u[4]; short8 v; } f0, f1;
      f0.u[0] = w0.x; f0.u[1] = w1.x; f0.u[2] = w0.y; f0.u[3] = w1.y;
      f1.u[0] = w2.x; f1.u[1] = w3.x; f1.u[2] = w2.y; f1.u[3] = w3.y;
      __builtin_amdgcn_s_setprio(1);
      {
        const int vrow0 = l31, vrow1 = 32 + l31;
        const int sa = ((2 * (tile * 2) + l5) ^ (vrow0 & 7)) * 8;
        const int sb = ((2 * (tile * 2 + 1) + l5) ^ (vrow0 & 7)) * 8;
        short8 va0 = *(const short8*)(Vb + vrow0 * 64 + sa);
        short8 vb0 = *(const short8*)(Vb + vrow0 * 64 + sb);
        short8 va1 = *(const short8*)(Vb + vrow1 * 64 + sa);
        short8 vb1 = *(const short8*)(Vb + vrow1 * 64 + sb);
        o0 = MFMA32(va0, f0.v, o0);
        o0 = MFMA32(vb0, f1.v, o0);
        o1 = MFMA32(va1, f0.v, o1);
        o1 = MFMA32(vb1, f1.v, o1);
      }
      __builtin_amdgcn_s_setprio(0);
    }
    if (t + 1 < NT) {
      *(short8*)&lK[(t + 1) & 1][srow * 64 + sw0] = rk0;
      *(short8*)&lK[(t + 1) & 1][(srow + 32) * 64 + sw0] = rk1;
      *(short8*)&lV[(t + 1) & 1][srow * 64 + sw0] = rv0;
      *(short8*)&lV[(t + 1) & 1][(srow + 32) * 64 + sw0] = rv1;
    }
  }
  lsum += __shfl_xor(lsum, 32);
  const float rinv = 1.0f / lsum;
  unsigned short* orow = out + (size_t)(b * SEQ + qr0 + l31) * D_MODEL + h * 64 + l5 * 4;
#pragma unroll
  for (int rq = 0; rq < 4; ++rq)
#pragma unroll
    for (int rr = 0; rr < 4; rr += 2) {
      *(unsigned*)(orow + rq * 8 + rr) =
          cvt_pk_bf16(o0[rq * 4 + rr] * rinv, o0[rq * 4 + rr + 1] * rinv);
      *(unsigned*)(orow + 32 + rq * 8 + rr) =
          cvt_pk_bf16(o1[rq * 4 + rr] * rinv, o1[rq * 4 + rr + 1] * rinv);
    }
}

// ---------------- host launch ----------------
extern "C" void kernel_launch(void* const* d_in, const int* in_sizes, int n_in, void* d_out,
                              int out_size, void* d_ws, size_t ws_size, hipStream_t stream) {
  const float* x = (const float*)d_in[0];
  const float* w_qkv = (const float*)d_in[1];
  const float* w_out = (const float*)d_in[2];
  const float* w_ffn1 = (const float*)d_in[3];
  const float* w_ffn2 = (const float*)d_in[4];
  const float* g1 = (const float*)d_in[5];
  const float* b1 = (const float*)d_in[6];
  const float* g2 = (const float*)d_in[7];
  const float* b2 = (const float*)d_in[8];
  const float* temp = (const float*)d_in[9];
  float* outp = (float*)d_out;

  char* ws = (char*)d_ws;
  size_t off = 0;
  auto alloc = [&](size_t bytes) {
    void* p = ws + off;
    off += (bytes + 255) & ~(size_t)255;
    return p;
  };
  unsigned short* wqkv_bf = (unsigned short*)alloc((size_t)3072 * 1024 * 2);
  unsigned short* wout_bf = (unsigned short*)alloc((size_t)1024 * 1024 * 2);
  unsigned short* wf1_bf = (unsigned short*)alloc((size_t)2048 * 1024 * 2);
  unsigned short* wf2_bf = (unsigned short*)alloc((size_t)1024 * 2048 * 2);
  unsigned short* h_bf = (unsigned short*)alloc((size_t)MTOK * 1024 * 2);   // reused for h2
  unsigned short* qkv_bf = (unsigned short*)alloc((size_t)MTOK * 3072 * 2); // reused for ffn1 out
  unsigned short* vt_bf = (unsigned short*)alloc((size_t)BATCH * NHEADS * DHEAD * SEQ * 2);
  unsigned short* ao_bf = (unsigned short*)alloc((size_t)MTOK * 1024 * 2);
  float* x2 = (float*)alloc((size_t)MTOK * 1024 * 4);

  // weight conversions (single launch)
  f32_to_bf16_all<<<8192, 256, 0, stream>>>(w_qkv, w_out, w_ffn1, w_ffn2, wqkv_bf, wout_bf, wf1_bf,
                                            wf2_bf);
  // LN1
  ln_fwd<<<MTOK, 256, 0, stream>>>(x, g1, b1, h_bf);
  // qkv = h @ w_qkv^T with fused per-head l2norm of q (x log2e/T) and k
  gemm_bt3<3><<<dim3(3072 / 128, MTOK / 256), 512, 0, stream>>>(h_bf, wqkv_bf, nullptr, temp,
                                                                (void*)qkv_bf, MTOK, 3072, 1024);
  // build Vt
  transpose_v<<<BATCH * NHEADS * (SEQ / 64), 256, 0, stream>>>(qkv_bf, vt_bf);
  // attention (32x32 MFMA, in-register P, raw v_exp, XCD-local mapping)
  attn_fwd9<<<BATCH * NHEADS * (SEQ / 128), 256, 0, stream>>>(qkv_bf, vt_bf, ao_bf, temp);
  // x2 = x + attn_out @ w_out^T
  gemm_bt3<1><<<dim3(1024 / 128, MTOK / 256), 512, 0, stream>>>(ao_bf, wout_bf, x, nullptr,
                                                                (void*)x2, MTOK, 1024, 1024);
  // LN2
  ln_fwd<<<MTOK, 256, 0, stream>>>(x2, g2, b2, h_bf);
  // ffn1 = relu(h2 @ w_ffn1^T)  (reuse qkv buffer)
  gemm_bt3<2><<<dim3(2048 / 128, MTOK / 256), 512, 0, stream>>>(h_bf, wf1_bf, nullptr, nullptr,
                                                                (void*)qkv_bf, MTOK, 2048, 1024);
  // out = x2 + ffn1 @ w_ffn2^T
  gemm_bt3<1><<<dim3(1024 / 128, MTOK / 256), 512, 0, stream>>>(qkv_bf, wf2_bf, x2, nullptr,
                                                                (void*)outp, MTOK, 1024, 2048);
}

// Round 11
// 344.955 us; speedup vs baseline: 1.1284x; 1.1284x over previous
//
#include <hip/hip_runtime.h>
#include <cstdint>
#include <cstddef>
#include <math.h>

typedef __attribute__((ext_vector_type(8))) short short8;
typedef __attribute__((ext_vector_type(4))) float f32x4;
typedef __attribute__((ext_vector_type(16))) float f32x16;
typedef __attribute__((ext_vector_type(2))) unsigned uint2v;

#define D_MODEL 1024
#define NHEADS 16
#define DHEAD 64
#define BATCH 4
#define SEQ 2048
#define MTOK (BATCH * SEQ)

__device__ __forceinline__ unsigned short f2bf(float f) {
  union { float f; unsigned u; } v; v.f = f;
  unsigned r = v.u + 0x7fffu + ((v.u >> 16) & 1u);
  return (unsigned short)(r >> 16);
}
__device__ __forceinline__ float bf2f(unsigned short u) {
  union { unsigned u; float f; } v; v.u = ((unsigned)u) << 16;
  return v.f;
}
__device__ __forceinline__ unsigned cvt_pk_bf16(float a, float b) {
  unsigned u;
  asm("v_cvt_pk_bf16_f32 %0, %1, %2" : "=v"(u) : "v"(a), "v"(b));
  return u;
}
// raw v_exp_f32 (2^x). Safe for x in [-126, 127]; our args are in [-62, 0].
__device__ __forceinline__ float exp2_fast(float x) {
  float r;
  asm("v_exp_f32 %0, %1" : "=v"(r) : "v"(x));
  return r;
}

typedef const __attribute__((address_space(1))) unsigned int* gas1_t;
typedef __attribute__((address_space(3))) unsigned int* las3_t;
// async global->LDS, 16B per lane; LDS dest must be wave-uniform base (HW adds lane*16B)
__device__ __forceinline__ void gload16(const unsigned short* g, unsigned short* l) {
  __builtin_amdgcn_global_load_lds((gas1_t)g, (las3_t)l, 16, 0, 0);
}

#define MFMA_BF16(a, b, c) __builtin_amdgcn_mfma_f32_16x16x32_bf16(a, b, c, 0, 0, 0)
#define MFMA32(a, b, c) __builtin_amdgcn_mfma_f32_32x32x16_bf16(a, b, c, 0, 0, 0)

// ---------------- fp32 -> bf16 conversion, all 4 weights in one launch ----------------
__global__ __launch_bounds__(256) void f32_to_bf16_all(const float* __restrict__ s0,
                                                       const float* __restrict__ s1,
                                                       const float* __restrict__ s2,
                                                       const float* __restrict__ s3,
                                                       unsigned short* __restrict__ d0,
                                                       unsigned short* __restrict__ d1,
                                                       unsigned short* __restrict__ d2,
                                                       unsigned short* __restrict__ d3) {
  int j = blockIdx.x * 256 + threadIdx.x;  // float4 index over concatenated ranges
  const float* s;
  unsigned short* d;
  if (j < 786432) { s = s0; d = d0; }
  else if ((j -= 786432) < 262144) { s = s1; d = d1; }
  else if ((j -= 262144) < 524288) { s = s2; d = d2; }
  else { j -= 524288; s = s3; d = d3; }
  float4 v = ((const float4*)s)[j];
  ushort4 o;
  o.x = f2bf(v.x); o.y = f2bf(v.y); o.z = f2bf(v.z); o.w = f2bf(v.w);
  ((ushort4*)d)[j] = o;
}

// ---------------- LayerNorm: fp32 in -> bf16 out ----------------
__global__ __launch_bounds__(256) void ln_fwd(const float* __restrict__ x, const float* __restrict__ g,
                                              const float* __restrict__ b,
                                              unsigned short* __restrict__ out) {
  const int row = blockIdx.x, t = threadIdx.x;
  float4 v = *(const float4*)(x + (size_t)row * D_MODEL + t * 4);
  float s = v.x + v.y + v.z + v.w;
  float s2 = v.x * v.x + v.y * v.y + v.z * v.z + v.w * v.w;
#pragma unroll
  for (int m = 1; m < 64; m <<= 1) { s += __shfl_xor(s, m); s2 += __shfl_xor(s2, m); }
  __shared__ float red[8];
  int wv = t >> 6;
  if ((t & 63) == 0) { red[wv] = s; red[4 + wv] = s2; }
  __syncthreads();
  s = red[0] + red[1] + red[2] + red[3];
  s2 = red[4] + red[5] + red[6] + red[7];
  float mu = s * (1.f / D_MODEL);
  float var = s2 * (1.f / D_MODEL) - mu * mu;
  float rs = rsqrtf(var + 1e-5f);
  float4 gg = *(const float4*)(g + t * 4);
  float4 bb = *(const float4*)(b + t * 4);
  ushort4 o;
  o.x = f2bf((v.x - mu) * rs * gg.x + bb.x);
  o.y = f2bf((v.y - mu) * rs * gg.y + bb.y);
  o.z = f2bf((v.z - mu) * rs * gg.z + bb.z);
  o.w = f2bf((v.w - mu) * rs * gg.w + bb.w);
  *(ushort4*)(out + (size_t)row * D_MODEL + t * 4) = o;
}

// ---------------- GEMM v2 (m97 structure, proven 716 TF): used for N=1024 GEMMs ----------------
// EPI: 0 bf16, 1 fp32 R+acc, 2 bf16 relu(acc), 3 qkv-fused l2norm.
template <int EPI>
__global__ __launch_bounds__(256) void gemm_bt2(const unsigned short* __restrict__ A,
                                                const unsigned short* __restrict__ B,
                                                const float* __restrict__ R,
                                                const float* __restrict__ Tptr,
                                                void* __restrict__ Cout, int M, int N, int K) {
  constexpr int BM = 128, BN = 128, BK = 32;
  __shared__ unsigned short lA[2][BM * BK], lB[2][BN * BK];
  const int tid = threadIdx.x, lane = tid & 63, wave = tid >> 6;
  const int lo = lane & 15, g = lane >> 4;
  const int nbx = gridDim.x;
  const int o = blockIdx.y * nbx + blockIdx.x;
  const int cpx = (nbx * gridDim.y) >> 3;
  const int w = (o & 7) * cpx + (o >> 3);
  const int bx = w % nbx, by = w / nbx;
  const int bm = by * BM, bn = bx * BN;
  const int wr = wave >> 1, wc = wave & 1;
  f32x4 acc[4][4] = {};
  const int c0 = wave * 128 + lane, c1 = c0 + 64;
  const unsigned short* gA0 = A + (size_t)(bm + (c0 >> 2)) * K + (c0 & 3) * 8;
  const unsigned short* gA1 = A + (size_t)(bm + (c1 >> 2)) * K + (c1 & 3) * 8;
  const unsigned short* gB0 = B + (size_t)(bn + (c0 >> 2)) * K + (c0 & 3) * 8;
  const unsigned short* gB1 = B + (size_t)(bn + (c1 >> 2)) * K + (c1 & 3) * 8;
  const int nk = K / BK;
  auto stage = [&](int buf, int kt) {
    const size_t ko = (size_t)kt * BK;
    gload16(gA0 + ko, &lA[buf][(wave * 128) * 8]);
    gload16(gA1 + ko, &lA[buf][(wave * 128 + 64) * 8]);
    gload16(gB0 + ko, &lB[buf][(wave * 128) * 8]);
    gload16(gB1 + ko, &lB[buf][(wave * 128 + 64) * 8]);
  };
  stage(0, 0);
  for (int kt = 0; kt < nk; ++kt) {
    __syncthreads();
    if (kt + 1 < nk) stage((kt + 1) & 1, kt + 1);
    const unsigned short* La = &lA[kt & 1][0];
    const unsigned short* Lb = &lB[kt & 1][0];
    short8 af[4], bfr[4];
#pragma unroll
    for (int m = 0; m < 4; ++m)
      af[m] = *(const short8*)(La + (wr * 64 + m * 16 + lo) * BK + g * 8);
#pragma unroll
    for (int n = 0; n < 4; ++n)
      bfr[n] = *(const short8*)(Lb + (wc * 64 + n * 16 + lo) * BK + g * 8);
#pragma unroll
    for (int m = 0; m < 4; ++m)
#pragma unroll
      for (int n = 0; n < 4; ++n) acc[m][n] = MFMA_BF16(af[m], bfr[n], acc[m][n]);
  }
  const int r0 = bm + wr * 64 + g * 4;
  const int c0c = bn + wc * 64 + lo;
#pragma unroll
  for (int m = 0; m < 4; ++m)
#pragma unroll
    for (int n = 0; n < 4; ++n) {
#pragma unroll
      for (int r = 0; r < 4; ++r) {
        size_t off = (size_t)(r0 + m * 16 + r) * N + (c0c + n * 16);
        float v = acc[m][n][r];
        if (EPI == 0) ((unsigned short*)Cout)[off] = f2bf(v);
        else if (EPI == 1) ((float*)Cout)[off] = R[off] + v;
        else ((unsigned short*)Cout)[off] = f2bf(fmaxf(v, 0.f));
      }
    }
}

// ---------------- GEMM v4 (gemm8): 256x128, BK=64, 2 fat phases/K-tile, counted vmcnt ----------------
// Fixes R10's defect: per K-tile now 16 ds_read_b128 (no duplicate fragment reads; B-frags
// held in registers across phases), 4 barriers (was 8), 8-MFMA interleaved clusters (was 4).
// Triple-buffered LDS (144KB), prefetch depth 2, vmcnt(6) only at K-tile end (T4).
// Staging: linear gload_lds dest + inverse-swizzled global source; reads XOR (row&7) (T2).
template <int EPI>
__global__ __launch_bounds__(512) void gemm8(const unsigned short* __restrict__ A,
                                             const unsigned short* __restrict__ B,
                                             const float* __restrict__ R,
                                             const float* __restrict__ Tptr,
                                             void* __restrict__ Cout, int M, int N, int K) {
  constexpr int BM = 256, BN = 128, BK = 64;
  __shared__ unsigned short lA[3][BM * BK];  // 3 x 32KB
  __shared__ unsigned short lB[3][BN * BK];  // 3 x 16KB
  const int tid = threadIdx.x, lane = tid & 63, wave = tid >> 6;
  const int l31 = lane & 31, l5 = lane >> 5;
  const int wm = wave >> 1, wn = wave & 1;
  const int nbx = gridDim.x;
  const int o = blockIdx.y * nbx + blockIdx.x;
  const int cpx = (nbx * gridDim.y) >> 3;
  const int w = (o & 7) * cpx + (o >> 3);
  const int bx = w % nbx, by = w / nbx;
  const int bm = by * BM, bn = bx * BN;
  const int srow8 = lane >> 3;
  const int sslot = (lane & 7) ^ srow8;  // inverse-swizzled source slot (involution)
  const unsigned short* sA0 = A + (size_t)(bm + wave * 8 + srow8) * K + sslot * 8;
  const unsigned short* sA1 = sA0 + (size_t)64 * K;
  const unsigned short* sA2 = sA0 + (size_t)128 * K;
  const unsigned short* sA3 = sA0 + (size_t)192 * K;
  const unsigned short* sB0 = B + (size_t)(bn + wave * 8 + srow8) * K + sslot * 8;
  const unsigned short* sB1 = sB0 + (size_t)64 * K;
  // LDS read offsets (shorts): row*64 + ((kk*2+l5) ^ (row&7))*8
  const int sx = l31 & 7;
  const int ar0 = (wm * 64 + l31) * 64, ar1 = ar0 + 32 * 64;
  const int br0 = (wn * 64 + l31) * 64, br1 = br0 + 32 * 64;
  const int k0 = ((0 + l5) ^ sx) * 8, k1 = ((2 + l5) ^ sx) * 8;
  const int k2 = ((4 + l5) ^ sx) * 8, k3 = ((6 + l5) ^ sx) * 8;
  f32x16 acc00 = {}, acc01 = {}, acc10 = {}, acc11 = {};
  const int NK = K / BK;
  // prologue: stage tiles 0,1 (6 gloads each); wait tile 0 landed
  {
    gload16(sA0, &lA[0][(wave * 8) * 64]);
    gload16(sA1, &lA[0][(64 + wave * 8) * 64]);
    gload16(sA2, &lA[0][(128 + wave * 8) * 64]);
    gload16(sA3, &lA[0][(192 + wave * 8) * 64]);
    gload16(sB0, &lB[0][(wave * 8) * 64]);
    gload16(sB1, &lB[0][(64 + wave * 8) * 64]);
    gload16(sA0 + 64, &lA[1][(wave * 8) * 64]);
    gload16(sA1 + 64, &lA[1][(64 + wave * 8) * 64]);
    gload16(sA2 + 64, &lA[1][(128 + wave * 8) * 64]);
    gload16(sA3 + 64, &lA[1][(192 + wave * 8) * 64]);
    gload16(sB0 + 64, &lB[1][(wave * 8) * 64]);
    gload16(sB1 + 64, &lB[1][(64 + wave * 8) * 64]);
    asm volatile("s_waitcnt vmcnt(6)" ::: "memory");
    asm volatile("s_barrier" ::: "memory");
  }
  for (int t = 0; t < NK; ++t) {
    const unsigned short* La = &lA[t % 3][0];
    const unsigned short* Lb = &lB[t % 3][0];
    const int bufn = (t + 2) % 3;
    const bool pre = (t + 2 < NK);
    const size_t ko = (size_t)(t + 2) * 64;
    // ---- phase 0: read B (both halves) + A-half0; 8 MFMA (acc00, acc01 interleaved) ----
    short8 b00 = *(const short8*)(Lb + br0 + k0), b01 = *(const short8*)(Lb + br0 + k1);
    short8 b02 = *(const short8*)(Lb + br0 + k2), b03 = *(const short8*)(Lb + br0 + k3);
    short8 b10 = *(const short8*)(Lb + br1 + k0), b11 = *(const short8*)(Lb + br1 + k1);
    short8 b12 = *(const short8*)(Lb + br1 + k2), b13 = *(const short8*)(Lb + br1 + k3);
    {
      short8 a0 = *(const short8*)(La + ar0 + k0), a1 = *(const short8*)(La + ar0 + k1);
      short8 a2 = *(const short8*)(La + ar0 + k2), a3 = *(const short8*)(La + ar0 + k3);
      if (pre) {
        gload16(sA0 + ko, &lA[bufn][(wave * 8) * 64]);
        gload16(sA1 + ko, &lA[bufn][(64 + wave * 8) * 64]);
        gload16(sB0 + ko, &lB[bufn][(wave * 8) * 64]);
      }
      asm volatile("s_barrier" ::: "memory");
      __builtin_amdgcn_s_setprio(1);
      acc00 = MFMA32(a0, b00, acc00); acc01 = MFMA32(a0, b10, acc01);
      acc00 = MFMA32(a1, b01, acc00); acc01 = MFMA32(a1, b11, acc01);
      acc00 = MFMA32(a2, b02, acc00); acc01 = MFMA32(a2, b12, acc01);
      acc00 = MFMA32(a3, b03, acc00); acc01 = MFMA32(a3, b13, acc01);
      __builtin_amdgcn_s_setprio(0);
      asm volatile("s_barrier" ::: "memory");
    }
    // ---- phase 1: read A-half1 only (B-frags live in regs); 8 MFMA (acc10, acc11) ----
    {
      short8 a0 = *(const short8*)(La + ar1 + k0), a1 = *(const short8*)(La + ar1 + k1);
      short8 a2 = *(const short8*)(La + ar1 + k2), a3 = *(const short8*)(La + ar1 + k3);
      if (pre) {
        gload16(sA2 + ko, &lA[bufn][(128 + wave * 8) * 64]);
        gload16(sA3 + ko, &lA[bufn][(192 + wave * 8) * 64]);
        gload16(sB1 + ko, &lB[bufn][(64 + wave * 8) * 64]);
      }
      asm volatile("s_barrier" ::: "memory");
      __builtin_amdgcn_s_setprio(1);
      acc10 = MFMA32(a0, b00, acc10); acc11 = MFMA32(a0, b10, acc11);
      acc10 = MFMA32(a1, b01, acc10); acc11 = MFMA32(a1, b11, acc11);
      acc10 = MFMA32(a2, b02, acc10); acc11 = MFMA32(a2, b12, acc11);
      acc10 = MFMA32(a3, b03, acc10); acc11 = MFMA32(a3, b13, acc11);
      __builtin_amdgcn_s_setprio(0);
      if (pre) asm volatile("s_waitcnt vmcnt(6)" ::: "memory");
      else if (t + 1 < NK) asm volatile("s_waitcnt vmcnt(0)" ::: "memory");
      asm volatile("s_barrier" ::: "memory");
    }
  }
  // ---- epilogue: row = bm + wm*64 + i*32 + (reg&3)+8*(reg>>2)+4*l5, col = bn + wn*64 + j*32 + l31
  const int r0 = bm + wm * 64 + 4 * l5;
  const int c0 = bn + wn * 64;
  if (EPI == 3) {
    const bool isq = c0 < 1024, isk = (c0 >= 1024) && (c0 < 2048);
    const float qs = 1.44269504088896f / Tptr[0];  // log2(e)/T folded into q
#pragma unroll
    for (int i = 0; i < 2; ++i) {
      const f32x16 va = (i == 0) ? acc00 : acc10;
      const f32x16 vb = (i == 0) ? acc01 : acc11;
#pragma unroll
      for (int reg = 0; reg < 16; ++reg) {
        float a0 = va[reg], a1 = vb[reg];
        float sc = 1.0f;
        if (isq || isk) {
          float ss = a0 * a0 + a1 * a1;
          ss += __shfl_xor(ss, 1);
          ss += __shfl_xor(ss, 2);
          ss += __shfl_xor(ss, 4);
          ss += __shfl_xor(ss, 8);
          ss += __shfl_xor(ss, 16);
          sc = 1.0f / fmaxf(sqrtf(ss), 1e-12f);
          if (isq) sc *= qs;
        }
        const int row = r0 + i * 32 + (reg & 3) + 8 * (reg >> 2);
        ((unsigned short*)Cout)[(size_t)row * N + (c0 + l31)] = f2bf(a0 * sc);
        ((unsigned short*)Cout)[(size_t)row * N + (c0 + 32 + l31)] = f2bf(a1 * sc);
      }
    }
  } else {
#pragma unroll
    for (int i = 0; i < 2; ++i) {
      const f32x16 va = (i == 0) ? acc00 : acc10;
      const f32x16 vb = (i == 0) ? acc01 : acc11;
#pragma unroll
      for (int reg = 0; reg < 16; ++reg) {
        const int row = r0 + i * 32 + (reg & 3) + 8 * (reg >> 2);
        size_t off0 = (size_t)row * N + (c0 + l31);
        size_t off1 = (size_t)row * N + (c0 + 32 + l31);
        float v0 = va[reg], v1 = vb[reg];
        if (EPI == 0) {
          ((unsigned short*)Cout)[off0] = f2bf(v0);
          ((unsigned short*)Cout)[off1] = f2bf(v1);
        } else if (EPI == 1) {
          ((float*)Cout)[off0] = R[off0] + v0;
          ((float*)Cout)[off1] = R[off1] + v1;
        } else {
          ((unsigned short*)Cout)[off0] = f2bf(fmaxf(v0, 0.f));
          ((unsigned short*)Cout)[off1] = f2bf(fmaxf(v1, 0.f));
        }
      }
    }
  }
}

// ---------------- transpose v -> Vt[b,h,d,n] ----------------
__global__ __launch_bounds__(256) void transpose_v(const unsigned short* __restrict__ qkv,
                                                   unsigned short* __restrict__ vt) {
  __shared__ unsigned short tile[64][80];
  const int blk = blockIdx.x;
  const int ntile = blk & 31, h = (blk >> 5) & 15, b = blk >> 9;
  const int t = threadIdx.x;
  const int tt = t >> 2, c4 = t & 3;
  size_t rowbase = (size_t)(b * SEQ + ntile * 64 + tt) * 3072 + h * 64 + c4 * 16;
  const unsigned short* pv = qkv + rowbase + 2048;
  *(short8*)&tile[tt][c4 * 16] = *(const short8*)pv;
  *(short8*)&tile[tt][c4 * 16 + 8] = *(const short8*)(pv + 8);
  __syncthreads();
  const int d = tt;
  short8 o0, o1;
#pragma unroll
  for (int j = 0; j < 8; ++j) o0[j] = (short)tile[c4 * 16 + j][d];
#pragma unroll
  for (int j = 0; j < 8; ++j) o1[j] = (short)tile[c4 * 16 + 8 + j][d];
  size_t vr = (size_t)((b * NHEADS + h) * DHEAD + d) * SEQ + ntile * 64 + c4 * 16;
  *(short8*)(vt + vr) = o0;
  *(short8*)(vt + vr + 8) = o1;
}

// ---------------- flash attention v9: 32x32 MFMA, in-register P, raw v_exp_f32 ----------------
__global__ __launch_bounds__(256) void attn_fwd9(const unsigned short* __restrict__ qkv,
                                                 const unsigned short* __restrict__ vt,
                                                 unsigned short* __restrict__ out,
                                                 const float* __restrict__ temp) {
  __shared__ unsigned short lK[2][64 * 64];
  __shared__ unsigned short lV[2][64 * 64];
  const int blk = blockIdx.x;
  const int bh = blk & 63, qt = blk >> 6;
  const int b = bh >> 4, h = bh & 15;
  const int tid = threadIdx.x, lane = tid & 63, wave = tid >> 6;
  const int l5 = lane >> 5, l31 = lane & 31;
  const int qr0 = qt * 128 + wave * 32;
  const float M0 = 1.05f * 1.44269504088896f / temp[0];  // bound on folded scores
  f32x16 minit;
#pragma unroll
  for (int r = 0; r < 16; ++r) minit[r] = -M0;
  const unsigned short* qrow = qkv + (size_t)(b * SEQ + qr0 + l31) * 3072 + h * 64 + l5 * 8;
  short8 qf[4];
#pragma unroll
  for (int t = 0; t < 4; ++t) qf[t] = *(const short8*)(qrow + t * 16);
  const int srow = tid >> 3, slot = tid & 7;
  const int sw0 = ((slot ^ (srow & 7)) * 8);
  const unsigned short* gK = qkv + (size_t)(b * SEQ + srow) * 3072 + 1024 + h * 64 + slot * 8;
  const unsigned short* gV = vt + ((size_t)(bh * 64) + srow) * SEQ + slot * 8;
  short8 rk0 = *(const short8*)gK;
  short8 rk1 = *(const short8*)(gK + (size_t)32 * 3072);
  short8 rv0 = *(const short8*)gV;
  short8 rv1 = *(const short8*)(gV + (size_t)32 * SEQ);
  *(short8*)&lK[0][srow * 64 + sw0] = rk0;
  *(short8*)&lK[0][(srow + 32) * 64 + sw0] = rk1;
  *(short8*)&lV[0][srow * 64 + sw0] = rv0;
  *(short8*)&lV[0][(srow + 32) * 64 + sw0] = rv1;
  f32x16 o0 = {}, o1 = {};
  float lsum = 0.f;
  constexpr int NT = SEQ / 64;
  for (int t = 0; t < NT; ++t) {
    __syncthreads();
    const unsigned short* Kb = &lK[t & 1][0];
    const unsigned short* Vb = &lV[t & 1][0];
    if (t + 1 < NT) {
      rk0 = *(const short8*)(gK + (size_t)(t + 1) * 64 * 3072);
      rk1 = *(const short8*)(gK + (size_t)((t + 1) * 64 + 32) * 3072);
      rv0 = *(const short8*)(gV + (t + 1) * 64);
      rv1 = *(const short8*)(gV + (size_t)32 * SEQ + (t + 1) * 64);
    }
#pragma unroll
    for (int tile = 0; tile < 2; ++tile) {
      f32x16 s = minit;
      __builtin_amdgcn_s_setprio(1);
#pragma unroll
      for (int td = 0; td < 4; ++td) {
        const int row = tile * 32 + l31;
        const int sl = ((2 * td + l5) ^ (row & 7)) * 8;
        short8 kf = *(const short8*)(Kb + row * 64 + sl);
        s = MFMA32(kf, qf[td], s);
      }
      __builtin_amdgcn_s_setprio(0);
      float p[16];
#pragma unroll
      for (int r = 0; r < 16; ++r) p[r] = exp2_fast(s[r]);
      float q01 = p[0] + p[1], q23 = p[2] + p[3], q45 = p[4] + p[5], q67 = p[6] + p[7];
      float q89 = p[8] + p[9], qab = p[10] + p[11], qcd = p[12] + p[13], qef = p[14] + p[15];
      lsum += ((q01 + q23) + (q45 + q67)) + ((q89 + qab) + (qcd + qef));
      unsigned a0 = cvt_pk_bf16(p[0], p[1]), a1 = cvt_pk_bf16(p[2], p[3]);
      unsigned a2 = cvt_pk_bf16(p[4], p[5]), a3 = cvt_pk_bf16(p[6], p[7]);
      unsigned c0 = cvt_pk_bf16(p[8], p[9]), c1 = cvt_pk_bf16(p[10], p[11]);
      unsigned c2 = cvt_pk_bf16(p[12], p[13]), c3 = cvt_pk_bf16(p[14], p[15]);
      uint2v w0 = __builtin_amdgcn_permlane32_swap(a0, a2, false, false);
      uint2v w1 = __builtin_amdgcn_permlane32_swap(a1, a3, false, false);
      uint2v w2 = __builtin_amdgcn_permlane32_swap(c0, c2, false, false);
      uint2v w3 = __builtin_amdgcn_permlane32_swap(c1, c3, false, false);
      union { unsigned u[4]; short8 v; } f0, f1;
      f0.u[0] = w0.x; f0.u[1] = w1.x; f0.u[2] = w0.y; f0.u[3] = w1.y;
      f1.u[0] = w2.x; f1.u[1] = w3.x; f1.u[2] = w2.y; f1.u[3] = w3.y;
      __builtin_amdgcn_s_setprio(1);
      {
        const int vrow0 = l31, vrow1 = 32 + l31;
        const int sa = ((2 * (tile * 2) + l5) ^ (vrow0 & 7)) * 8;
        const int sb = ((2 * (tile * 2 + 1) + l5) ^ (vrow0 & 7)) * 8;
        short8 va0 = *(const short8*)(Vb + vrow0 * 64 + sa);
        short8 vb0 = *(const short8*)(Vb + vrow0 * 64 + sb);
        short8 va1 = *(const short8*)(Vb + vrow1 * 64 + sa);
        short8 vb1 = *(const short8*)(Vb + vrow1 * 64 + sb);
        o0 = MFMA32(va0, f0.v, o0);
        o0 = MFMA32(vb0, f1.v, o0);
        o1 = MFMA32(va1, f0.v, o1);
        o1 = MFMA32(vb1, f1.v, o1);
      }
      __builtin_amdgcn_s_setprio(0);
    }
    if (t + 1 < NT) {
      *(short8*)&lK[(t + 1) & 1][srow * 64 + sw0] = rk0;
      *(short8*)&lK[(t + 1) & 1][(srow + 32) * 64 + sw0] = rk1;
      *(short8*)&lV[(t + 1) & 1][srow * 64 + sw0] = rv0;
      *(short8*)&lV[(t + 1) & 1][(srow + 32) * 64 + sw0] = rv1;
    }
  }
  lsum += __shfl_xor(lsum, 32);
  const float rinv = 1.0f / lsum;
  unsigned short* orow = out + (size_t)(b * SEQ + qr0 + l31) * D_MODEL + h * 64 + l5 * 4;
#pragma unroll
  for (int rq = 0; rq < 4; ++rq)
#pragma unroll
    for (int rr = 0; rr < 4; rr += 2) {
      *(unsigned*)(orow + rq * 8 + rr) =
          cvt_pk_bf16(o0[rq * 4 + rr] * rinv, o0[rq * 4 + rr + 1] * rinv);
      *(unsigned*)(orow + 32 + rq * 8 + rr) =
          cvt_pk_bf16(o1[rq * 4 + rr] * rinv, o1[rq * 4 + rr + 1] * rinv);
    }
}

// ---------------- host launch ----------------
extern "C" void kernel_launch(void* const* d_in, const int* in_sizes, int n_in, void* d_out,
                              int out_size, void* d_ws, size_t ws_size, hipStream_t stream) {
  const float* x = (const float*)d_in[0];
  const float* w_qkv = (const float*)d_in[1];
  const float* w_out = (const float*)d_in[2];
  const float* w_ffn1 = (const float*)d_in[3];
  const float* w_ffn2 = (const float*)d_in[4];
  const float* g1 = (const float*)d_in[5];
  const float* b1 = (const float*)d_in[6];
  const float* g2 = (const float*)d_in[7];
  const float* b2 = (const float*)d_in[8];
  const float* temp = (const float*)d_in[9];
  float* outp = (float*)d_out;

  char* ws = (char*)d_ws;
  size_t off = 0;
  auto alloc = [&](size_t bytes) {
    void* p = ws + off;
    off += (bytes + 255) & ~(size_t)255;
    return p;
  };
  unsigned short* wqkv_bf = (unsigned short*)alloc((size_t)3072 * 1024 * 2);
  unsigned short* wout_bf = (unsigned short*)alloc((size_t)1024 * 1024 * 2);
  unsigned short* wf1_bf = (unsigned short*)alloc((size_t)2048 * 1024 * 2);
  unsigned short* wf2_bf = (unsigned short*)alloc((size_t)1024 * 2048 * 2);
  unsigned short* h_bf = (unsigned short*)alloc((size_t)MTOK * 1024 * 2);   // reused for h2
  unsigned short* qkv_bf = (unsigned short*)alloc((size_t)MTOK * 3072 * 2); // reused for ffn1 out
  unsigned short* vt_bf = (unsigned short*)alloc((size_t)BATCH * NHEADS * DHEAD * SEQ * 2);
  unsigned short* ao_bf = (unsigned short*)alloc((size_t)MTOK * 1024 * 2);
  float* x2 = (float*)alloc((size_t)MTOK * 1024 * 4);

  // weight conversions (single launch)
  f32_to_bf16_all<<<8192, 256, 0, stream>>>(w_qkv, w_out, w_ffn1, w_ffn2, wqkv_bf, wout_bf, wf1_bf,
                                            wf2_bf);
  // LN1
  ln_fwd<<<MTOK, 256, 0, stream>>>(x, g1, b1, h_bf);
  // qkv = h @ w_qkv^T with fused per-head l2norm of q (x log2e/T) and k  [gemm8]
  gemm8<3><<<dim3(3072 / 128, MTOK / 256), 512, 0, stream>>>(h_bf, wqkv_bf, nullptr, temp,
                                                             (void*)qkv_bf, MTOK, 3072, 1024);
  // build Vt
  transpose_v<<<BATCH * NHEADS * (SEQ / 64), 256, 0, stream>>>(qkv_bf, vt_bf);
  // attention (32x32 MFMA, in-register P, raw v_exp, XCD-local mapping)
  attn_fwd9<<<BATCH * NHEADS * (SEQ / 128), 256, 0, stream>>>(qkv_bf, vt_bf, ao_bf, temp);
  // x2 = x + attn_out @ w_out^T  [proven gemm_bt2]
  gemm_bt2<1><<<dim3(1024 / 128, MTOK / 128), 256, 0, stream>>>(ao_bf, wout_bf, x, nullptr,
                                                                (void*)x2, MTOK, 1024, 1024);
  // LN2
  ln_fwd<<<MTOK, 256, 0, stream>>>(x2, g2, b2, h_bf);
  // ffn1 = relu(h2 @ w_ffn1^T)  [gemm8]
  gemm8<2><<<dim3(2048 / 128, MTOK / 256), 512, 0, stream>>>(h_bf, wf1_bf, nullptr, nullptr,
                                                             (void*)qkv_bf, MTOK, 2048, 1024);
  // out = x2 + ffn1 @ w_ffn2^T  [proven gemm_bt2]
  gemm_bt2<1><<<dim3(1024 / 128, MTOK / 128), 256, 0, stream>>>(qkv_bf, wf2_bf, x2, nullptr,
                                                                (void*)outp, MTOK, 1024, 2048);
}

// Round 12
// 331.922 us; speedup vs baseline: 1.1727x; 1.0393x over previous
//
#include <hip/hip_runtime.h>
#include <cstdint>
#include <cstddef>
#include <math.h>

typedef __attribute__((ext_vector_type(8))) short short8;
typedef __attribute__((ext_vector_type(4))) float f32x4;
typedef __attribute__((ext_vector_type(16))) float f32x16;
typedef __attribute__((ext_vector_type(2))) unsigned uint2v;

#define D_MODEL 1024
#define NHEADS 16
#define DHEAD 64
#define BATCH 4
#define SEQ 2048
#define MTOK (BATCH * SEQ)

__device__ __forceinline__ unsigned short f2bf(float f) {
  union { float f; unsigned u; } v; v.f = f;
  unsigned r = v.u + 0x7fffu + ((v.u >> 16) & 1u);
  return (unsigned short)(r >> 16);
}
__device__ __forceinline__ float bf2f(unsigned short u) {
  union { unsigned u; float f; } v; v.u = ((unsigned)u) << 16;
  return v.f;
}
__device__ __forceinline__ unsigned cvt_pk_bf16(float a, float b) {
  unsigned u;
  asm("v_cvt_pk_bf16_f32 %0, %1, %2" : "=v"(u) : "v"(a), "v"(b));
  return u;
}
// raw v_exp_f32 (2^x). Safe for x in [-126, 127]; our args are in [-62, 0].
__device__ __forceinline__ float exp2_fast(float x) {
  float r;
  asm("v_exp_f32 %0, %1" : "=v"(r) : "v"(x));
  return r;
}

typedef const __attribute__((address_space(1))) unsigned int* gas1_t;
typedef __attribute__((address_space(3))) unsigned int* las3_t;
// async global->LDS, 16B per lane; LDS dest must be wave-uniform base (HW adds lane*16B)
__device__ __forceinline__ void gload16(const unsigned short* g, unsigned short* l) {
  __builtin_amdgcn_global_load_lds((gas1_t)g, (las3_t)l, 16, 0, 0);
}

#define MFMA_BF16(a, b, c) __builtin_amdgcn_mfma_f32_16x16x32_bf16(a, b, c, 0, 0, 0)
#define MFMA32(a, b, c) __builtin_amdgcn_mfma_f32_32x32x16_bf16(a, b, c, 0, 0, 0)

// ---------------- fp32 -> bf16 conversion, all 4 weights in one launch ----------------
__global__ __launch_bounds__(256) void f32_to_bf16_all(const float* __restrict__ s0,
                                                       const float* __restrict__ s1,
                                                       const float* __restrict__ s2,
                                                       const float* __restrict__ s3,
                                                       unsigned short* __restrict__ d0,
                                                       unsigned short* __restrict__ d1,
                                                       unsigned short* __restrict__ d2,
                                                       unsigned short* __restrict__ d3) {
  int j = blockIdx.x * 256 + threadIdx.x;  // float4 index over concatenated ranges
  const float* s;
  unsigned short* d;
  if (j < 786432) { s = s0; d = d0; }
  else if ((j -= 786432) < 262144) { s = s1; d = d1; }
  else if ((j -= 262144) < 524288) { s = s2; d = d2; }
  else { j -= 524288; s = s3; d = d3; }
  float4 v = ((const float4*)s)[j];
  ushort4 o;
  o.x = f2bf(v.x); o.y = f2bf(v.y); o.z = f2bf(v.z); o.w = f2bf(v.w);
  ((ushort4*)d)[j] = o;
}

// ---------------- LayerNorm: fp32 in -> bf16 out ----------------
__global__ __launch_bounds__(256) void ln_fwd(const float* __restrict__ x, const float* __restrict__ g,
                                              const float* __restrict__ b,
                                              unsigned short* __restrict__ out) {
  const int row = blockIdx.x, t = threadIdx.x;
  float4 v = *(const float4*)(x + (size_t)row * D_MODEL + t * 4);
  float s = v.x + v.y + v.z + v.w;
  float s2 = v.x * v.x + v.y * v.y + v.z * v.z + v.w * v.w;
#pragma unroll
  for (int m = 1; m < 64; m <<= 1) { s += __shfl_xor(s, m); s2 += __shfl_xor(s2, m); }
  __shared__ float red[8];
  int wv = t >> 6;
  if ((t & 63) == 0) { red[wv] = s; red[4 + wv] = s2; }
  __syncthreads();
  s = red[0] + red[1] + red[2] + red[3];
  s2 = red[4] + red[5] + red[6] + red[7];
  float mu = s * (1.f / D_MODEL);
  float var = s2 * (1.f / D_MODEL) - mu * mu;
  float rs = rsqrtf(var + 1e-5f);
  float4 gg = *(const float4*)(g + t * 4);
  float4 bb = *(const float4*)(b + t * 4);
  ushort4 o;
  o.x = f2bf((v.x - mu) * rs * gg.x + bb.x);
  o.y = f2bf((v.y - mu) * rs * gg.y + bb.y);
  o.z = f2bf((v.z - mu) * rs * gg.z + bb.z);
  o.w = f2bf((v.w - mu) * rs * gg.w + bb.w);
  *(ushort4*)(out + (size_t)row * D_MODEL + t * 4) = o;
}

// ---------------- GEMM (m97 structure, proven): C[M,N] = A[M,K] * B[N,K]^T ----------------
// XCD-chunked block swizzle. EPI: 0 bf16, 1 fp32 R+acc, 2 bf16 relu(acc),
// 3 qkv-fused: per-head l2norm of q,k rows (q also x log2e/T), v plain bf16.
template <int EPI>
__global__ __launch_bounds__(256) void gemm_bt2(const unsigned short* __restrict__ A,
                                                const unsigned short* __restrict__ B,
                                                const float* __restrict__ R,
                                                const float* __restrict__ Tptr,
                                                void* __restrict__ Cout, int M, int N, int K) {
  constexpr int BM = 128, BN = 128, BK = 32;
  __shared__ unsigned short lA[2][BM * BK], lB[2][BN * BK];
  const int tid = threadIdx.x, lane = tid & 63, wave = tid >> 6;
  const int lo = lane & 15, g = lane >> 4;
  const int nbx = gridDim.x;
  const int o = blockIdx.y * nbx + blockIdx.x;
  const int cpx = (nbx * gridDim.y) >> 3;
  const int w = (o & 7) * cpx + (o >> 3);
  const int bx = w % nbx, by = w / nbx;
  const int bm = by * BM, bn = bx * BN;
  const int wr = wave >> 1, wc = wave & 1;
  f32x4 acc[4][4] = {};
  const int c0 = wave * 128 + lane, c1 = c0 + 64;
  const unsigned short* gA0 = A + (size_t)(bm + (c0 >> 2)) * K + (c0 & 3) * 8;
  const unsigned short* gA1 = A + (size_t)(bm + (c1 >> 2)) * K + (c1 & 3) * 8;
  const unsigned short* gB0 = B + (size_t)(bn + (c0 >> 2)) * K + (c0 & 3) * 8;
  const unsigned short* gB1 = B + (size_t)(bn + (c1 >> 2)) * K + (c1 & 3) * 8;
  const int nk = K / BK;
  auto stage = [&](int buf, int kt) {
    const size_t ko = (size_t)kt * BK;
    gload16(gA0 + ko, &lA[buf][(wave * 128) * 8]);
    gload16(gA1 + ko, &lA[buf][(wave * 128 + 64) * 8]);
    gload16(gB0 + ko, &lB[buf][(wave * 128) * 8]);
    gload16(gB1 + ko, &lB[buf][(wave * 128 + 64) * 8]);
  };
  stage(0, 0);
  for (int kt = 0; kt < nk; ++kt) {
    __syncthreads();
    if (kt + 1 < nk) stage((kt + 1) & 1, kt + 1);
    const unsigned short* La = &lA[kt & 1][0];
    const unsigned short* Lb = &lB[kt & 1][0];
    short8 af[4], bfr[4];
#pragma unroll
    for (int m = 0; m < 4; ++m)
      af[m] = *(const short8*)(La + (wr * 64 + m * 16 + lo) * BK + g * 8);
#pragma unroll
    for (int n = 0; n < 4; ++n)
      bfr[n] = *(const short8*)(Lb + (wc * 64 + n * 16 + lo) * BK + g * 8);
#pragma unroll
    for (int m = 0; m < 4; ++m)
#pragma unroll
      for (int n = 0; n < 4; ++n) acc[m][n] = MFMA_BF16(af[m], bfr[n], acc[m][n]);
  }
  const int r0 = bm + wr * 64 + g * 4;
  const int c0c = bn + wc * 64 + lo;
  if (EPI == 3) {
    // this wave's 64 output columns are exactly one head-slice of q, k, or v
    const int hb = bn + wc * 64;
    const bool isq = hb < 1024, isk = (hb >= 1024) && (hb < 2048);
    const float qs = 1.44269504088896f / Tptr[0];  // log2(e)/T folded into q
#pragma unroll
    for (int m = 0; m < 4; ++m)
#pragma unroll
      for (int r = 0; r < 4; ++r) {
        float sc = 1.0f;
        if (isq || isk) {
          float ss = 0.f;
#pragma unroll
          for (int n = 0; n < 4; ++n) ss += acc[m][n][r] * acc[m][n][r];
          ss += __shfl_xor(ss, 1);
          ss += __shfl_xor(ss, 2);
          ss += __shfl_xor(ss, 4);
          ss += __shfl_xor(ss, 8);  // full head-dim sum across the 16 lo-lanes
          sc = 1.0f / fmaxf(sqrtf(ss), 1e-12f);
          if (isq) sc *= qs;
        }
#pragma unroll
        for (int n = 0; n < 4; ++n) {
          size_t off = (size_t)(r0 + m * 16 + r) * N + (c0c + n * 16);
          ((unsigned short*)Cout)[off] = f2bf(acc[m][n][r] * sc);
        }
      }
  } else {
#pragma unroll
    for (int m = 0; m < 4; ++m)
#pragma unroll
      for (int n = 0; n < 4; ++n) {
#pragma unroll
        for (int r = 0; r < 4; ++r) {
          size_t off = (size_t)(r0 + m * 16 + r) * N + (c0c + n * 16);
          float v = acc[m][n][r];
          if (EPI == 0) ((unsigned short*)Cout)[off] = f2bf(v);
          else if (EPI == 1) ((float*)Cout)[off] = R[off] + v;
          else ((unsigned short*)Cout)[off] = f2bf(fmaxf(v, 0.f));
        }
      }
  }
}

// ---------------- transpose v -> Vt[b,h,d,n] ----------------
__global__ __launch_bounds__(256) void transpose_v(const unsigned short* __restrict__ qkv,
                                                   unsigned short* __restrict__ vt) {
  __shared__ unsigned short tile[64][80];
  const int blk = blockIdx.x;
  const int ntile = blk & 31, h = (blk >> 5) & 15, b = blk >> 9;
  const int t = threadIdx.x;
  const int tt = t >> 2, c4 = t & 3;
  size_t rowbase = (size_t)(b * SEQ + ntile * 64 + tt) * 3072 + h * 64 + c4 * 16;
  const unsigned short* pv = qkv + rowbase + 2048;
  *(short8*)&tile[tt][c4 * 16] = *(const short8*)pv;
  *(short8*)&tile[tt][c4 * 16 + 8] = *(const short8*)(pv + 8);
  __syncthreads();
  const int d = tt;
  short8 o0, o1;
#pragma unroll
  for (int j = 0; j < 8; ++j) o0[j] = (short)tile[c4 * 16 + j][d];
#pragma unroll
  for (int j = 0; j < 8; ++j) o1[j] = (short)tile[c4 * 16 + 8 + j][d];
  size_t vr = (size_t)((b * NHEADS + h) * DHEAD + d) * SEQ + ntile * 64 + c4 * 16;
  *(short8*)(vt + vr) = o0;
  *(short8*)(vt + vr + 8) = o1;
}

// ---------------- flash attention v10: 32x32 MFMA, in-register P, MFMA row-sum ----------------
// Swapped mfma(K,Q): lane holds S[k][q=lane&31]. Static-max via C-init=-M0 (cosine bound).
// P -> bf16 (cvt_pk) -> permlane32_swap builds PV B-frags in registers (no P LDS).
// Softmax denominator via MFMA with A=ones: sumacc[m][q] += sum_k P[k][q] accumulated across
// ALL iterations on the idle matrix pipe -- zero VALU adds, zero cross-lane reduce.
__global__ __launch_bounds__(256) void attn_fwd10(const unsigned short* __restrict__ qkv,
                                                  const unsigned short* __restrict__ vt,
                                                  unsigned short* __restrict__ out,
                                                  const float* __restrict__ temp) {
  __shared__ unsigned short lK[2][64 * 64];
  __shared__ unsigned short lV[2][64 * 64];
  const int blk = blockIdx.x;
  const int bh = blk & 63, qt = blk >> 6;
  const int b = bh >> 4, h = bh & 15;
  const int tid = threadIdx.x, lane = tid & 63, wave = tid >> 6;
  const int l5 = lane >> 5, l31 = lane & 31;
  const int qr0 = qt * 128 + wave * 32;
  const float M0 = 1.05f * 1.44269504088896f / temp[0];  // bound on folded scores
  f32x16 minit;
#pragma unroll
  for (int r = 0; r < 16; ++r) minit[r] = -M0;
  short8 ones;
#pragma unroll
  for (int j = 0; j < 8; ++j) ones[j] = (short)0x3F80;  // bf16 1.0
  const unsigned short* qrow = qkv + (size_t)(b * SEQ + qr0 + l31) * 3072 + h * 64 + l5 * 8;
  short8 qf[4];
#pragma unroll
  for (int t = 0; t < 4; ++t) qf[t] = *(const short8*)(qrow + t * 16);
  const int srow = tid >> 3, slot = tid & 7;
  const int sw0 = ((slot ^ (srow & 7)) * 8);
  const unsigned short* gK = qkv + (size_t)(b * SEQ + srow) * 3072 + 1024 + h * 64 + slot * 8;
  const unsigned short* gV = vt + ((size_t)(bh * 64) + srow) * SEQ + slot * 8;
  short8 rk0 = *(const short8*)gK;
  short8 rk1 = *(const short8*)(gK + (size_t)32 * 3072);
  short8 rv0 = *(const short8*)gV;
  short8 rv1 = *(const short8*)(gV + (size_t)32 * SEQ);
  *(short8*)&lK[0][srow * 64 + sw0] = rk0;
  *(short8*)&lK[0][(srow + 32) * 64 + sw0] = rk1;
  *(short8*)&lV[0][srow * 64 + sw0] = rv0;
  *(short8*)&lV[0][(srow + 32) * 64 + sw0] = rv1;
  f32x16 o0 = {}, o1 = {};   // O[d][q]: d-blocks 0..31 / 32..63
  f32x16 sacc = {};          // row-sum accumulator (all 16 regs identical at the end)
  constexpr int NT = SEQ / 64;
  for (int t = 0; t < NT; ++t) {
    __syncthreads();
    const unsigned short* Kb = &lK[t & 1][0];
    const unsigned short* Vb = &lV[t & 1][0];
    if (t + 1 < NT) {
      rk0 = *(const short8*)(gK + (size_t)(t + 1) * 64 * 3072);
      rk1 = *(const short8*)(gK + (size_t)((t + 1) * 64 + 32) * 3072);
      rv0 = *(const short8*)(gV + (t + 1) * 64);
      rv1 = *(const short8*)(gV + (size_t)32 * SEQ + (t + 1) * 64);
    }
#pragma unroll
    for (int tile = 0; tile < 2; ++tile) {
      f32x16 s = minit;
      __builtin_amdgcn_s_setprio(1);
#pragma unroll
      for (int td = 0; td < 4; ++td) {
        const int row = tile * 32 + l31;
        const int sl = ((2 * td + l5) ^ (row & 7)) * 8;
        short8 kf = *(const short8*)(Kb + row * 64 + sl);
        s = MFMA32(kf, qf[td], s);
      }
      __builtin_amdgcn_s_setprio(0);
      float p[16];
#pragma unroll
      for (int r = 0; r < 16; ++r) p[r] = exp2_fast(s[r]);
      unsigned a0 = cvt_pk_bf16(p[0], p[1]), a1 = cvt_pk_bf16(p[2], p[3]);
      unsigned a2 = cvt_pk_bf16(p[4], p[5]), a3 = cvt_pk_bf16(p[6], p[7]);
      unsigned c0 = cvt_pk_bf16(p[8], p[9]), c1 = cvt_pk_bf16(p[10], p[11]);
      unsigned c2 = cvt_pk_bf16(p[12], p[13]), c3 = cvt_pk_bf16(p[14], p[15]);
      uint2v w0 = __builtin_amdgcn_permlane32_swap(a0, a2, false, false);
      uint2v w1 = __builtin_amdgcn_permlane32_swap(a1, a3, false, false);
      uint2v w2 = __builtin_amdgcn_permlane32_swap(c0, c2, false, false);
      uint2v w3 = __builtin_amdgcn_permlane32_swap(c1, c3, false, false);
      union { unsigned u[4]; short8 v; } f0, f1;
      f0.u[0] = w0.x; f0.u[1] = w1.x; f0.u[2] = w0.y; f0.u[3] = w1.y;
      f1.u[0] = w2.x; f1.u[1] = w3.x; f1.u[2] = w2.y; f1.u[3] = w3.y;
      __builtin_amdgcn_s_setprio(1);
      {
        const int vrow0 = l31, vrow1 = 32 + l31;
        const int sa = ((2 * (tile * 2) + l5) ^ (vrow0 & 7)) * 8;
        const int sb = ((2 * (tile * 2 + 1) + l5) ^ (vrow0 & 7)) * 8;
        short8 va0 = *(const short8*)(Vb + vrow0 * 64 + sa);
        short8 vb0 = *(const short8*)(Vb + vrow0 * 64 + sb);
        short8 va1 = *(const short8*)(Vb + vrow1 * 64 + sa);
        short8 vb1 = *(const short8*)(Vb + vrow1 * 64 + sb);
        o0 = MFMA32(va0, f0.v, o0);
        o0 = MFMA32(vb0, f1.v, o0);
        o1 = MFMA32(va1, f0.v, o1);
        o1 = MFMA32(vb1, f1.v, o1);
        sacc = MFMA32(ones, f0.v, sacc);  // denominator on the matrix pipe
        sacc = MFMA32(ones, f1.v, sacc);
      }
      __builtin_amdgcn_s_setprio(0);
    }
    if (t + 1 < NT) {
      *(short8*)&lK[(t + 1) & 1][srow * 64 + sw0] = rk0;
      *(short8*)&lK[(t + 1) & 1][(srow + 32) * 64 + sw0] = rk1;
      *(short8*)&lV[(t + 1) & 1][srow * 64 + sw0] = rv0;
      *(short8*)&lV[(t + 1) & 1][(srow + 32) * 64 + sw0] = rv1;
    }
  }
  // sacc[m][q] = full row sum for q = l31 (every reg identical); no reduce needed
  const float rinv = 1.0f / sacc[0];
  unsigned short* orow = out + (size_t)(b * SEQ + qr0 + l31) * D_MODEL + h * 64 + l5 * 4;
#pragma unroll
  for (int rq = 0; rq < 4; ++rq)
#pragma unroll
    for (int rr = 0; rr < 4; rr += 2) {
      *(unsigned*)(orow + rq * 8 + rr) =
          cvt_pk_bf16(o0[rq * 4 + rr] * rinv, o0[rq * 4 + rr + 1] * rinv);
      *(unsigned*)(orow + 32 + rq * 8 + rr) =
          cvt_pk_bf16(o1[rq * 4 + rr] * rinv, o1[rq * 4 + rr + 1] * rinv);
    }
}

// ---------------- host launch ----------------
extern "C" void kernel_launch(void* const* d_in, const int* in_sizes, int n_in, void* d_out,
                              int out_size, void* d_ws, size_t ws_size, hipStream_t stream) {
  const float* x = (const float*)d_in[0];
  const float* w_qkv = (const float*)d_in[1];
  const float* w_out = (const float*)d_in[2];
  const float* w_ffn1 = (const float*)d_in[3];
  const float* w_ffn2 = (const float*)d_in[4];
  const float* g1 = (const float*)d_in[5];
  const float* b1 = (const float*)d_in[6];
  const float* g2 = (const float*)d_in[7];
  const float* b2 = (const float*)d_in[8];
  const float* temp = (const float*)d_in[9];
  float* outp = (float*)d_out;

  char* ws = (char*)d_ws;
  size_t off = 0;
  auto alloc = [&](size_t bytes) {
    void* p = ws + off;
    off += (bytes + 255) & ~(size_t)255;
    return p;
  };
  unsigned short* wqkv_bf = (unsigned short*)alloc((size_t)3072 * 1024 * 2);
  unsigned short* wout_bf = (unsigned short*)alloc((size_t)1024 * 1024 * 2);
  unsigned short* wf1_bf = (unsigned short*)alloc((size_t)2048 * 1024 * 2);
  unsigned short* wf2_bf = (unsigned short*)alloc((size_t)1024 * 2048 * 2);
  unsigned short* h_bf = (unsigned short*)alloc((size_t)MTOK * 1024 * 2);   // reused for h2
  unsigned short* qkv_bf = (unsigned short*)alloc((size_t)MTOK * 3072 * 2); // reused for ffn1 out
  unsigned short* vt_bf = (unsigned short*)alloc((size_t)BATCH * NHEADS * DHEAD * SEQ * 2);
  unsigned short* ao_bf = (unsigned short*)alloc((size_t)MTOK * 1024 * 2);
  float* x2 = (float*)alloc((size_t)MTOK * 1024 * 4);

  // weight conversions (single launch)
  f32_to_bf16_all<<<8192, 256, 0, stream>>>(w_qkv, w_out, w_ffn1, w_ffn2, wqkv_bf, wout_bf, wf1_bf,
                                            wf2_bf);
  // LN1
  ln_fwd<<<MTOK, 256, 0, stream>>>(x, g1, b1, h_bf);
  // qkv = h @ w_qkv^T with fused per-head l2norm of q (x log2e/T) and k  [proven gemm_bt2]
  gemm_bt2<3><<<dim3(3072 / 128, MTOK / 128), 256, 0, stream>>>(h_bf, wqkv_bf, nullptr, temp,
                                                                (void*)qkv_bf, MTOK, 3072, 1024);
  // build Vt
  transpose_v<<<BATCH * NHEADS * (SEQ / 64), 256, 0, stream>>>(qkv_bf, vt_bf);
  // attention (32x32 MFMA, in-register P, MFMA row-sum, XCD-local mapping)
  attn_fwd10<<<BATCH * NHEADS * (SEQ / 128), 256, 0, stream>>>(qkv_bf, vt_bf, ao_bf, temp);
  // x2 = x + attn_out @ w_out^T
  gemm_bt2<1><<<dim3(1024 / 128, MTOK / 128), 256, 0, stream>>>(ao_bf, wout_bf, x, nullptr,
                                                                (void*)x2, MTOK, 1024, 1024);
  // LN2
  ln_fwd<<<MTOK, 256, 0, stream>>>(x2, g2, b2, h_bf);
  // ffn1 = relu(h2 @ w_ffn1^T)  (reuse qkv buffer)
  gemm_bt2<2><<<dim3(2048 / 128, MTOK / 128), 256, 0, stream>>>(h_bf, wf1_bf, nullptr, nullptr,
                                                                (void*)qkv_bf, MTOK, 2048, 1024);
  // out = x2 + ffn1 @ w_ffn2^T
  gemm_bt2<1><<<dim3(1024 / 128, MTOK / 128), 256, 0, stream>>>(qkv_bf, wf2_bf, x2, nullptr,
                                                                (void*)outp, MTOK, 1024, 2048);
}

// Round 13
// 320.163 us; speedup vs baseline: 1.2157x; 1.0367x over previous
//
#include <hip/hip_runtime.h>
#include <cstdint>
#include <cstddef>
#include <math.h>

typedef __attribute__((ext_vector_type(8))) short short8;
typedef __attribute__((ext_vector_type(4))) float f32x4;
typedef __attribute__((ext_vector_type(16))) float f32x16;
typedef __attribute__((ext_vector_type(2))) unsigned uint2v;

#define D_MODEL 1024
#define NHEADS 16
#define DHEAD 64
#define BATCH 4
#define SEQ 2048
#define MTOK (BATCH * SEQ)

__device__ __forceinline__ unsigned short f2bf(float f) {
  union { float f; unsigned u; } v; v.f = f;
  unsigned r = v.u + 0x7fffu + ((v.u >> 16) & 1u);
  return (unsigned short)(r >> 16);
}
__device__ __forceinline__ float bf2f(unsigned short u) {
  union { unsigned u; float f; } v; v.u = ((unsigned)u) << 16;
  return v.f;
}
__device__ __forceinline__ unsigned cvt_pk_bf16(float a, float b) {
  unsigned u;
  asm("v_cvt_pk_bf16_f32 %0, %1, %2" : "=v"(u) : "v"(a), "v"(b));
  return u;
}
// raw v_exp_f32 (2^x). Safe for x in [-126, 127]; our args are in [-62, 0].
__device__ __forceinline__ float exp2_fast(float x) {
  float r;
  asm("v_exp_f32 %0, %1" : "=v"(r) : "v"(x));
  return r;
}

typedef const __attribute__((address_space(1))) unsigned int* gas1_t;
typedef __attribute__((address_space(3))) unsigned int* las3_t;
// async global->LDS, 16B per lane; LDS dest must be wave-uniform base (HW adds lane*16B)
__device__ __forceinline__ void gload16(const unsigned short* g, unsigned short* l) {
  __builtin_amdgcn_global_load_lds((gas1_t)g, (las3_t)l, 16, 0, 0);
}

#define MFMA_BF16(a, b, c) __builtin_amdgcn_mfma_f32_16x16x32_bf16(a, b, c, 0, 0, 0)
#define MFMA32(a, b, c) __builtin_amdgcn_mfma_f32_32x32x16_bf16(a, b, c, 0, 0, 0)

// ---------------- fp32 -> bf16 conversion, all 4 weights in one launch ----------------
__global__ __launch_bounds__(256) void f32_to_bf16_all(const float* __restrict__ s0,
                                                       const float* __restrict__ s1,
                                                       const float* __restrict__ s2,
                                                       const float* __restrict__ s3,
                                                       unsigned short* __restrict__ d0,
                                                       unsigned short* __restrict__ d1,
                                                       unsigned short* __restrict__ d2,
                                                       unsigned short* __restrict__ d3) {
  int j = blockIdx.x * 256 + threadIdx.x;  // float4 index over concatenated ranges
  const float* s;
  unsigned short* d;
  if (j < 786432) { s = s0; d = d0; }
  else if ((j -= 786432) < 262144) { s = s1; d = d1; }
  else if ((j -= 262144) < 524288) { s = s2; d = d2; }
  else { j -= 524288; s = s3; d = d3; }
  float4 v = ((const float4*)s)[j];
  ushort4 o;
  o.x = f2bf(v.x); o.y = f2bf(v.y); o.z = f2bf(v.z); o.w = f2bf(v.w);
  ((ushort4*)d)[j] = o;
}

// ---------------- LayerNorm: fp32 in -> bf16 out ----------------
__global__ __launch_bounds__(256) void ln_fwd(const float* __restrict__ x, const float* __restrict__ g,
                                              const float* __restrict__ b,
                                              unsigned short* __restrict__ out) {
  const int row = blockIdx.x, t = threadIdx.x;
  float4 v = *(const float4*)(x + (size_t)row * D_MODEL + t * 4);
  float s = v.x + v.y + v.z + v.w;
  float s2 = v.x * v.x + v.y * v.y + v.z * v.z + v.w * v.w;
#pragma unroll
  for (int m = 1; m < 64; m <<= 1) { s += __shfl_xor(s, m); s2 += __shfl_xor(s2, m); }
  __shared__ float red[8];
  int wv = t >> 6;
  if ((t & 63) == 0) { red[wv] = s; red[4 + wv] = s2; }
  __syncthreads();
  s = red[0] + red[1] + red[2] + red[3];
  s2 = red[4] + red[5] + red[6] + red[7];
  float mu = s * (1.f / D_MODEL);
  float var = s2 * (1.f / D_MODEL) - mu * mu;
  float rs = rsqrtf(var + 1e-5f);
  float4 gg = *(const float4*)(g + t * 4);
  float4 bb = *(const float4*)(b + t * 4);
  ushort4 o;
  o.x = f2bf((v.x - mu) * rs * gg.x + bb.x);
  o.y = f2bf((v.y - mu) * rs * gg.y + bb.y);
  o.z = f2bf((v.z - mu) * rs * gg.z + bb.z);
  o.w = f2bf((v.w - mu) * rs * gg.w + bb.w);
  *(ushort4*)(out + (size_t)row * D_MODEL + t * 4) = o;
}

// ---------------- LayerNorm: bf16 in -> bf16 out ----------------
__global__ __launch_bounds__(256) void ln_fwd_b(const unsigned short* __restrict__ x,
                                                const float* __restrict__ g,
                                                const float* __restrict__ b,
                                                unsigned short* __restrict__ out) {
  const int row = blockIdx.x, t = threadIdx.x;
  ushort4 vi = *(const ushort4*)(x + (size_t)row * D_MODEL + t * 4);
  float f0 = bf2f(vi.x), f1 = bf2f(vi.y), f2 = bf2f(vi.z), f3 = bf2f(vi.w);
  float s = f0 + f1 + f2 + f3;
  float s2 = f0 * f0 + f1 * f1 + f2 * f2 + f3 * f3;
#pragma unroll
  for (int m = 1; m < 64; m <<= 1) { s += __shfl_xor(s, m); s2 += __shfl_xor(s2, m); }
  __shared__ float red[8];
  int wv = t >> 6;
  if ((t & 63) == 0) { red[wv] = s; red[4 + wv] = s2; }
  __syncthreads();
  s = red[0] + red[1] + red[2] + red[3];
  s2 = red[4] + red[5] + red[6] + red[7];
  float mu = s * (1.f / D_MODEL);
  float var = s2 * (1.f / D_MODEL) - mu * mu;
  float rs = rsqrtf(var + 1e-5f);
  float4 gg = *(const float4*)(g + t * 4);
  float4 bb = *(const float4*)(b + t * 4);
  ushort4 o;
  o.x = f2bf((f0 - mu) * rs * gg.x + bb.x);
  o.y = f2bf((f1 - mu) * rs * gg.y + bb.y);
  o.z = f2bf((f2 - mu) * rs * gg.z + bb.z);
  o.w = f2bf((f3 - mu) * rs * gg.w + bb.w);
  *(ushort4*)(out + (size_t)row * D_MODEL + t * 4) = o;
}

// ---------------- GEMM (m97 structure, proven): C[M,N] = A[M,K] * B[N,K]^T ----------------
// XCD-chunked block swizzle. EPI: 0 bf16, 1 fp32 R+acc, 2 bf16 relu(acc),
// 3 qkv-fused per-head l2norm (q also x log2e/T), 4 bf16 store of (R_f32 + acc),
// 5 fp32 store of (R_bf16 + acc)  [R passed as bf16 buffer cast to float*].
template <int EPI>
__global__ __launch_bounds__(256) void gemm_bt2(const unsigned short* __restrict__ A,
                                                const unsigned short* __restrict__ B,
                                                const float* __restrict__ R,
                                                const float* __restrict__ Tptr,
                                                void* __restrict__ Cout, int M, int N, int K) {
  constexpr int BM = 128, BN = 128, BK = 32;
  __shared__ unsigned short lA[2][BM * BK], lB[2][BN * BK];
  const int tid = threadIdx.x, lane = tid & 63, wave = tid >> 6;
  const int lo = lane & 15, g = lane >> 4;
  const int nbx = gridDim.x;
  const int o = blockIdx.y * nbx + blockIdx.x;
  const int cpx = (nbx * gridDim.y) >> 3;
  const int w = (o & 7) * cpx + (o >> 3);
  const int bx = w % nbx, by = w / nbx;
  const int bm = by * BM, bn = bx * BN;
  const int wr = wave >> 1, wc = wave & 1;
  f32x4 acc[4][4] = {};
  const int c0 = wave * 128 + lane, c1 = c0 + 64;
  const unsigned short* gA0 = A + (size_t)(bm + (c0 >> 2)) * K + (c0 & 3) * 8;
  const unsigned short* gA1 = A + (size_t)(bm + (c1 >> 2)) * K + (c1 & 3) * 8;
  const unsigned short* gB0 = B + (size_t)(bn + (c0 >> 2)) * K + (c0 & 3) * 8;
  const unsigned short* gB1 = B + (size_t)(bn + (c1 >> 2)) * K + (c1 & 3) * 8;
  const int nk = K / BK;
  auto stage = [&](int buf, int kt) {
    const size_t ko = (size_t)kt * BK;
    gload16(gA0 + ko, &lA[buf][(wave * 128) * 8]);
    gload16(gA1 + ko, &lA[buf][(wave * 128 + 64) * 8]);
    gload16(gB0 + ko, &lB[buf][(wave * 128) * 8]);
    gload16(gB1 + ko, &lB[buf][(wave * 128 + 64) * 8]);
  };
  stage(0, 0);
  for (int kt = 0; kt < nk; ++kt) {
    __syncthreads();
    if (kt + 1 < nk) stage((kt + 1) & 1, kt + 1);
    const unsigned short* La = &lA[kt & 1][0];
    const unsigned short* Lb = &lB[kt & 1][0];
    short8 af[4], bfr[4];
#pragma unroll
    for (int m = 0; m < 4; ++m)
      af[m] = *(const short8*)(La + (wr * 64 + m * 16 + lo) * BK + g * 8);
#pragma unroll
    for (int n = 0; n < 4; ++n)
      bfr[n] = *(const short8*)(Lb + (wc * 64 + n * 16 + lo) * BK + g * 8);
#pragma unroll
    for (int m = 0; m < 4; ++m)
#pragma unroll
      for (int n = 0; n < 4; ++n) acc[m][n] = MFMA_BF16(af[m], bfr[n], acc[m][n]);
  }
  const int r0 = bm + wr * 64 + g * 4;
  const int c0c = bn + wc * 64 + lo;
  if (EPI == 3) {
    // this wave's 64 output columns are exactly one head-slice of q, k, or v
    const int hb = bn + wc * 64;
    const bool isq = hb < 1024, isk = (hb >= 1024) && (hb < 2048);
    const float qs = 1.44269504088896f / Tptr[0];  // log2(e)/T folded into q
#pragma unroll
    for (int m = 0; m < 4; ++m)
#pragma unroll
      for (int r = 0; r < 4; ++r) {
        float sc = 1.0f;
        if (isq || isk) {
          float ss = 0.f;
#pragma unroll
          for (int n = 0; n < 4; ++n) ss += acc[m][n][r] * acc[m][n][r];
          ss += __shfl_xor(ss, 1);
          ss += __shfl_xor(ss, 2);
          ss += __shfl_xor(ss, 4);
          ss += __shfl_xor(ss, 8);  // full head-dim sum across the 16 lo-lanes
          sc = 1.0f / fmaxf(sqrtf(ss), 1e-12f);
          if (isq) sc *= qs;
        }
#pragma unroll
        for (int n = 0; n < 4; ++n) {
          size_t off = (size_t)(r0 + m * 16 + r) * N + (c0c + n * 16);
          ((unsigned short*)Cout)[off] = f2bf(acc[m][n][r] * sc);
        }
      }
  } else {
#pragma unroll
    for (int m = 0; m < 4; ++m)
#pragma unroll
      for (int n = 0; n < 4; ++n) {
#pragma unroll
        for (int r = 0; r < 4; ++r) {
          size_t off = (size_t)(r0 + m * 16 + r) * N + (c0c + n * 16);
          float v = acc[m][n][r];
          if (EPI == 0) ((unsigned short*)Cout)[off] = f2bf(v);
          else if (EPI == 1) ((float*)Cout)[off] = R[off] + v;
          else if (EPI == 2) ((unsigned short*)Cout)[off] = f2bf(fmaxf(v, 0.f));
          else if (EPI == 4) ((unsigned short*)Cout)[off] = f2bf(R[off] + v);
          else /* EPI == 5 */ ((float*)Cout)[off] = bf2f(((const unsigned short*)R)[off]) + v;
        }
      }
  }
}

// ---------------- transpose v -> Vt[b,h,d,n] ----------------
__global__ __launch_bounds__(256) void transpose_v(const unsigned short* __restrict__ qkv,
                                                   unsigned short* __restrict__ vt) {
  __shared__ unsigned short tile[64][80];
  const int blk = blockIdx.x;
  const int ntile = blk & 31, h = (blk >> 5) & 15, b = blk >> 9;
  const int t = threadIdx.x;
  const int tt = t >> 2, c4 = t & 3;
  size_t rowbase = (size_t)(b * SEQ + ntile * 64 + tt) * 3072 + h * 64 + c4 * 16;
  const unsigned short* pv = qkv + rowbase + 2048;
  *(short8*)&tile[tt][c4 * 16] = *(const short8*)pv;
  *(short8*)&tile[tt][c4 * 16 + 8] = *(const short8*)(pv + 8);
  __syncthreads();
  const int d = tt;
  short8 o0, o1;
#pragma unroll
  for (int j = 0; j < 8; ++j) o0[j] = (short)tile[c4 * 16 + j][d];
#pragma unroll
  for (int j = 0; j < 8; ++j) o1[j] = (short)tile[c4 * 16 + 8 + j][d];
  size_t vr = (size_t)((b * NHEADS + h) * DHEAD + d) * SEQ + ntile * 64 + c4 * 16;
  *(short8*)(vt + vr) = o0;
  *(short8*)(vt + vr + 8) = o1;
}

// ---------------- flash attention v9: 32x32 MFMA, in-register P, raw v_exp_f32 ----------------
// Swapped mfma(K,Q): lane holds S[k][q=lane&31]. Static-max via C-init=-M0 (cosine bound).
// P -> bf16 (cvt_pk) -> permlane32_swap builds PV B-frags in registers (no P LDS).
// exp2 via raw v_exp_f32 (args in [-62,0]); P-sum as a balanced tree (no ordered chain).
__global__ __launch_bounds__(256) void attn_fwd9(const unsigned short* __restrict__ qkv,
                                                 const unsigned short* __restrict__ vt,
                                                 unsigned short* __restrict__ out,
                                                 const float* __restrict__ temp) {
  __shared__ unsigned short lK[2][64 * 64];
  __shared__ unsigned short lV[2][64 * 64];
  const int blk = blockIdx.x;
  const int bh = blk & 63, qt = blk >> 6;
  const int b = bh >> 4, h = bh & 15;
  const int tid = threadIdx.x, lane = tid & 63, wave = tid >> 6;
  const int l5 = lane >> 5, l31 = lane & 31;
  const int qr0 = qt * 128 + wave * 32;
  const float M0 = 1.05f * 1.44269504088896f / temp[0];  // bound on folded scores
  f32x16 minit;
#pragma unroll
  for (int r = 0; r < 16; ++r) minit[r] = -M0;
  const unsigned short* qrow = qkv + (size_t)(b * SEQ + qr0 + l31) * 3072 + h * 64 + l5 * 8;
  short8 qf[4];
#pragma unroll
  for (int t = 0; t < 4; ++t) qf[t] = *(const short8*)(qrow + t * 16);
  const int srow = tid >> 3, slot = tid & 7;
  const int sw0 = ((slot ^ (srow & 7)) * 8);
  const unsigned short* gK = qkv + (size_t)(b * SEQ + srow) * 3072 + 1024 + h * 64 + slot * 8;
  const unsigned short* gV = vt + ((size_t)(bh * 64) + srow) * SEQ + slot * 8;
  short8 rk0 = *(const short8*)gK;
  short8 rk1 = *(const short8*)(gK + (size_t)32 * 3072);
  short8 rv0 = *(const short8*)gV;
  short8 rv1 = *(const short8*)(gV + (size_t)32 * SEQ);
  *(short8*)&lK[0][srow * 64 + sw0] = rk0;
  *(short8*)&lK[0][(srow + 32) * 64 + sw0] = rk1;
  *(short8*)&lV[0][srow * 64 + sw0] = rv0;
  *(short8*)&lV[0][(srow + 32) * 64 + sw0] = rv1;
  f32x16 o0 = {}, o1 = {};
  float lsum = 0.f;
  constexpr int NT = SEQ / 64;
  for (int t = 0; t < NT; ++t) {
    __syncthreads();
    const unsigned short* Kb = &lK[t & 1][0];
    const unsigned short* Vb = &lV[t & 1][0];
    if (t + 1 < NT) {
      rk0 = *(const short8*)(gK + (size_t)(t + 1) * 64 * 3072);
      rk1 = *(const short8*)(gK + (size_t)((t + 1) * 64 + 32) * 3072);
      rv0 = *(const short8*)(gV + (t + 1) * 64);
      rv1 = *(const short8*)(gV + (size_t)32 * SEQ + (t + 1) * 64);
    }
#pragma unroll
    for (int tile = 0; tile < 2; ++tile) {
      f32x16 s = minit;
      __builtin_amdgcn_s_setprio(1);
#pragma unroll
      for (int td = 0; td < 4; ++td) {
        const int row = tile * 32 + l31;
        const int sl = ((2 * td + l5) ^ (row & 7)) * 8;
        short8 kf = *(const short8*)(Kb + row * 64 + sl);
        s = MFMA32(kf, qf[td], s);
      }
      __builtin_amdgcn_s_setprio(0);
      float p[16];
#pragma unroll
      for (int r = 0; r < 16; ++r) p[r] = exp2_fast(s[r]);
      float q01 = p[0] + p[1], q23 = p[2] + p[3], q45 = p[4] + p[5], q67 = p[6] + p[7];
      float q89 = p[8] + p[9], qab = p[10] + p[11], qcd = p[12] + p[13], qef = p[14] + p[15];
      lsum += ((q01 + q23) + (q45 + q67)) + ((q89 + qab) + (qcd + qef));
      unsigned a0 = cvt_pk_bf16(p[0], p[1]), a1 = cvt_pk_bf16(p[2], p[3]);
      unsigned a2 = cvt_pk_bf16(p[4], p[5]), a3 = cvt_pk_bf16(p[6], p[7]);
      unsigned c0 = cvt_pk_bf16(p[8], p[9]), c1 = cvt_pk_bf16(p[10], p[11]);
      unsigned c2 = cvt_pk_bf16(p[12], p[13]), c3 = cvt_pk_bf16(p[14], p[15]);
      uint2v w0 = __builtin_amdgcn_permlane32_swap(a0, a2, false, false);
      uint2v w1 = __builtin_amdgcn_permlane32_swap(a1, a3, false, false);
      uint2v w2 = __builtin_amdgcn_permlane32_swap(c0, c2, false, false);
      uint2v w3 = __builtin_amdgcn_permlane32_swap(c1, c3, false, false);
      union { unsigned u[4]; short8 v; } f0, f1;
      f0.u[0] = w0.x; f0.u[1] = w1.x; f0.u[2] = w0.y; f0.u[3] = w1.y;
      f1.u[0] = w2.x; f1.u[1] = w3.x; f1.u[2] = w2.y; f1.u[3] = w3.y;
      __builtin_amdgcn_s_setprio(1);
      {
        const int vrow0 = l31, vrow1 = 32 + l31;
        const int sa = ((2 * (tile * 2) + l5) ^ (vrow0 & 7)) * 8;
        const int sb = ((2 * (tile * 2 + 1) + l5) ^ (vrow0 & 7)) * 8;
        short8 va0 = *(const short8*)(Vb + vrow0 * 64 + sa);
        short8 vb0 = *(const short8*)(Vb + vrow0 * 64 + sb);
        short8 va1 = *(const short8*)(Vb + vrow1 * 64 + sa);
        short8 vb1 = *(const short8*)(Vb + vrow1 * 64 + sb);
        o0 = MFMA32(va0, f0.v, o0);
        o0 = MFMA32(vb0, f1.v, o0);
        o1 = MFMA32(va1, f0.v, o1);
        o1 = MFMA32(vb1, f1.v, o1);
      }
      __builtin_amdgcn_s_setprio(0);
    }
    if (t + 1 < NT) {
      *(short8*)&lK[(t + 1) & 1][srow * 64 + sw0] = rk0;
      *(short8*)&lK[(t + 1) & 1][(srow + 32) * 64 + sw0] = rk1;
      *(short8*)&lV[(t + 1) & 1][srow * 64 + sw0] = rv0;
      *(short8*)&lV[(t + 1) & 1][(srow + 32) * 64 + sw0] = rv1;
    }
  }
  lsum += __shfl_xor(lsum, 32);
  const float rinv = 1.0f / lsum;
  unsigned short* orow = out + (size_t)(b * SEQ + qr0 + l31) * D_MODEL + h * 64 + l5 * 4;
#pragma unroll
  for (int rq = 0; rq < 4; ++rq)
#pragma unroll
    for (int rr = 0; rr < 4; rr += 2) {
      *(unsigned*)(orow + rq * 8 + rr) =
          cvt_pk_bf16(o0[rq * 4 + rr] * rinv, o0[rq * 4 + rr + 1] * rinv);
      *(unsigned*)(orow + 32 + rq * 8 + rr) =
          cvt_pk_bf16(o1[rq * 4 + rr] * rinv, o1[rq * 4 + rr + 1] * rinv);
    }
}

// ---------------- host launch ----------------
extern "C" void kernel_launch(void* const* d_in, const int* in_sizes, int n_in, void* d_out,
                              int out_size, void* d_ws, size_t ws_size, hipStream_t stream) {
  const float* x = (const float*)d_in[0];
  const float* w_qkv = (const float*)d_in[1];
  const float* w_out = (const float*)d_in[2];
  const float* w_ffn1 = (const float*)d_in[3];
  const float* w_ffn2 = (const float*)d_in[4];
  const float* g1 = (const float*)d_in[5];
  const float* b1 = (const float*)d_in[6];
  const float* g2 = (const float*)d_in[7];
  const float* b2 = (const float*)d_in[8];
  const float* temp = (const float*)d_in[9];
  float* outp = (float*)d_out;

  char* ws = (char*)d_ws;
  size_t off = 0;
  auto alloc = [&](size_t bytes) {
    void* p = ws + off;
    off += (bytes + 255) & ~(size_t)255;
    return p;
  };
  unsigned short* wqkv_bf = (unsigned short*)alloc((size_t)3072 * 1024 * 2);
  unsigned short* wout_bf = (unsigned short*)alloc((size_t)1024 * 1024 * 2);
  unsigned short* wf1_bf = (unsigned short*)alloc((size_t)2048 * 1024 * 2);
  unsigned short* wf2_bf = (unsigned short*)alloc((size_t)1024 * 2048 * 2);
  unsigned short* h_bf = (unsigned short*)alloc((size_t)MTOK * 1024 * 2);   // reused for h2
  unsigned short* qkv_bf = (unsigned short*)alloc((size_t)MTOK * 3072 * 2); // reused for ffn1 out
  unsigned short* vt_bf = (unsigned short*)alloc((size_t)BATCH * NHEADS * DHEAD * SEQ * 2);
  unsigned short* ao_bf = (unsigned short*)alloc((size_t)MTOK * 1024 * 2);
  unsigned short* x2_bf = (unsigned short*)alloc((size_t)MTOK * 1024 * 2);  // bf16 residual

  // weight conversions (single launch)
  f32_to_bf16_all<<<8192, 256, 0, stream>>>(w_qkv, w_out, w_ffn1, w_ffn2, wqkv_bf, wout_bf, wf1_bf,
                                            wf2_bf);
  // LN1
  ln_fwd<<<MTOK, 256, 0, stream>>>(x, g1, b1, h_bf);
  // qkv = h @ w_qkv^T with fused per-head l2norm of q (x log2e/T) and k
  gemm_bt2<3><<<dim3(3072 / 128, MTOK / 128), 256, 0, stream>>>(h_bf, wqkv_bf, nullptr, temp,
                                                                (void*)qkv_bf, MTOK, 3072, 1024);
  // build Vt
  transpose_v<<<BATCH * NHEADS * (SEQ / 64), 256, 0, stream>>>(qkv_bf, vt_bf);
  // attention (32x32 MFMA, in-register P, raw v_exp, XCD-local mapping)
  attn_fwd9<<<BATCH * NHEADS * (SEQ / 128), 256, 0, stream>>>(qkv_bf, vt_bf, ao_bf, temp);
  // x2 = x + attn_out @ w_out^T  (stored bf16)
  gemm_bt2<4><<<dim3(1024 / 128, MTOK / 128), 256, 0, stream>>>(ao_bf, wout_bf, x, nullptr,
                                                                (void*)x2_bf, MTOK, 1024, 1024);
  // LN2 (bf16 input)
  ln_fwd_b<<<MTOK, 256, 0, stream>>>(x2_bf, g2, b2, h_bf);
  // ffn1 = relu(h2 @ w_ffn1^T)  (reuse qkv buffer)
  gemm_bt2<2><<<dim3(2048 / 128, MTOK / 128), 256, 0, stream>>>(h_bf, wf1_bf, nullptr, nullptr,
                                                                (void*)qkv_bf, MTOK, 2048, 1024);
  // out = x2 + ffn1 @ w_ffn2^T  (bf16 residual read, fp32 out)
  gemm_bt2<5><<<dim3(1024 / 128, MTOK / 128), 256, 0, stream>>>(qkv_bf, wf2_bf,
                                                                (const float*)x2_bf, nullptr,
                                                                (void*)outp, MTOK, 1024, 2048);
}

// Round 15
// 319.585 us; speedup vs baseline: 1.2179x; 1.0018x over previous
//
#include <hip/hip_runtime.h>
#include <cstdint>
#include <cstddef>
#include <math.h>

typedef __attribute__((ext_vector_type(8))) short short8;
typedef __attribute__((ext_vector_type(4))) float f32x4;
typedef __attribute__((ext_vector_type(16))) float f32x16;
typedef __attribute__((ext_vector_type(2))) unsigned uint2v;

#define D_MODEL 1024
#define NHEADS 16
#define DHEAD 64
#define BATCH 4
#define SEQ 2048
#define MTOK (BATCH * SEQ)

__device__ __forceinline__ unsigned short f2bf(float f) {
  union { float f; unsigned u; } v; v.f = f;
  unsigned r = v.u + 0x7fffu + ((v.u >> 16) & 1u);
  return (unsigned short)(r >> 16);
}
__device__ __forceinline__ float bf2f(unsigned short u) {
  union { unsigned u; float f; } v; v.u = ((unsigned)u) << 16;
  return v.f;
}
__device__ __forceinline__ unsigned cvt_pk_bf16(float a, float b) {
  unsigned u;
  asm("v_cvt_pk_bf16_f32 %0, %1, %2" : "=v"(u) : "v"(a), "v"(b));
  return u;
}
// raw v_exp_f32 (2^x). Safe for x in [-126, 127]; our args are in [-62, 0].
__device__ __forceinline__ float exp2_fast(float x) {
  float r;
  asm("v_exp_f32 %0, %1" : "=v"(r) : "v"(x));
  return r;
}

typedef const __attribute__((address_space(1))) unsigned int* gas1_t;
typedef __attribute__((address_space(3))) unsigned int* las3_t;
// async global->LDS, 16B per lane; LDS dest must be wave-uniform base (HW adds lane*16B)
__device__ __forceinline__ void gload16(const unsigned short* g, unsigned short* l) {
  __builtin_amdgcn_global_load_lds((gas1_t)g, (las3_t)l, 16, 0, 0);
}

#define MFMA_BF16(a, b, c) __builtin_amdgcn_mfma_f32_16x16x32_bf16(a, b, c, 0, 0, 0)
#define MFMA32(a, b, c) __builtin_amdgcn_mfma_f32_32x32x16_bf16(a, b, c, 0, 0, 0)

// ---------------- fp32 -> bf16 conversion, all 4 weights in one launch ----------------
__global__ __launch_bounds__(256) void f32_to_bf16_all(const float* __restrict__ s0,
                                                       const float* __restrict__ s1,
                                                       const float* __restrict__ s2,
                                                       const float* __restrict__ s3,
                                                       unsigned short* __restrict__ d0,
                                                       unsigned short* __restrict__ d1,
                                                       unsigned short* __restrict__ d2,
                                                       unsigned short* __restrict__ d3) {
  int j = blockIdx.x * 256 + threadIdx.x;  // float4 index over concatenated ranges
  const float* s;
  unsigned short* d;
  if (j < 786432) { s = s0; d = d0; }
  else if ((j -= 786432) < 262144) { s = s1; d = d1; }
  else if ((j -= 262144) < 524288) { s = s2; d = d2; }
  else { j -= 524288; s = s3; d = d3; }
  float4 v = ((const float4*)s)[j];
  ushort4 o;
  o.x = f2bf(v.x); o.y = f2bf(v.y); o.z = f2bf(v.z); o.w = f2bf(v.w);
  ((ushort4*)d)[j] = o;
}

// ---------------- LayerNorm: fp32 in -> bf16 out ----------------
__global__ __launch_bounds__(256) void ln_fwd(const float* __restrict__ x, const float* __restrict__ g,
                                              const float* __restrict__ b,
                                              unsigned short* __restrict__ out) {
  const int row = blockIdx.x, t = threadIdx.x;
  float4 v = *(const float4*)(x + (size_t)row * D_MODEL + t * 4);
  float s = v.x + v.y + v.z + v.w;
  float s2 = v.x * v.x + v.y * v.y + v.z * v.z + v.w * v.w;
#pragma unroll
  for (int m = 1; m < 64; m <<= 1) { s += __shfl_xor(s, m); s2 += __shfl_xor(s2, m); }
  __shared__ float red[8];
  int wv = t >> 6;
  if ((t & 63) == 0) { red[wv] = s; red[4 + wv] = s2; }
  __syncthreads();
  s = red[0] + red[1] + red[2] + red[3];
  s2 = red[4] + red[5] + red[6] + red[7];
  float mu = s * (1.f / D_MODEL);
  float var = s2 * (1.f / D_MODEL) - mu * mu;
  float rs = rsqrtf(var + 1e-5f);
  float4 gg = *(const float4*)(g + t * 4);
  float4 bb = *(const float4*)(b + t * 4);
  ushort4 o;
  o.x = f2bf((v.x - mu) * rs * gg.x + bb.x);
  o.y = f2bf((v.y - mu) * rs * gg.y + bb.y);
  o.z = f2bf((v.z - mu) * rs * gg.z + bb.z);
  o.w = f2bf((v.w - mu) * rs * gg.w + bb.w);
  *(ushort4*)(out + (size_t)row * D_MODEL + t * 4) = o;
}

// ---------------- LayerNorm: bf16 in -> bf16 out ----------------
__global__ __launch_bounds__(256) void ln_fwd_b(const unsigned short* __restrict__ x,
                                                const float* __restrict__ g,
                                                const float* __restrict__ b,
                                                unsigned short* __restrict__ out) {
  const int row = blockIdx.x, t = threadIdx.x;
  ushort4 vi = *(const ushort4*)(x + (size_t)row * D_MODEL + t * 4);
  float f0 = bf2f(vi.x), f1 = bf2f(vi.y), f2 = bf2f(vi.z), f3 = bf2f(vi.w);
  float s = f0 + f1 + f2 + f3;
  float s2 = f0 * f0 + f1 * f1 + f2 * f2 + f3 * f3;
#pragma unroll
  for (int m = 1; m < 64; m <<= 1) { s += __shfl_xor(s, m); s2 += __shfl_xor(s2, m); }
  __shared__ float red[8];
  int wv = t >> 6;
  if ((t & 63) == 0) { red[wv] = s; red[4 + wv] = s2; }
  __syncthreads();
  s = red[0] + red[1] + red[2] + red[3];
  s2 = red[4] + red[5] + red[6] + red[7];
  float mu = s * (1.f / D_MODEL);
  float var = s2 * (1.f / D_MODEL) - mu * mu;
  float rs = rsqrtf(var + 1e-5f);
  float4 gg = *(const float4*)(g + t * 4);
  float4 bb = *(const float4*)(b + t * 4);
  ushort4 o;
  o.x = f2bf((f0 - mu) * rs * gg.x + bb.x);
  o.y = f2bf((f1 - mu) * rs * gg.y + bb.y);
  o.z = f2bf((f2 - mu) * rs * gg.z + bb.z);
  o.w = f2bf((f3 - mu) * rs * gg.w + bb.w);
  *(ushort4*)(out + (size_t)row * D_MODEL + t * 4) = o;
}

// ---------------- GEMM (m97 structure, proven): C[M,N] = A[M,K] * B[N,K]^T ----------------
// XCD-chunked block swizzle. EPI: 0 bf16, 1 fp32 R+acc, 2 bf16 relu(acc),
// 3 qkv-fused per-head l2norm (q also x log2e/T), 4 bf16 store of (R_f32 + acc),
// 5 fp32 store of (R_bf16 + acc)  [R passed as bf16 buffer cast to float*].
template <int EPI>
__global__ __launch_bounds__(256) void gemm_bt2(const unsigned short* __restrict__ A,
                                                const unsigned short* __restrict__ B,
                                                const float* __restrict__ R,
                                                const float* __restrict__ Tptr,
                                                void* __restrict__ Cout, int M, int N, int K) {
  constexpr int BM = 128, BN = 128, BK = 32;
  __shared__ unsigned short lA[2][BM * BK], lB[2][BN * BK];
  const int tid = threadIdx.x, lane = tid & 63, wave = tid >> 6;
  const int lo = lane & 15, g = lane >> 4;
  const int nbx = gridDim.x;
  const int o = blockIdx.y * nbx + blockIdx.x;
  const int cpx = (nbx * gridDim.y) >> 3;
  const int w = (o & 7) * cpx + (o >> 3);
  const int bx = w % nbx, by = w / nbx;
  const int bm = by * BM, bn = bx * BN;
  const int wr = wave >> 1, wc = wave & 1;
  f32x4 acc[4][4] = {};
  const int c0 = wave * 128 + lane, c1 = c0 + 64;
  const unsigned short* gA0 = A + (size_t)(bm + (c0 >> 2)) * K + (c0 & 3) * 8;
  const unsigned short* gA1 = A + (size_t)(bm + (c1 >> 2)) * K + (c1 & 3) * 8;
  const unsigned short* gB0 = B + (size_t)(bn + (c0 >> 2)) * K + (c0 & 3) * 8;
  const unsigned short* gB1 = B + (size_t)(bn + (c1 >> 2)) * K + (c1 & 3) * 8;
  const int nk = K / BK;
  auto stage = [&](int buf, int kt) {
    const size_t ko = (size_t)kt * BK;
    gload16(gA0 + ko, &lA[buf][(wave * 128) * 8]);
    gload16(gA1 + ko, &lA[buf][(wave * 128 + 64) * 8]);
    gload16(gB0 + ko, &lB[buf][(wave * 128) * 8]);
    gload16(gB1 + ko, &lB[buf][(wave * 128 + 64) * 8]);
  };
  stage(0, 0);
  for (int kt = 0; kt < nk; ++kt) {
    __syncthreads();
    if (kt + 1 < nk) stage((kt + 1) & 1, kt + 1);
    const unsigned short* La = &lA[kt & 1][0];
    const unsigned short* Lb = &lB[kt & 1][0];
    short8 af[4], bfr[4];
#pragma unroll
    for (int m = 0; m < 4; ++m)
      af[m] = *(const short8*)(La + (wr * 64 + m * 16 + lo) * BK + g * 8);
#pragma unroll
    for (int n = 0; n < 4; ++n)
      bfr[n] = *(const short8*)(Lb + (wc * 64 + n * 16 + lo) * BK + g * 8);
#pragma unroll
    for (int m = 0; m < 4; ++m)
#pragma unroll
      for (int n = 0; n < 4; ++n) acc[m][n] = MFMA_BF16(af[m], bfr[n], acc[m][n]);
  }
  const int r0 = bm + wr * 64 + g * 4;
  const int c0c = bn + wc * 64 + lo;
  if (EPI == 3) {
    // this wave's 64 output columns are exactly one head-slice of q, k, or v
    const int hb = bn + wc * 64;
    const bool isq = hb < 1024, isk = (hb >= 1024) && (hb < 2048);
    const float qs = 1.44269504088896f / Tptr[0];  // log2(e)/T folded into q
#pragma unroll
    for (int m = 0; m < 4; ++m)
#pragma unroll
      for (int r = 0; r < 4; ++r) {
        float sc = 1.0f;
        if (isq || isk) {
          float ss = 0.f;
#pragma unroll
          for (int n = 0; n < 4; ++n) ss += acc[m][n][r] * acc[m][n][r];
          ss += __shfl_xor(ss, 1);
          ss += __shfl_xor(ss, 2);
          ss += __shfl_xor(ss, 4);
          ss += __shfl_xor(ss, 8);  // full head-dim sum across the 16 lo-lanes
          sc = 1.0f / fmaxf(sqrtf(ss), 1e-12f);
          if (isq) sc *= qs;
        }
#pragma unroll
        for (int n = 0; n < 4; ++n) {
          size_t off = (size_t)(r0 + m * 16 + r) * N + (c0c + n * 16);
          ((unsigned short*)Cout)[off] = f2bf(acc[m][n][r] * sc);
        }
      }
  } else {
#pragma unroll
    for (int m = 0; m < 4; ++m)
#pragma unroll
      for (int n = 0; n < 4; ++n) {
#pragma unroll
        for (int r = 0; r < 4; ++r) {
          size_t off = (size_t)(r0 + m * 16 + r) * N + (c0c + n * 16);
          float v = acc[m][n][r];
          if (EPI == 0) ((unsigned short*)Cout)[off] = f2bf(v);
          else if (EPI == 1) ((float*)Cout)[off] = R[off] + v;
          else if (EPI == 2) ((unsigned short*)Cout)[off] = f2bf(fmaxf(v, 0.f));
          else if (EPI == 4) ((unsigned short*)Cout)[off] = f2bf(R[off] + v);
          else /* EPI == 5 */ ((float*)Cout)[off] = bf2f(((const unsigned short*)R)[off]) + v;
        }
      }
  }
}

// ---------------- transpose v -> Vt[b,h,d,n] ----------------
__global__ __launch_bounds__(256) void transpose_v(const unsigned short* __restrict__ qkv,
                                                   unsigned short* __restrict__ vt) {
  __shared__ unsigned short tile[64][80];
  const int blk = blockIdx.x;
  const int ntile = blk & 31, h = (blk >> 5) & 15, b = blk >> 9;
  const int t = threadIdx.x;
  const int tt = t >> 2, c4 = t & 3;
  size_t rowbase = (size_t)(b * SEQ + ntile * 64 + tt) * 3072 + h * 64 + c4 * 16;
  const unsigned short* pv = qkv + rowbase + 2048;
  *(short8*)&tile[tt][c4 * 16] = *(const short8*)pv;
  *(short8*)&tile[tt][c4 * 16 + 8] = *(const short8*)(pv + 8);
  __syncthreads();
  const int d = tt;
  short8 o0, o1;
#pragma unroll
  for (int j = 0; j < 8; ++j) o0[j] = (short)tile[c4 * 16 + j][d];
#pragma unroll
  for (int j = 0; j < 8; ++j) o1[j] = (short)tile[c4 * 16 + 8 + j][d];
  size_t vr = (size_t)((b * NHEADS + h) * DHEAD + d) * SEQ + ntile * 64 + c4 * 16;
  *(short8*)(vt + vr) = o0;
  *(short8*)(vt + vr + 8) = o1;
}

// ---------------- flash attention v9: 32x32 MFMA, in-register P, raw v_exp_f32 ----------------
// Swapped mfma(K,Q): lane holds S[k][q=lane&31]. Static-max via C-init=-M0 (cosine bound).
// P -> bf16 (cvt_pk) -> permlane32_swap builds PV B-frags in registers (no P LDS).
// exp2 via raw v_exp_f32 (args in [-62,0]); P-sum as a balanced tree (no ordered chain).
__global__ __launch_bounds__(256) void attn_fwd9(const unsigned short* __restrict__ qkv,
                                                 const unsigned short* __restrict__ vt,
                                                 unsigned short* __restrict__ out,
                                                 const float* __restrict__ temp) {
  __shared__ unsigned short lK[2][64 * 64];
  __shared__ unsigned short lV[2][64 * 64];
  const int blk = blockIdx.x;
  const int bh = blk & 63, qt = blk >> 6;
  const int b = bh >> 4, h = bh & 15;
  const int tid = threadIdx.x, lane = tid & 63, wave = tid >> 6;
  const int l5 = lane >> 5, l31 = lane & 31;
  const int qr0 = qt * 128 + wave * 32;
  const float M0 = 1.05f * 1.44269504088896f / temp[0];  // bound on folded scores
  f32x16 minit;
#pragma unroll
  for (int r = 0; r < 16; ++r) minit[r] = -M0;
  const unsigned short* qrow = qkv + (size_t)(b * SEQ + qr0 + l31) * 3072 + h * 64 + l5 * 8;
  short8 qf[4];
#pragma unroll
  for (int t = 0; t < 4; ++t) qf[t] = *(const short8*)(qrow + t * 16);
  const int srow = tid >> 3, slot = tid & 7;
  const int sw0 = ((slot ^ (srow & 7)) * 8);
  const unsigned short* gK = qkv + (size_t)(b * SEQ + srow) * 3072 + 1024 + h * 64 + slot * 8;
  const unsigned short* gV = vt + ((size_t)(bh * 64) + srow) * SEQ + slot * 8;
  short8 rk0 = *(const short8*)gK;
  short8 rk1 = *(const short8*)(gK + (size_t)32 * 3072);
  short8 rv0 = *(const short8*)gV;
  short8 rv1 = *(const short8*)(gV + (size_t)32 * SEQ);
  *(short8*)&lK[0][srow * 64 + sw0] = rk0;
  *(short8*)&lK[0][(srow + 32) * 64 + sw0] = rk1;
  *(short8*)&lV[0][srow * 64 + sw0] = rv0;
  *(short8*)&lV[0][(srow + 32) * 64 + sw0] = rv1;
  f32x16 o0 = {}, o1 = {};
  float lsum = 0.f;
  constexpr int NT = SEQ / 64;
  for (int t = 0; t < NT; ++t) {
    __syncthreads();
    const unsigned short* Kb = &lK[t & 1][0];
    const unsigned short* Vb = &lV[t & 1][0];
    if (t + 1 < NT) {
      rk0 = *(const short8*)(gK + (size_t)(t + 1) * 64 * 3072);
      rk1 = *(const short8*)(gK + (size_t)((t + 1) * 64 + 32) * 3072);
      rv0 = *(const short8*)(gV + (t + 1) * 64);
      rv1 = *(const short8*)(gV + (size_t)32 * SEQ + (t + 1) * 64);
    }
#pragma unroll
    for (int tile = 0; tile < 2; ++tile) {
      f32x16 s = minit;
      __builtin_amdgcn_s_setprio(1);
#pragma unroll
      for (int td = 0; td < 4; ++td) {
        const int row = tile * 32 + l31;
        const int sl = ((2 * td + l5) ^ (row & 7)) * 8;
        short8 kf = *(const short8*)(Kb + row * 64 + sl);
        s = MFMA32(kf, qf[td], s);
      }
      __builtin_amdgcn_s_setprio(0);
      float p[16];
#pragma unroll
      for (int r = 0; r < 16; ++r) p[r] = exp2_fast(s[r]);
      float q01 = p[0] + p[1], q23 = p[2] + p[3], q45 = p[4] + p[5], q67 = p[6] + p[7];
      float q89 = p[8] + p[9], qab = p[10] + p[11], qcd = p[12] + p[13], qef = p[14] + p[15];
      lsum += ((q01 + q23) + (q45 + q67)) + ((q89 + qab) + (qcd + qef));
      unsigned a0 = cvt_pk_bf16(p[0], p[1]), a1 = cvt_pk_bf16(p[2], p[3]);
      unsigned a2 = cvt_pk_bf16(p[4], p[5]), a3 = cvt_pk_bf16(p[6], p[7]);
      unsigned c0 = cvt_pk_bf16(p[8], p[9]), c1 = cvt_pk_bf16(p[10], p[11]);
      unsigned c2 = cvt_pk_bf16(p[12], p[13]), c3 = cvt_pk_bf16(p[14], p[15]);
      uint2v w0 = __builtin_amdgcn_permlane32_swap(a0, a2, false, false);
      uint2v w1 = __builtin_amdgcn_permlane32_swap(a1, a3, false, false);
      uint2v w2 = __builtin_amdgcn_permlane32_swap(c0, c2, false, false);
      uint2v w3 = __builtin_amdgcn_permlane32_swap(c1, c3, false, false);
      union { unsigned u[4]; short8 v; } f0, f1;
      f0.u[0] = w0.x; f0.u[1] = w1.x; f0.u[2] = w0.y; f0.u[3] = w1.y;
      f1.u[0] = w2.x; f1.u[1] = w3.x; f1.u[2] = w2.y; f1.u[3] = w3.y;
      __builtin_amdgcn_s_setprio(1);
      {
        const int vrow0 = l31, vrow1 = 32 + l31;
        const int sa = ((2 * (tile * 2) + l5) ^ (vrow0 & 7)) * 8;
        const int sb = ((2 * (tile * 2 + 1) + l5) ^ (vrow0 & 7)) * 8;
        short8 va0 = *(const short8*)(Vb + vrow0 * 64 + sa);
        short8 vb0 = *(const short8*)(Vb + vrow0 * 64 + sb);
        short8 va1 = *(const short8*)(Vb + vrow1 * 64 + sa);
        short8 vb1 = *(const short8*)(Vb + vrow1 * 64 + sb);
        o0 = MFMA32(va0, f0.v, o0);
        o0 = MFMA32(vb0, f1.v, o0);
        o1 = MFMA32(va1, f0.v, o1);
        o1 = MFMA32(vb1, f1.v, o1);
      }
      __builtin_amdgcn_s_setprio(0);
    }
    if (t + 1 < NT) {
      *(short8*)&lK[(t + 1) & 1][srow * 64 + sw0] = rk0;
      *(short8*)&lK[(t + 1) & 1][(srow + 32) * 64 + sw0] = rk1;
      *(short8*)&lV[(t + 1) & 1][srow * 64 + sw0] = rv0;
      *(short8*)&lV[(t + 1) & 1][(srow + 32) * 64 + sw0] = rv1;
    }
  }
  lsum += __shfl_xor(lsum, 32);
  const float rinv = 1.0f / lsum;
  unsigned short* orow = out + (size_t)(b * SEQ + qr0 + l31) * D_MODEL + h * 64 + l5 * 4;
#pragma unroll
  for (int rq = 0; rq < 4; ++rq)
#pragma unroll
    for (int rr = 0; rr < 4; rr += 2) {
      *(unsigned*)(orow + rq * 8 + rr) =
          cvt_pk_bf16(o0[rq * 4 + rr] * rinv, o0[rq * 4 + rr + 1] * rinv);
      *(unsigned*)(orow + 32 + rq * 8 + rr) =
          cvt_pk_bf16(o1[rq * 4 + rr] * rinv, o1[rq * 4 + rr + 1] * rinv);
    }
}

// ---------------- host launch ----------------
extern "C" void kernel_launch(void* const* d_in, const int* in_sizes, int n_in, void* d_out,
                              int out_size, void* d_ws, size_t ws_size, hipStream_t stream) {
  const float* x = (const float*)d_in[0];
  const float* w_qkv = (const float*)d_in[1];
  const float* w_out = (const float*)d_in[2];
  const float* w_ffn1 = (const float*)d_in[3];
  const float* w_ffn2 = (const float*)d_in[4];
  const float* g1 = (const float*)d_in[5];
  const float* b1 = (const float*)d_in[6];
  const float* g2 = (const float*)d_in[7];
  const float* b2 = (const float*)d_in[8];
  const float* temp = (const float*)d_in[9];
  float* outp = (float*)d_out;

  char* ws = (char*)d_ws;
  size_t off = 0;
  auto alloc = [&](size_t bytes) {
    void* p = ws + off;
    off += (bytes + 255) & ~(size_t)255;
    return p;
  };
  unsigned short* wqkv_bf = (unsigned short*)alloc((size_t)3072 * 1024 * 2);
  unsigned short* wout_bf = (unsigned short*)alloc((size_t)1024 * 1024 * 2);
  unsigned short* wf1_bf = (unsigned short*)alloc((size_t)2048 * 1024 * 2);
  unsigned short* wf2_bf = (unsigned short*)alloc((size_t)1024 * 2048 * 2);
  unsigned short* h_bf = (unsigned short*)alloc((size_t)MTOK * 1024 * 2);   // reused for h2
  unsigned short* qkv_bf = (unsigned short*)alloc((size_t)MTOK * 3072 * 2); // reused for ffn1 out
  unsigned short* vt_bf = (unsigned short*)alloc((size_t)BATCH * NHEADS * DHEAD * SEQ * 2);
  unsigned short* ao_bf = (unsigned short*)alloc((size_t)MTOK * 1024 * 2);
  unsigned short* x2_bf = (unsigned short*)alloc((size_t)MTOK * 1024 * 2);  // bf16 residual

  // weight conversions (single launch)
  f32_to_bf16_all<<<8192, 256, 0, stream>>>(w_qkv, w_out, w_ffn1, w_ffn2, wqkv_bf, wout_bf, wf1_bf,
                                            wf2_bf);
  // LN1
  ln_fwd<<<MTOK, 256, 0, stream>>>(x, g1, b1, h_bf);
  // qkv = h @ w_qkv^T with fused per-head l2norm of q (x log2e/T) and k
  gemm_bt2<3><<<dim3(3072 / 128, MTOK / 128), 256, 0, stream>>>(h_bf, wqkv_bf, nullptr, temp,
                                                                (void*)qkv_bf, MTOK, 3072, 1024);
  // build Vt
  transpose_v<<<BATCH * NHEADS * (SEQ / 64), 256, 0, stream>>>(qkv_bf, vt_bf);
  // attention (32x32 MFMA, in-register P, raw v_exp, XCD-local mapping)
  attn_fwd9<<<BATCH * NHEADS * (SEQ / 128), 256, 0, stream>>>(qkv_bf, vt_bf, ao_bf, temp);
  // x2 = x + attn_out @ w_out^T  (stored bf16)
  gemm_bt2<4><<<dim3(1024 / 128, MTOK / 128), 256, 0, stream>>>(ao_bf, wout_bf, x, nullptr,
                                                                (void*)x2_bf, MTOK, 1024, 1024);
  // LN2 (bf16 input)
  ln_fwd_b<<<MTOK, 256, 0, stream>>>(x2_bf, g2, b2, h_bf);
  // ffn1 = relu(h2 @ w_ffn1^T)  (reuse qkv buffer)
  gemm_bt2<2><<<dim3(2048 / 128, MTOK / 128), 256, 0, stream>>>(h_bf, wf1_bf, nullptr, nullptr,
                                                                (void*)qkv_bf, MTOK, 2048, 1024);
  // out = x2 + ffn1 @ w_ffn2^T  (bf16 residual read, fp32 out)
  gemm_bt2<5><<<dim3(1024 / 128, MTOK / 128), 256, 0, stream>>>(qkv_bf, wf2_bf,
                                                                (const float*)x2_bf, nullptr,
                                                                (void*)outp, MTOK, 1024, 2048);
}

// Round 16
// 309.433 us; speedup vs baseline: 1.2579x; 1.0328x over previous
//
#include <hip/hip_runtime.h>
#include <cstdint>
#include <cstddef>
#include <math.h>

typedef __attribute__((ext_vector_type(8))) short short8;
typedef __attribute__((ext_vector_type(4))) float f32x4;
typedef __attribute__((ext_vector_type(16))) float f32x16;
typedef __attribute__((ext_vector_type(2))) unsigned uint2v;

#define D_MODEL 1024
#define NHEADS 16
#define DHEAD 64
#define BATCH 4
#define SEQ 2048
#define MTOK (BATCH * SEQ)

__device__ __forceinline__ unsigned short f2bf(float f) {
  union { float f; unsigned u; } v; v.f = f;
  unsigned r = v.u + 0x7fffu + ((v.u >> 16) & 1u);
  return (unsigned short)(r >> 16);
}
__device__ __forceinline__ float bf2f(unsigned short u) {
  union { unsigned u; float f; } v; v.u = ((unsigned)u) << 16;
  return v.f;
}
__device__ __forceinline__ unsigned cvt_pk_bf16(float a, float b) {
  unsigned u;
  asm("v_cvt_pk_bf16_f32 %0, %1, %2" : "=v"(u) : "v"(a), "v"(b));
  return u;
}
// raw v_exp_f32 (2^x). Safe for x in [-126, 127]; our args are in [-62, 0].
__device__ __forceinline__ float exp2_fast(float x) {
  float r;
  asm("v_exp_f32 %0, %1" : "=v"(r) : "v"(x));
  return r;
}

typedef const __attribute__((address_space(1))) unsigned int* gas1_t;
typedef __attribute__((address_space(3))) unsigned int* las3_t;
// async global->LDS, 16B per lane; LDS dest must be wave-uniform base (HW adds lane*16B)
__device__ __forceinline__ void gload16(const unsigned short* g, unsigned short* l) {
  __builtin_amdgcn_global_load_lds((gas1_t)g, (las3_t)l, 16, 0, 0);
}

#define MFMA_BF16(a, b, c) __builtin_amdgcn_mfma_f32_16x16x32_bf16(a, b, c, 0, 0, 0)
#define MFMA32(a, b, c) __builtin_amdgcn_mfma_f32_32x32x16_bf16(a, b, c, 0, 0, 0)

// ---------------- fp32 -> bf16 conversion, all 4 weights in one launch ----------------
__global__ __launch_bounds__(256) void f32_to_bf16_all(const float* __restrict__ s0,
                                                       const float* __restrict__ s1,
                                                       const float* __restrict__ s2,
                                                       const float* __restrict__ s3,
                                                       unsigned short* __restrict__ d0,
                                                       unsigned short* __restrict__ d1,
                                                       unsigned short* __restrict__ d2,
                                                       unsigned short* __restrict__ d3) {
  int j = blockIdx.x * 256 + threadIdx.x;  // float4 index over concatenated ranges
  const float* s;
  unsigned short* d;
  if (j < 786432) { s = s0; d = d0; }
  else if ((j -= 786432) < 262144) { s = s1; d = d1; }
  else if ((j -= 262144) < 524288) { s = s2; d = d2; }
  else { j -= 524288; s = s3; d = d3; }
  float4 v = ((const float4*)s)[j];
  ushort4 o;
  o.x = f2bf(v.x); o.y = f2bf(v.y); o.z = f2bf(v.z); o.w = f2bf(v.w);
  ((ushort4*)d)[j] = o;
}

// ---------------- LayerNorm: fp32 in -> bf16 out ----------------
__global__ __launch_bounds__(256) void ln_fwd(const float* __restrict__ x, const float* __restrict__ g,
                                              const float* __restrict__ b,
                                              unsigned short* __restrict__ out) {
  const int row = blockIdx.x, t = threadIdx.x;
  float4 v = *(const float4*)(x + (size_t)row * D_MODEL + t * 4);
  float s = v.x + v.y + v.z + v.w;
  float s2 = v.x * v.x + v.y * v.y + v.z * v.z + v.w * v.w;
#pragma unroll
  for (int m = 1; m < 64; m <<= 1) { s += __shfl_xor(s, m); s2 += __shfl_xor(s2, m); }
  __shared__ float red[8];
  int wv = t >> 6;
  if ((t & 63) == 0) { red[wv] = s; red[4 + wv] = s2; }
  __syncthreads();
  s = red[0] + red[1] + red[2] + red[3];
  s2 = red[4] + red[5] + red[6] + red[7];
  float mu = s * (1.f / D_MODEL);
  float var = s2 * (1.f / D_MODEL) - mu * mu;
  float rs = rsqrtf(var + 1e-5f);
  float4 gg = *(const float4*)(g + t * 4);
  float4 bb = *(const float4*)(b + t * 4);
  ushort4 o;
  o.x = f2bf((v.x - mu) * rs * gg.x + bb.x);
  o.y = f2bf((v.y - mu) * rs * gg.y + bb.y);
  o.z = f2bf((v.z - mu) * rs * gg.z + bb.z);
  o.w = f2bf((v.w - mu) * rs * gg.w + bb.w);
  *(ushort4*)(out + (size_t)row * D_MODEL + t * 4) = o;
}

// ---------------- LayerNorm: bf16 in -> bf16 out ----------------
__global__ __launch_bounds__(256) void ln_fwd_b(const unsigned short* __restrict__ x,
                                                const float* __restrict__ g,
                                                const float* __restrict__ b,
                                                unsigned short* __restrict__ out) {
  const int row = blockIdx.x, t = threadIdx.x;
  ushort4 vi = *(const ushort4*)(x + (size_t)row * D_MODEL + t * 4);
  float f0 = bf2f(vi.x), f1 = bf2f(vi.y), f2 = bf2f(vi.z), f3 = bf2f(vi.w);
  float s = f0 + f1 + f2 + f3;
  float s2 = f0 * f0 + f1 * f1 + f2 * f2 + f3 * f3;
#pragma unroll
  for (int m = 1; m < 64; m <<= 1) { s += __shfl_xor(s, m); s2 += __shfl_xor(s2, m); }
  __shared__ float red[8];
  int wv = t >> 6;
  if ((t & 63) == 0) { red[wv] = s; red[4 + wv] = s2; }
  __syncthreads();
  s = red[0] + red[1] + red[2] + red[3];
  s2 = red[4] + red[5] + red[6] + red[7];
  float mu = s * (1.f / D_MODEL);
  float var = s2 * (1.f / D_MODEL) - mu * mu;
  float rs = rsqrtf(var + 1e-5f);
  float4 gg = *(const float4*)(g + t * 4);
  float4 bb = *(const float4*)(b + t * 4);
  ushort4 o;
  o.x = f2bf((f0 - mu) * rs * gg.x + bb.x);
  o.y = f2bf((f1 - mu) * rs * gg.y + bb.y);
  o.z = f2bf((f2 - mu) * rs * gg.z + bb.z);
  o.w = f2bf((f3 - mu) * rs * gg.w + bb.w);
  *(ushort4*)(out + (size_t)row * D_MODEL + t * 4) = o;
}

// ---------------- GEMM (m97 structure, proven): C[M,N] = A[M,K] * B[N,K]^T ----------------
// XCD-chunked block swizzle. EPI: 0 bf16, 1 fp32 R+acc, 2 bf16 relu(acc),
// 3 qkv-fused: per-head l2norm of q,k (q also x log2e/T); v written TRANSPOSED into VT
//   (vt[(b*16+h)*64 + d][tok], replacing the old transpose_v pass); 4 bf16 (R_f32+acc);
// 5 fp32 store of (R_bf16 + acc)  [R passed as bf16 buffer cast to float*].
template <int EPI>
__global__ __launch_bounds__(256) void gemm_bt2(const unsigned short* __restrict__ A,
                                                const unsigned short* __restrict__ B,
                                                const float* __restrict__ R,
                                                const float* __restrict__ Tptr,
                                                unsigned short* __restrict__ VT,
                                                void* __restrict__ Cout, int M, int N, int K) {
  constexpr int BM = 128, BN = 128, BK = 32;
  __shared__ unsigned short lA[2][BM * BK], lB[2][BN * BK];
  const int tid = threadIdx.x, lane = tid & 63, wave = tid >> 6;
  const int lo = lane & 15, g = lane >> 4;
  const int nbx = gridDim.x;
  const int o = blockIdx.y * nbx + blockIdx.x;
  const int cpx = (nbx * gridDim.y) >> 3;
  const int w = (o & 7) * cpx + (o >> 3);
  const int bx = w % nbx, by = w / nbx;
  const int bm = by * BM, bn = bx * BN;
  const int wr = wave >> 1, wc = wave & 1;
  f32x4 acc[4][4] = {};
  const int c0 = wave * 128 + lane, c1 = c0 + 64;
  const unsigned short* gA0 = A + (size_t)(bm + (c0 >> 2)) * K + (c0 & 3) * 8;
  const unsigned short* gA1 = A + (size_t)(bm + (c1 >> 2)) * K + (c1 & 3) * 8;
  const unsigned short* gB0 = B + (size_t)(bn + (c0 >> 2)) * K + (c0 & 3) * 8;
  const unsigned short* gB1 = B + (size_t)(bn + (c1 >> 2)) * K + (c1 & 3) * 8;
  const int nk = K / BK;
  auto stage = [&](int buf, int kt) {
    const size_t ko = (size_t)kt * BK;
    gload16(gA0 + ko, &lA[buf][(wave * 128) * 8]);
    gload16(gA1 + ko, &lA[buf][(wave * 128 + 64) * 8]);
    gload16(gB0 + ko, &lB[buf][(wave * 128) * 8]);
    gload16(gB1 + ko, &lB[buf][(wave * 128 + 64) * 8]);
  };
  stage(0, 0);
  for (int kt = 0; kt < nk; ++kt) {
    __syncthreads();
    if (kt + 1 < nk) stage((kt + 1) & 1, kt + 1);
    const unsigned short* La = &lA[kt & 1][0];
    const unsigned short* Lb = &lB[kt & 1][0];
    short8 af[4], bfr[4];
#pragma unroll
    for (int m = 0; m < 4; ++m)
      af[m] = *(const short8*)(La + (wr * 64 + m * 16 + lo) * BK + g * 8);
#pragma unroll
    for (int n = 0; n < 4; ++n)
      bfr[n] = *(const short8*)(Lb + (wc * 64 + n * 16 + lo) * BK + g * 8);
#pragma unroll
    for (int m = 0; m < 4; ++m)
#pragma unroll
      for (int n = 0; n < 4; ++n) acc[m][n] = MFMA_BF16(af[m], bfr[n], acc[m][n]);
  }
  const int r0 = bm + wr * 64 + g * 4;
  const int c0c = bn + wc * 64 + lo;
  if (EPI == 3) {
    const int hb = bn + wc * 64;
    if (hb >= 2048) {
      // v-slice: write transposed directly into VT; tokens r0+m*16+0..3 are contiguous,
      // 4-aligned, and within one batch (BM=128 divides SEQ=2048).
      const int h = (hb - 2048) >> 6;
      const int bq = r0 >> 11;  // batch index (constant over the whole block)
      unsigned short* vtp = VT + (size_t)((bq * 16 + h) * 64) * SEQ;
#pragma unroll
      for (int m = 0; m < 4; ++m) {
        const int tis = (r0 + m * 16) & 2047;  // token within sequence
#pragma unroll
        for (int n = 0; n < 4; ++n) {
          const int d = n * 16 + lo;  // head-dim 0..63
          unsigned lo32 = (unsigned)f2bf(acc[m][n][0]) | ((unsigned)f2bf(acc[m][n][1]) << 16);
          unsigned hi32 = (unsigned)f2bf(acc[m][n][2]) | ((unsigned)f2bf(acc[m][n][3]) << 16);
          unsigned* p = (unsigned*)(vtp + (size_t)d * SEQ + tis);
          p[0] = lo32;
          p[1] = hi32;
        }
      }
    } else {
      // q/k slice: per-head l2norm across the 16 lo-lanes; q also x log2e/T
      const bool isq = hb < 1024;
      const float qs = 1.44269504088896f / Tptr[0];
#pragma unroll
      for (int m = 0; m < 4; ++m)
#pragma unroll
        for (int r = 0; r < 4; ++r) {
          float ss = 0.f;
#pragma unroll
          for (int n = 0; n < 4; ++n) ss += acc[m][n][r] * acc[m][n][r];
          ss += __shfl_xor(ss, 1);
          ss += __shfl_xor(ss, 2);
          ss += __shfl_xor(ss, 4);
          ss += __shfl_xor(ss, 8);  // full head-dim sum across the 16 lo-lanes
          float sc = 1.0f / fmaxf(sqrtf(ss), 1e-12f);
          if (isq) sc *= qs;
#pragma unroll
          for (int n = 0; n < 4; ++n) {
            size_t off = (size_t)(r0 + m * 16 + r) * N + (c0c + n * 16);
            ((unsigned short*)Cout)[off] = f2bf(acc[m][n][r] * sc);
          }
        }
    }
  } else {
#pragma unroll
    for (int m = 0; m < 4; ++m)
#pragma unroll
      for (int n = 0; n < 4; ++n) {
#pragma unroll
        for (int r = 0; r < 4; ++r) {
          size_t off = (size_t)(r0 + m * 16 + r) * N + (c0c + n * 16);
          float v = acc[m][n][r];
          if (EPI == 0) ((unsigned short*)Cout)[off] = f2bf(v);
          else if (EPI == 1) ((float*)Cout)[off] = R[off] + v;
          else if (EPI == 2) ((unsigned short*)Cout)[off] = f2bf(fmaxf(v, 0.f));
          else if (EPI == 4) ((unsigned short*)Cout)[off] = f2bf(R[off] + v);
          else /* EPI == 5 */ ((float*)Cout)[off] = bf2f(((const unsigned short*)R)[off]) + v;
        }
      }
  }
}

// ---------------- flash attention v9: 32x32 MFMA, in-register P, raw v_exp_f32 ----------------
// Swapped mfma(K,Q): lane holds S[k][q=lane&31]. Static-max via C-init=-M0 (cosine bound).
// P -> bf16 (cvt_pk) -> permlane32_swap builds PV B-frags in registers (no P LDS).
// exp2 via raw v_exp_f32 (args in [-62,0]); P-sum as a balanced tree (no ordered chain).
__global__ __launch_bounds__(256) void attn_fwd9(const unsigned short* __restrict__ qkv,
                                                 const unsigned short* __restrict__ vt,
                                                 unsigned short* __restrict__ out,
                                                 const float* __restrict__ temp) {
  __shared__ unsigned short lK[2][64 * 64];
  __shared__ unsigned short lV[2][64 * 64];
  const int blk = blockIdx.x;
  const int bh = blk & 63, qt = blk >> 6;
  const int b = bh >> 4, h = bh & 15;
  const int tid = threadIdx.x, lane = tid & 63, wave = tid >> 6;
  const int l5 = lane >> 5, l31 = lane & 31;
  const int qr0 = qt * 128 + wave * 32;
  const float M0 = 1.05f * 1.44269504088896f / temp[0];  // bound on folded scores
  f32x16 minit;
#pragma unroll
  for (int r = 0; r < 16; ++r) minit[r] = -M0;
  const unsigned short* qrow = qkv + (size_t)(b * SEQ + qr0 + l31) * 3072 + h * 64 + l5 * 8;
  short8 qf[4];
#pragma unroll
  for (int t = 0; t < 4; ++t) qf[t] = *(const short8*)(qrow + t * 16);
  const int srow = tid >> 3, slot = tid & 7;
  const int sw0 = ((slot ^ (srow & 7)) * 8);
  const unsigned short* gK = qkv + (size_t)(b * SEQ + srow) * 3072 + 1024 + h * 64 + slot * 8;
  const unsigned short* gV = vt + ((size_t)(bh * 64) + srow) * SEQ + slot * 8;
  short8 rk0 = *(const short8*)gK;
  short8 rk1 = *(const short8*)(gK + (size_t)32 * 3072);
  short8 rv0 = *(const short8*)gV;
  short8 rv1 = *(const short8*)(gV + (size_t)32 * SEQ);
  *(short8*)&lK[0][srow * 64 + sw0] = rk0;
  *(short8*)&lK[0][(srow + 32) * 64 + sw0] = rk1;
  *(short8*)&lV[0][srow * 64 + sw0] = rv0;
  *(short8*)&lV[0][(srow + 32) * 64 + sw0] = rv1;
  f32x16 o0 = {}, o1 = {};
  float lsum = 0.f;
  constexpr int NT = SEQ / 64;
  for (int t = 0; t < NT; ++t) {
    __syncthreads();
    const unsigned short* Kb = &lK[t & 1][0];
    const unsigned short* Vb = &lV[t & 1][0];
    if (t + 1 < NT) {
      rk0 = *(const short8*)(gK + (size_t)(t + 1) * 64 * 3072);
      rk1 = *(const short8*)(gK + (size_t)((t + 1) * 64 + 32) * 3072);
      rv0 = *(const short8*)(gV + (t + 1) * 64);
      rv1 = *(const short8*)(gV + (size_t)32 * SEQ + (t + 1) * 64);
    }
#pragma unroll
    for (int tile = 0; tile < 2; ++tile) {
      f32x16 s = minit;
      __builtin_amdgcn_s_setprio(1);
#pragma unroll
      for (int td = 0; td < 4; ++td) {
        const int row = tile * 32 + l31;
        const int sl = ((2 * td + l5) ^ (row & 7)) * 8;
        short8 kf = *(const short8*)(Kb + row * 64 + sl);
        s = MFMA32(kf, qf[td], s);
      }
      __builtin_amdgcn_s_setprio(0);
      float p[16];
#pragma unroll
      for (int r = 0; r < 16; ++r) p[r] = exp2_fast(s[r]);
      float q01 = p[0] + p[1], q23 = p[2] + p[3], q45 = p[4] + p[5], q67 = p[6] + p[7];
      float q89 = p[8] + p[9], qab = p[10] + p[11], qcd = p[12] + p[13], qef = p[14] + p[15];
      lsum += ((q01 + q23) + (q45 + q67)) + ((q89 + qab) + (qcd + qef));
      unsigned a0 = cvt_pk_bf16(p[0], p[1]), a1 = cvt_pk_bf16(p[2], p[3]);
      unsigned a2 = cvt_pk_bf16(p[4], p[5]), a3 = cvt_pk_bf16(p[6], p[7]);
      unsigned c0 = cvt_pk_bf16(p[8], p[9]), c1 = cvt_pk_bf16(p[10], p[11]);
      unsigned c2 = cvt_pk_bf16(p[12], p[13]), c3 = cvt_pk_bf16(p[14], p[15]);
      uint2v w0 = __builtin_amdgcn_permlane32_swap(a0, a2, false, false);
      uint2v w1 = __builtin_amdgcn_permlane32_swap(a1, a3, false, false);
      uint2v w2 = __builtin_amdgcn_permlane32_swap(c0, c2, false, false);
      uint2v w3 = __builtin_amdgcn_permlane32_swap(c1, c3, false, false);
      union { unsigned u[4]; short8 v; } f0, f1;
      f0.u[0] = w0.x; f0.u[1] = w1.x; f0.u[2] = w0.y; f0.u[3] = w1.y;
      f1.u[0] = w2.x; f1.u[1] = w3.x; f1.u[2] = w2.y; f1.u[3] = w3.y;
      __builtin_amdgcn_s_setprio(1);
      {
        const int vrow0 = l31, vrow1 = 32 + l31;
        const int sa = ((2 * (tile * 2) + l5) ^ (vrow0 & 7)) * 8;
        const int sb = ((2 * (tile * 2 + 1) + l5) ^ (vrow0 & 7)) * 8;
        short8 va0 = *(const short8*)(Vb + vrow0 * 64 + sa);
        short8 vb0 = *(const short8*)(Vb + vrow0 * 64 + sb);
        short8 va1 = *(const short8*)(Vb + vrow1 * 64 + sa);
        short8 vb1 = *(const short8*)(Vb + vrow1 * 64 + sb);
        o0 = MFMA32(va0, f0.v, o0);
        o0 = MFMA32(vb0, f1.v, o0);
        o1 = MFMA32(va1, f0.v, o1);
        o1 = MFMA32(vb1, f1.v, o1);
      }
      __builtin_amdgcn_s_setprio(0);
    }
    if (t + 1 < NT) {
      *(short8*)&lK[(t + 1) & 1][srow * 64 + sw0] = rk0;
      *(short8*)&lK[(t + 1) & 1][(srow + 32) * 64 + sw0] = rk1;
      *(short8*)&lV[(t + 1) & 1][srow * 64 + sw0] = rv0;
      *(short8*)&lV[(t + 1) & 1][(srow + 32) * 64 + sw0] = rv1;
    }
  }
  lsum += __shfl_xor(lsum, 32);
  const float rinv = 1.0f / lsum;
  unsigned short* orow = out + (size_t)(b * SEQ + qr0 + l31) * D_MODEL + h * 64 + l5 * 4;
#pragma unroll
  for (int rq = 0; rq < 4; ++rq)
#pragma unroll
    for (int rr = 0; rr < 4; rr += 2) {
      *(unsigned*)(orow + rq * 8 + rr) =
          cvt_pk_bf16(o0[rq * 4 + rr] * rinv, o0[rq * 4 + rr + 1] * rinv);
      *(unsigned*)(orow + 32 + rq * 8 + rr) =
          cvt_pk_bf16(o1[rq * 4 + rr] * rinv, o1[rq * 4 + rr + 1] * rinv);
    }
}

// ---------------- host launch ----------------
extern "C" void kernel_launch(void* const* d_in, const int* in_sizes, int n_in, void* d_out,
                              int out_size, void* d_ws, size_t ws_size, hipStream_t stream) {
  const float* x = (const float*)d_in[0];
  const float* w_qkv = (const float*)d_in[1];
  const float* w_out = (const float*)d_in[2];
  const float* w_ffn1 = (const float*)d_in[3];
  const float* w_ffn2 = (const float*)d_in[4];
  const float* g1 = (const float*)d_in[5];
  const float* b1 = (const float*)d_in[6];
  const float* g2 = (const float*)d_in[7];
  const float* b2 = (const float*)d_in[8];
  const float* temp = (const float*)d_in[9];
  float* outp = (float*)d_out;

  char* ws = (char*)d_ws;
  size_t off = 0;
  auto alloc = [&](size_t bytes) {
    void* p = ws + off;
    off += (bytes + 255) & ~(size_t)255;
    return p;
  };
  unsigned short* wqkv_bf = (unsigned short*)alloc((size_t)3072 * 1024 * 2);
  unsigned short* wout_bf = (unsigned short*)alloc((size_t)1024 * 1024 * 2);
  unsigned short* wf1_bf = (unsigned short*)alloc((size_t)2048 * 1024 * 2);
  unsigned short* wf2_bf = (unsigned short*)alloc((size_t)1024 * 2048 * 2);
  unsigned short* h_bf = (unsigned short*)alloc((size_t)MTOK * 1024 * 2);   // reused for h2
  unsigned short* qkv_bf = (unsigned short*)alloc((size_t)MTOK * 3072 * 2); // reused for ffn1 out
  unsigned short* vt_bf = (unsigned short*)alloc((size_t)BATCH * NHEADS * DHEAD * SEQ * 2);
  unsigned short* ao_bf = (unsigned short*)alloc((size_t)MTOK * 1024 * 2);
  unsigned short* x2_bf = (unsigned short*)alloc((size_t)MTOK * 1024 * 2);  // bf16 residual

  // weight conversions (single launch)
  f32_to_bf16_all<<<8192, 256, 0, stream>>>(w_qkv, w_out, w_ffn1, w_ffn2, wqkv_bf, wout_bf, wf1_bf,
                                            wf2_bf);
  // LN1
  ln_fwd<<<MTOK, 256, 0, stream>>>(x, g1, b1, h_bf);
  // qkv = h @ w_qkv^T; q,k l2-normalized in-epilogue; v written transposed into vt directly
  gemm_bt2<3><<<dim3(3072 / 128, MTOK / 128), 256, 0, stream>>>(h_bf, wqkv_bf, nullptr, temp,
                                                                vt_bf, (void*)qkv_bf, MTOK, 3072,
                                                                1024);
  // attention (32x32 MFMA, in-register P, raw v_exp, XCD-local mapping)
  attn_fwd9<<<BATCH * NHEADS * (SEQ / 128), 256, 0, stream>>>(qkv_bf, vt_bf, ao_bf, temp);
  // x2 = x + attn_out @ w_out^T  (stored bf16)
  gemm_bt2<4><<<dim3(1024 / 128, MTOK / 128), 256, 0, stream>>>(ao_bf, wout_bf, x, nullptr,
                                                                nullptr, (void*)x2_bf, MTOK, 1024,
                                                                1024);
  // LN2 (bf16 input)
  ln_fwd_b<<<MTOK, 256, 0, stream>>>(x2_bf, g2, b2, h_bf);
  // ffn1 = relu(h2 @ w_ffn1^T)  (reuse qkv buffer)
  gemm_bt2<2><<<dim3(2048 / 128, MTOK / 128), 256, 0, stream>>>(h_bf, wf1_bf, nullptr, nullptr,
                                                                nullptr, (void*)qkv_bf, MTOK, 2048,
                                                                1024);
  // out = x2 + ffn1 @ w_ffn2^T  (bf16 residual read, fp32 out)
  gemm_bt2<5><<<dim3(1024 / 128, MTOK / 128), 256, 0, stream>>>(qkv_bf, wf2_bf,
                                                                (const float*)x2_bf, nullptr,
                                                                nullptr, (void*)outp, MTOK, 1024,
                                                                2048);
}

// Round 17
// 309.003 us; speedup vs baseline: 1.2596x; 1.0014x over previous
//
#include <hip/hip_runtime.h>
#include <cstdint>
#include <cstddef>
#include <math.h>

typedef __attribute__((ext_vector_type(8))) short short8;
typedef __attribute__((ext_vector_type(4))) float f32x4;
typedef __attribute__((ext_vector_type(16))) float f32x16;
typedef __attribute__((ext_vector_type(2))) unsigned uint2v;

#define D_MODEL 1024
#define NHEADS 16
#define DHEAD 64
#define BATCH 4
#define SEQ 2048
#define MTOK (BATCH * SEQ)

__device__ __forceinline__ unsigned short f2bf(float f) {
  union { float f; unsigned u; } v; v.f = f;
  unsigned r = v.u + 0x7fffu + ((v.u >> 16) & 1u);
  return (unsigned short)(r >> 16);
}
__device__ __forceinline__ float bf2f(unsigned short u) {
  union { unsigned u; float f; } v; v.u = ((unsigned)u) << 16;
  return v.f;
}
__device__ __forceinline__ unsigned cvt_pk_bf16(float a, float b) {
  unsigned u;
  asm("v_cvt_pk_bf16_f32 %0, %1, %2" : "=v"(u) : "v"(a), "v"(b));
  return u;
}
// raw v_exp_f32 (2^x). Safe for x in [-126, 127]; our args are in [-62, 0].
__device__ __forceinline__ float exp2_fast(float x) {
  float r;
  asm("v_exp_f32 %0, %1" : "=v"(r) : "v"(x));
  return r;
}

typedef const __attribute__((address_space(1))) unsigned int* gas1_t;
typedef __attribute__((address_space(3))) unsigned int* las3_t;
// async global->LDS, 16B per lane; LDS dest must be wave-uniform base (HW adds lane*16B)
__device__ __forceinline__ void gload16(const unsigned short* g, unsigned short* l) {
  __builtin_amdgcn_global_load_lds((gas1_t)g, (las3_t)l, 16, 0, 0);
}

#define MFMA_BF16(a, b, c) __builtin_amdgcn_mfma_f32_16x16x32_bf16(a, b, c, 0, 0, 0)
#define MFMA32(a, b, c) __builtin_amdgcn_mfma_f32_32x32x16_bf16(a, b, c, 0, 0, 0)

// ---------------- prep0: LN1 (blocks < MTOK) + all 4 weight conversions (blocks >= MTOK) ----------------
__global__ __launch_bounds__(256) void prep0(const float* __restrict__ x, const float* __restrict__ g,
                                             const float* __restrict__ b,
                                             unsigned short* __restrict__ out,
                                             const float* __restrict__ s0, const float* __restrict__ s1,
                                             const float* __restrict__ s2, const float* __restrict__ s3,
                                             unsigned short* __restrict__ d0, unsigned short* __restrict__ d1,
                                             unsigned short* __restrict__ d2, unsigned short* __restrict__ d3) {
  const int blk = blockIdx.x;
  if (blk < MTOK) {
    // ---- LayerNorm row (exact ln_fwd body) ----
    const int row = blk, t = threadIdx.x;
    float4 v = *(const float4*)(x + (size_t)row * D_MODEL + t * 4);
    float s = v.x + v.y + v.z + v.w;
    float s2 = v.x * v.x + v.y * v.y + v.z * v.z + v.w * v.w;
#pragma unroll
    for (int m = 1; m < 64; m <<= 1) { s += __shfl_xor(s, m); s2 += __shfl_xor(s2, m); }
    __shared__ float red[8];
    int wv = t >> 6;
    if ((t & 63) == 0) { red[wv] = s; red[4 + wv] = s2; }
    __syncthreads();
    s = red[0] + red[1] + red[2] + red[3];
    s2 = red[4] + red[5] + red[6] + red[7];
    float mu = s * (1.f / D_MODEL);
    float var = s2 * (1.f / D_MODEL) - mu * mu;
    float rs = rsqrtf(var + 1e-5f);
    float4 gg = *(const float4*)(g + t * 4);
    float4 bb = *(const float4*)(b + t * 4);
    ushort4 o;
    o.x = f2bf((v.x - mu) * rs * gg.x + bb.x);
    o.y = f2bf((v.y - mu) * rs * gg.y + bb.y);
    o.z = f2bf((v.z - mu) * rs * gg.z + bb.z);
    o.w = f2bf((v.w - mu) * rs * gg.w + bb.w);
    *(ushort4*)(out + (size_t)row * D_MODEL + t * 4) = o;
  } else {
    // ---- weight conversion chunk (exact f32_to_bf16_all body) ----
    int j = (blk - MTOK) * 256 + threadIdx.x;  // float4 index over concatenated ranges
    const float* s;
    unsigned short* d;
    if (j < 786432) { s = s0; d = d0; }
    else if ((j -= 786432) < 262144) { s = s1; d = d1; }
    else if ((j -= 262144) < 524288) { s = s2; d = d2; }
    else { j -= 524288; s = s3; d = d3; }
    float4 v = ((const float4*)s)[j];
    ushort4 o;
    o.x = f2bf(v.x); o.y = f2bf(v.y); o.z = f2bf(v.z); o.w = f2bf(v.w);
    ((ushort4*)d)[j] = o;
  }
}

// ---------------- LayerNorm: bf16 in -> bf16 out ----------------
__global__ __launch_bounds__(256) void ln_fwd_b(const unsigned short* __restrict__ x,
                                                const float* __restrict__ g,
                                                const float* __restrict__ b,
                                                unsigned short* __restrict__ out) {
  const int row = blockIdx.x, t = threadIdx.x;
  ushort4 vi = *(const ushort4*)(x + (size_t)row * D_MODEL + t * 4);
  float f0 = bf2f(vi.x), f1 = bf2f(vi.y), f2 = bf2f(vi.z), f3 = bf2f(vi.w);
  float s = f0 + f1 + f2 + f3;
  float s2 = f0 * f0 + f1 * f1 + f2 * f2 + f3 * f3;
#pragma unroll
  for (int m = 1; m < 64; m <<= 1) { s += __shfl_xor(s, m); s2 += __shfl_xor(s2, m); }
  __shared__ float red[8];
  int wv = t >> 6;
  if ((t & 63) == 0) { red[wv] = s; red[4 + wv] = s2; }
  __syncthreads();
  s = red[0] + red[1] + red[2] + red[3];
  s2 = red[4] + red[5] + red[6] + red[7];
  float mu = s * (1.f / D_MODEL);
  float var = s2 * (1.f / D_MODEL) - mu * mu;
  float rs = rsqrtf(var + 1e-5f);
  float4 gg = *(const float4*)(g + t * 4);
  float4 bb = *(const float4*)(b + t * 4);
  ushort4 o;
  o.x = f2bf((f0 - mu) * rs * gg.x + bb.x);
  o.y = f2bf((f1 - mu) * rs * gg.y + bb.y);
  o.z = f2bf((f2 - mu) * rs * gg.z + bb.z);
  o.w = f2bf((f3 - mu) * rs * gg.w + bb.w);
  *(ushort4*)(out + (size_t)row * D_MODEL + t * 4) = o;
}

// ---------------- GEMM (m97 structure, proven): C[M,N] = A[M,K] * B[N,K]^T ----------------
// XCD-chunked block swizzle. EPI: 0 bf16, 1 fp32 R+acc, 2 bf16 relu(acc),
// 3 qkv-fused: per-head l2norm of q,k (q also x log2e/T); v written TRANSPOSED into VT
//   (vt[(b*16+h)*64 + d][tok]); 4 bf16 (R_f32+acc); 5 fp32 store of (R_bf16 + acc).
template <int EPI>
__global__ __launch_bounds__(256) void gemm_bt2(const unsigned short* __restrict__ A,
                                                const unsigned short* __restrict__ B,
                                                const float* __restrict__ R,
                                                const float* __restrict__ Tptr,
                                                unsigned short* __restrict__ VT,
                                                void* __restrict__ Cout, int M, int N, int K) {
  constexpr int BM = 128, BN = 128, BK = 32;
  __shared__ unsigned short lA[2][BM * BK], lB[2][BN * BK];
  const int tid = threadIdx.x, lane = tid & 63, wave = tid >> 6;
  const int lo = lane & 15, g = lane >> 4;
  const int nbx = gridDim.x;
  const int o = blockIdx.y * nbx + blockIdx.x;
  const int cpx = (nbx * gridDim.y) >> 3;
  const int w = (o & 7) * cpx + (o >> 3);
  const int bx = w % nbx, by = w / nbx;
  const int bm = by * BM, bn = bx * BN;
  const int wr = wave >> 1, wc = wave & 1;
  f32x4 acc[4][4] = {};
  const int c0 = wave * 128 + lane, c1 = c0 + 64;
  const unsigned short* gA0 = A + (size_t)(bm + (c0 >> 2)) * K + (c0 & 3) * 8;
  const unsigned short* gA1 = A + (size_t)(bm + (c1 >> 2)) * K + (c1 & 3) * 8;
  const unsigned short* gB0 = B + (size_t)(bn + (c0 >> 2)) * K + (c0 & 3) * 8;
  const unsigned short* gB1 = B + (size_t)(bn + (c1 >> 2)) * K + (c1 & 3) * 8;
  const int nk = K / BK;
  auto stage = [&](int buf, int kt) {
    const size_t ko = (size_t)kt * BK;
    gload16(gA0 + ko, &lA[buf][(wave * 128) * 8]);
    gload16(gA1 + ko, &lA[buf][(wave * 128 + 64) * 8]);
    gload16(gB0 + ko, &lB[buf][(wave * 128) * 8]);
    gload16(gB1 + ko, &lB[buf][(wave * 128 + 64) * 8]);
  };
  stage(0, 0);
  for (int kt = 0; kt < nk; ++kt) {
    __syncthreads();
    if (kt + 1 < nk) stage((kt + 1) & 1, kt + 1);
    const unsigned short* La = &lA[kt & 1][0];
    const unsigned short* Lb = &lB[kt & 1][0];
    short8 af[4], bfr[4];
#pragma unroll
    for (int m = 0; m < 4; ++m)
      af[m] = *(const short8*)(La + (wr * 64 + m * 16 + lo) * BK + g * 8);
#pragma unroll
    for (int n = 0; n < 4; ++n)
      bfr[n] = *(const short8*)(Lb + (wc * 64 + n * 16 + lo) * BK + g * 8);
#pragma unroll
    for (int m = 0; m < 4; ++m)
#pragma unroll
      for (int n = 0; n < 4; ++n) acc[m][n] = MFMA_BF16(af[m], bfr[n], acc[m][n]);
  }
  const int r0 = bm + wr * 64 + g * 4;
  const int c0c = bn + wc * 64 + lo;
  if (EPI == 3) {
    const int hb = bn + wc * 64;
    if (hb >= 2048) {
      // v-slice: write transposed directly into VT; tokens r0+m*16+0..3 contiguous, 4-aligned.
      const int h = (hb - 2048) >> 6;
      const int bq = r0 >> 11;  // batch index (constant over the whole block)
      unsigned short* vtp = VT + (size_t)((bq * 16 + h) * 64) * SEQ;
#pragma unroll
      for (int m = 0; m < 4; ++m) {
        const int tis = (r0 + m * 16) & 2047;  // token within sequence
#pragma unroll
        for (int n = 0; n < 4; ++n) {
          const int d = n * 16 + lo;  // head-dim 0..63
          unsigned lo32 = (unsigned)f2bf(acc[m][n][0]) | ((unsigned)f2bf(acc[m][n][1]) << 16);
          unsigned hi32 = (unsigned)f2bf(acc[m][n][2]) | ((unsigned)f2bf(acc[m][n][3]) << 16);
          unsigned* p = (unsigned*)(vtp + (size_t)d * SEQ + tis);
          p[0] = lo32;
          p[1] = hi32;
        }
      }
    } else {
      // q/k slice: per-head l2norm across the 16 lo-lanes; q also x log2e/T
      const bool isq = hb < 1024;
      const float qs = 1.44269504088896f / Tptr[0];
#pragma unroll
      for (int m = 0; m < 4; ++m)
#pragma unroll
        for (int r = 0; r < 4; ++r) {
          float ss = 0.f;
#pragma unroll
          for (int n = 0; n < 4; ++n) ss += acc[m][n][r] * acc[m][n][r];
          ss += __shfl_xor(ss, 1);
          ss += __shfl_xor(ss, 2);
          ss += __shfl_xor(ss, 4);
          ss += __shfl_xor(ss, 8);  // full head-dim sum across the 16 lo-lanes
          float sc = 1.0f / fmaxf(sqrtf(ss), 1e-12f);
          if (isq) sc *= qs;
#pragma unroll
          for (int n = 0; n < 4; ++n) {
            size_t off = (size_t)(r0 + m * 16 + r) * N + (c0c + n * 16);
            ((unsigned short*)Cout)[off] = f2bf(acc[m][n][r] * sc);
          }
        }
    }
  } else {
#pragma unroll
    for (int m = 0; m < 4; ++m)
#pragma unroll
      for (int n = 0; n < 4; ++n) {
#pragma unroll
        for (int r = 0; r < 4; ++r) {
          size_t off = (size_t)(r0 + m * 16 + r) * N + (c0c + n * 16);
          float v = acc[m][n][r];
          if (EPI == 0) ((unsigned short*)Cout)[off] = f2bf(v);
          else if (EPI == 1) ((float*)Cout)[off] = R[off] + v;
          else if (EPI == 2) ((unsigned short*)Cout)[off] = f2bf(fmaxf(v, 0.f));
          else if (EPI == 4) ((unsigned short*)Cout)[off] = f2bf(R[off] + v);
          else /* EPI == 5 */ ((float*)Cout)[off] = bf2f(((const unsigned short*)R)[off]) + v;
        }
      }
  }
}

// ---------------- flash attention v9: 32x32 MFMA, in-register P, raw v_exp_f32 ----------------
// Swapped mfma(K,Q): lane holds S[k][q=lane&31]. Static-max via C-init=-M0 (cosine bound).
// P -> bf16 (cvt_pk) -> permlane32_swap builds PV B-frags in registers (no P LDS).
// exp2 via raw v_exp_f32 (args in [-62,0]); P-sum as a balanced tree (no ordered chain).
__global__ __launch_bounds__(256) void attn_fwd9(const unsigned short* __restrict__ qkv,
                                                 const unsigned short* __restrict__ vt,
                                                 unsigned short* __restrict__ out,
                                                 const float* __restrict__ temp) {
  __shared__ unsigned short lK[2][64 * 64];
  __shared__ unsigned short lV[2][64 * 64];
  const int blk = blockIdx.x;
  const int bh = blk & 63, qt = blk >> 6;
  const int b = bh >> 4, h = bh & 15;
  const int tid = threadIdx.x, lane = tid & 63, wave = tid >> 6;
  const int l5 = lane >> 5, l31 = lane & 31;
  const int qr0 = qt * 128 + wave * 32;
  const float M0 = 1.05f * 1.44269504088896f / temp[0];  // bound on folded scores
  f32x16 minit;
#pragma unroll
  for (int r = 0; r < 16; ++r) minit[r] = -M0;
  const unsigned short* qrow = qkv + (size_t)(b * SEQ + qr0 + l31) * 3072 + h * 64 + l5 * 8;
  short8 qf[4];
#pragma unroll
  for (int t = 0; t < 4; ++t) qf[t] = *(const short8*)(qrow + t * 16);
  const int srow = tid >> 3, slot = tid & 7;
  const int sw0 = ((slot ^ (srow & 7)) * 8);
  const unsigned short* gK = qkv + (size_t)(b * SEQ + srow) * 3072 + 1024 + h * 64 + slot * 8;
  const unsigned short* gV = vt + ((size_t)(bh * 64) + srow) * SEQ + slot * 8;
  short8 rk0 = *(const short8*)gK;
  short8 rk1 = *(const short8*)(gK + (size_t)32 * 3072);
  short8 rv0 = *(const short8*)gV;
  short8 rv1 = *(const short8*)(gV + (size_t)32 * SEQ);
  *(short8*)&lK[0][srow * 64 + sw0] = rk0;
  *(short8*)&lK[0][(srow + 32) * 64 + sw0] = rk1;
  *(short8*)&lV[0][srow * 64 + sw0] = rv0;
  *(short8*)&lV[0][(srow + 32) * 64 + sw0] = rv1;
  f32x16 o0 = {}, o1 = {};
  float lsum = 0.f;
  constexpr int NT = SEQ / 64;
  for (int t = 0; t < NT; ++t) {
    __syncthreads();
    const unsigned short* Kb = &lK[t & 1][0];
    const unsigned short* Vb = &lV[t & 1][0];
    if (t + 1 < NT) {
      rk0 = *(const short8*)(gK + (size_t)(t + 1) * 64 * 3072);
      rk1 = *(const short8*)(gK + (size_t)((t + 1) * 64 + 32) * 3072);
      rv0 = *(const short8*)(gV + (t + 1) * 64);
      rv1 = *(const short8*)(gV + (size_t)32 * SEQ + (t + 1) * 64);
    }
#pragma unroll
    for (int tile = 0; tile < 2; ++tile) {
      f32x16 s = minit;
      __builtin_amdgcn_s_setprio(1);
#pragma unroll
      for (int td = 0; td < 4; ++td) {
        const int row = tile * 32 + l31;
        const int sl = ((2 * td + l5) ^ (row & 7)) * 8;
        short8 kf = *(const short8*)(Kb + row * 64 + sl);
        s = MFMA32(kf, qf[td], s);
      }
      __builtin_amdgcn_s_setprio(0);
      float p[16];
#pragma unroll
      for (int r = 0; r < 16; ++r) p[r] = exp2_fast(s[r]);
      float q01 = p[0] + p[1], q23 = p[2] + p[3], q45 = p[4] + p[5], q67 = p[6] + p[7];
      float q89 = p[8] + p[9], qab = p[10] + p[11], qcd = p[12] + p[13], qef = p[14] + p[15];
      lsum += ((q01 + q23) + (q45 + q67)) + ((q89 + qab) + (qcd + qef));
      unsigned a0 = cvt_pk_bf16(p[0], p[1]), a1 = cvt_pk_bf16(p[2], p[3]);
      unsigned a2 = cvt_pk_bf16(p[4], p[5]), a3 = cvt_pk_bf16(p[6], p[7]);
      unsigned c0 = cvt_pk_bf16(p[8], p[9]), c1 = cvt_pk_bf16(p[10], p[11]);
      unsigned c2 = cvt_pk_bf16(p[12], p[13]), c3 = cvt_pk_bf16(p[14], p[15]);
      uint2v w0 = __builtin_amdgcn_permlane32_swap(a0, a2, false, false);
      uint2v w1 = __builtin_amdgcn_permlane32_swap(a1, a3, false, false);
      uint2v w2 = __builtin_amdgcn_permlane32_swap(c0, c2, false, false);
      uint2v w3 = __builtin_amdgcn_permlane32_swap(c1, c3, false, false);
      union { unsigned u[4]; short8 v; } f0, f1;
      f0.u[0] = w0.x; f0.u[1] = w1.x; f0.u[2] = w0.y; f0.u[3] = w1.y;
      f1.u[0] = w2.x; f1.u[1] = w3.x; f1.u[2] = w2.y; f1.u[3] = w3.y;
      __builtin_amdgcn_s_setprio(1);
      {
        const int vrow0 = l31, vrow1 = 32 + l31;
        const int sa = ((2 * (tile * 2) + l5) ^ (vrow0 & 7)) * 8;
        const int sb = ((2 * (tile * 2 + 1) + l5) ^ (vrow0 & 7)) * 8;
        short8 va0 = *(const short8*)(Vb + vrow0 * 64 + sa);
        short8 vb0 = *(const short8*)(Vb + vrow0 * 64 + sb);
        short8 va1 = *(const short8*)(Vb + vrow1 * 64 + sa);
        short8 vb1 = *(const short8*)(Vb + vrow1 * 64 + sb);
        o0 = MFMA32(va0, f0.v, o0);
        o0 = MFMA32(vb0, f1.v, o0);
        o1 = MFMA32(va1, f0.v, o1);
        o1 = MFMA32(vb1, f1.v, o1);
      }
      __builtin_amdgcn_s_setprio(0);
    }
    if (t + 1 < NT) {
      *(short8*)&lK[(t + 1) & 1][srow * 64 + sw0] = rk0;
      *(short8*)&lK[(t + 1) & 1][(srow + 32) * 64 + sw0] = rk1;
      *(short8*)&lV[(t + 1) & 1][srow * 64 + sw0] = rv0;
      *(short8*)&lV[(t + 1) & 1][(srow + 32) * 64 + sw0] = rv1;
    }
  }
  lsum += __shfl_xor(lsum, 32);
  const float rinv = 1.0f / lsum;
  unsigned short* orow = out + (size_t)(b * SEQ + qr0 + l31) * D_MODEL + h * 64 + l5 * 4;
#pragma unroll
  for (int rq = 0; rq < 4; ++rq)
#pragma unroll
    for (int rr = 0; rr < 4; rr += 2) {
      *(unsigned*)(orow + rq * 8 + rr) =
          cvt_pk_bf16(o0[rq * 4 + rr] * rinv, o0[rq * 4 + rr + 1] * rinv);
      *(unsigned*)(orow + 32 + rq * 8 + rr) =
          cvt_pk_bf16(o1[rq * 4 + rr] * rinv, o1[rq * 4 + rr + 1] * rinv);
    }
}

// ---------------- host launch ----------------
extern "C" void kernel_launch(void* const* d_in, const int* in_sizes, int n_in, void* d_out,
                              int out_size, void* d_ws, size_t ws_size, hipStream_t stream) {
  const float* x = (const float*)d_in[0];
  const float* w_qkv = (const float*)d_in[1];
  const float* w_out = (const float*)d_in[2];
  const float* w_ffn1 = (const float*)d_in[3];
  const float* w_ffn2 = (const float*)d_in[4];
  const float* g1 = (const float*)d_in[5];
  const float* b1 = (const float*)d_in[6];
  const float* g2 = (const float*)d_in[7];
  const float* b2 = (const float*)d_in[8];
  const float* temp = (const float*)d_in[9];
  float* outp = (float*)d_out;

  char* ws = (char*)d_ws;
  size_t off = 0;
  auto alloc = [&](size_t bytes) {
    void* p = ws + off;
    off += (bytes + 255) & ~(size_t)255;
    return p;
  };
  unsigned short* wqkv_bf = (unsigned short*)alloc((size_t)3072 * 1024 * 2);
  unsigned short* wout_bf = (unsigned short*)alloc((size_t)1024 * 1024 * 2);
  unsigned short* wf1_bf = (unsigned short*)alloc((size_t)2048 * 1024 * 2);
  unsigned short* wf2_bf = (unsigned short*)alloc((size_t)1024 * 2048 * 2);
  unsigned short* h_bf = (unsigned short*)alloc((size_t)MTOK * 1024 * 2);   // reused for h2
  unsigned short* qkv_bf = (unsigned short*)alloc((size_t)MTOK * 3072 * 2); // reused for ffn1 out
  unsigned short* vt_bf = (unsigned short*)alloc((size_t)BATCH * NHEADS * DHEAD * SEQ * 2);
  unsigned short* ao_bf = (unsigned short*)alloc((size_t)MTOK * 1024 * 2);
  unsigned short* x2_bf = (unsigned short*)alloc((size_t)MTOK * 1024 * 2);  // bf16 residual

  // LN1 + all weight conversions in one launch (independent memory streams)
  prep0<<<MTOK + 8192, 256, 0, stream>>>(x, g1, b1, h_bf, w_qkv, w_out, w_ffn1, w_ffn2, wqkv_bf,
                                         wout_bf, wf1_bf, wf2_bf);
  // qkv = h @ w_qkv^T; q,k l2-normalized in-epilogue; v written transposed into vt directly
  gemm_bt2<3><<<dim3(3072 / 128, MTOK / 128), 256, 0, stream>>>(h_bf, wqkv_bf, nullptr, temp,
                                                                vt_bf, (void*)qkv_bf, MTOK, 3072,
                                                                1024);
  // attention (32x32 MFMA, in-register P, raw v_exp, XCD-local mapping)
  attn_fwd9<<<BATCH * NHEADS * (SEQ / 128), 256, 0, stream>>>(qkv_bf, vt_bf, ao_bf, temp);
  // x2 = x + attn_out @ w_out^T  (stored bf16)
  gemm_bt2<4><<<dim3(1024 / 128, MTOK / 128), 256, 0, stream>>>(ao_bf, wout_bf, x, nullptr,
                                                                nullptr, (void*)x2_bf, MTOK, 1024,
                                                                1024);
  // LN2 (bf16 input)
  ln_fwd_b<<<MTOK, 256, 0, stream>>>(x2_bf, g2, b2, h_bf);
  // ffn1 = relu(h2 @ w_ffn1^T)  (reuse qkv buffer)
  gemm_bt2<2><<<dim3(2048 / 128, MTOK / 128), 256, 0, stream>>>(h_bf, wf1_bf, nullptr, nullptr,
                                                                nullptr, (void*)qkv_bf, MTOK, 2048,
                                                                1024);
  // out = x2 + ffn1 @ w_ffn2^T  (bf16 residual read, fp32 out)
  gemm_bt2<5><<<dim3(1024 / 128, MTOK / 128), 256, 0, stream>>>(qkv_bf, wf2_bf,
                                                                (const float*)x2_bf, nullptr,
                                                                nullptr, (void*)outp, MTOK, 1024,
                                                                2048);
}

// Round 18
// 308.795 us; speedup vs baseline: 1.2605x; 1.0007x over previous
//
#include <hip/hip_runtime.h>
#include <cstdint>
#include <cstddef>
#include <math.h>

typedef __attribute__((ext_vector_type(8))) short short8;
typedef __attribute__((ext_vector_type(4))) float f32x4;
typedef __attribute__((ext_vector_type(16))) float f32x16;
typedef __attribute__((ext_vector_type(2))) unsigned uint2v;

#define D_MODEL 1024
#define NHEADS 16
#define DHEAD 64
#define BATCH 4
#define SEQ 2048
#define MTOK (BATCH * SEQ)

__device__ __forceinline__ unsigned short f2bf(float f) {
  union { float f; unsigned u; } v; v.f = f;
  unsigned r = v.u + 0x7fffu + ((v.u >> 16) & 1u);
  return (unsigned short)(r >> 16);
}
__device__ __forceinline__ float bf2f(unsigned short u) {
  union { unsigned u; float f; } v; v.u = ((unsigned)u) << 16;
  return v.f;
}
__device__ __forceinline__ unsigned cvt_pk_bf16(float a, float b) {
  unsigned u;
  asm("v_cvt_pk_bf16_f32 %0, %1, %2" : "=v"(u) : "v"(a), "v"(b));
  return u;
}
// raw v_exp_f32 (2^x). Safe for x in [-126, 127]; our args are in [-62, 0].
__device__ __forceinline__ float exp2_fast(float x) {
  float r;
  asm("v_exp_f32 %0, %1" : "=v"(r) : "v"(x));
  return r;
}

typedef const __attribute__((address_space(1))) unsigned int* gas1_t;
typedef __attribute__((address_space(3))) unsigned int* las3_t;
// async global->LDS, 16B per lane; LDS dest must be wave-uniform base (HW adds lane*16B)
__device__ __forceinline__ void gload16(const unsigned short* g, unsigned short* l) {
  __builtin_amdgcn_global_load_lds((gas1_t)g, (las3_t)l, 16, 0, 0);
}

#define MFMA_BF16(a, b, c) __builtin_amdgcn_mfma_f32_16x16x32_bf16(a, b, c, 0, 0, 0)
#define MFMA32(a, b, c) __builtin_amdgcn_mfma_f32_32x32x16_bf16(a, b, c, 0, 0, 0)

// ---------------- prep0: LN1 (blocks < MTOK) + all 4 weight conversions (blocks >= MTOK) ----------------
__global__ __launch_bounds__(256) void prep0(const float* __restrict__ x, const float* __restrict__ g,
                                             const float* __restrict__ b,
                                             unsigned short* __restrict__ out,
                                             const float* __restrict__ s0, const float* __restrict__ s1,
                                             const float* __restrict__ s2, const float* __restrict__ s3,
                                             unsigned short* __restrict__ d0, unsigned short* __restrict__ d1,
                                             unsigned short* __restrict__ d2, unsigned short* __restrict__ d3) {
  const int blk = blockIdx.x;
  if (blk < MTOK) {
    // ---- LayerNorm row ----
    const int row = blk, t = threadIdx.x;
    float4 v = *(const float4*)(x + (size_t)row * D_MODEL + t * 4);
    float s = v.x + v.y + v.z + v.w;
    float s2 = v.x * v.x + v.y * v.y + v.z * v.z + v.w * v.w;
#pragma unroll
    for (int m = 1; m < 64; m <<= 1) { s += __shfl_xor(s, m); s2 += __shfl_xor(s2, m); }
    __shared__ float red[8];
    int wv = t >> 6;
    if ((t & 63) == 0) { red[wv] = s; red[4 + wv] = s2; }
    __syncthreads();
    s = red[0] + red[1] + red[2] + red[3];
    s2 = red[4] + red[5] + red[6] + red[7];
    float mu = s * (1.f / D_MODEL);
    float var = s2 * (1.f / D_MODEL) - mu * mu;
    float rs = rsqrtf(var + 1e-5f);
    float4 gg = *(const float4*)(g + t * 4);
    float4 bb = *(const float4*)(b + t * 4);
    ushort4 o;
    o.x = f2bf((v.x - mu) * rs * gg.x + bb.x);
    o.y = f2bf((v.y - mu) * rs * gg.y + bb.y);
    o.z = f2bf((v.z - mu) * rs * gg.z + bb.z);
    o.w = f2bf((v.w - mu) * rs * gg.w + bb.w);
    *(ushort4*)(out + (size_t)row * D_MODEL + t * 4) = o;
  } else {
    // ---- weight conversion chunk ----
    int j = (blk - MTOK) * 256 + threadIdx.x;  // float4 index over concatenated ranges
    const float* s;
    unsigned short* d;
    if (j < 786432) { s = s0; d = d0; }
    else if ((j -= 786432) < 262144) { s = s1; d = d1; }
    else if ((j -= 262144) < 524288) { s = s2; d = d2; }
    else { j -= 524288; s = s3; d = d3; }
    float4 v = ((const float4*)s)[j];
    ushort4 o;
    o.x = f2bf(v.x); o.y = f2bf(v.y); o.z = f2bf(v.z); o.w = f2bf(v.w);
    ((ushort4*)d)[j] = o;
  }
}

// ---------------- LayerNorm: bf16 in -> bf16 out ----------------
__global__ __launch_bounds__(256) void ln_fwd_b(const unsigned short* __restrict__ x,
                                                const float* __restrict__ g,
                                                const float* __restrict__ b,
                                                unsigned short* __restrict__ out) {
  const int row = blockIdx.x, t = threadIdx.x;
  ushort4 vi = *(const ushort4*)(x + (size_t)row * D_MODEL + t * 4);
  float f0 = bf2f(vi.x), f1 = bf2f(vi.y), f2 = bf2f(vi.z), f3 = bf2f(vi.w);
  float s = f0 + f1 + f2 + f3;
  float s2 = f0 * f0 + f1 * f1 + f2 * f2 + f3 * f3;
#pragma unroll
  for (int m = 1; m < 64; m <<= 1) { s += __shfl_xor(s, m); s2 += __shfl_xor(s2, m); }
  __shared__ float red[8];
  int wv = t >> 6;
  if ((t & 63) == 0) { red[wv] = s; red[4 + wv] = s2; }
  __syncthreads();
  s = red[0] + red[1] + red[2] + red[3];
  s2 = red[4] + red[5] + red[6] + red[7];
  float mu = s * (1.f / D_MODEL);
  float var = s2 * (1.f / D_MODEL) - mu * mu;
  float rs = rsqrtf(var + 1e-5f);
  float4 gg = *(const float4*)(g + t * 4);
  float4 bb = *(const float4*)(b + t * 4);
  ushort4 o;
  o.x = f2bf((f0 - mu) * rs * gg.x + bb.x);
  o.y = f2bf((f1 - mu) * rs * gg.y + bb.y);
  o.z = f2bf((f2 - mu) * rs * gg.z + bb.z);
  o.w = f2bf((f3 - mu) * rs * gg.w + bb.w);
  *(ushort4*)(out + (size_t)row * D_MODEL + t * 4) = o;
}

// ---------------- GEMM (m97 structure, proven): C[M,N] = A[M,K] * B[N,K]^T ----------------
// XCD-chunked block swizzle. EPI: 0 bf16, 1 fp32 R+acc, 2 bf16 relu(acc),
// 3 qkv-fused: per-head l2norm of q,k (q also x log2e/T); v written TRANSPOSED into VT
//   (vt[(b*16+h)*64 + d][tok]); 4 bf16 (R_f32+acc); 5 fp32 store of (R_bf16 + acc).
template <int EPI>
__global__ __launch_bounds__(256) void gemm_bt2(const unsigned short* __restrict__ A,
                                                const unsigned short* __restrict__ B,
                                                const float* __restrict__ R,
                                                const float* __restrict__ Tptr,
                                                unsigned short* __restrict__ VT,
                                                void* __restrict__ Cout, int M, int N, int K) {
  constexpr int BM = 128, BN = 128, BK = 32;
  __shared__ unsigned short lA[2][BM * BK], lB[2][BN * BK];
  const int tid = threadIdx.x, lane = tid & 63, wave = tid >> 6;
  const int lo = lane & 15, g = lane >> 4;
  const int nbx = gridDim.x;
  const int o = blockIdx.y * nbx + blockIdx.x;
  const int cpx = (nbx * gridDim.y) >> 3;
  const int w = (o & 7) * cpx + (o >> 3);
  const int bx = w % nbx, by = w / nbx;
  const int bm = by * BM, bn = bx * BN;
  const int wr = wave >> 1, wc = wave & 1;
  f32x4 acc[4][4] = {};
  const int c0 = wave * 128 + lane, c1 = c0 + 64;
  const unsigned short* gA0 = A + (size_t)(bm + (c0 >> 2)) * K + (c0 & 3) * 8;
  const unsigned short* gA1 = A + (size_t)(bm + (c1 >> 2)) * K + (c1 & 3) * 8;
  const unsigned short* gB0 = B + (size_t)(bn + (c0 >> 2)) * K + (c0 & 3) * 8;
  const unsigned short* gB1 = B + (size_t)(bn + (c1 >> 2)) * K + (c1 & 3) * 8;
  const int nk = K / BK;
  auto stage = [&](int buf, int kt) {
    const size_t ko = (size_t)kt * BK;
    gload16(gA0 + ko, &lA[buf][(wave * 128) * 8]);
    gload16(gA1 + ko, &lA[buf][(wave * 128 + 64) * 8]);
    gload16(gB0 + ko, &lB[buf][(wave * 128) * 8]);
    gload16(gB1 + ko, &lB[buf][(wave * 128 + 64) * 8]);
  };
  stage(0, 0);
  for (int kt = 0; kt < nk; ++kt) {
    __syncthreads();
    if (kt + 1 < nk) stage((kt + 1) & 1, kt + 1);
    const unsigned short* La = &lA[kt & 1][0];
    const unsigned short* Lb = &lB[kt & 1][0];
    short8 af[4], bfr[4];
#pragma unroll
    for (int m = 0; m < 4; ++m)
      af[m] = *(const short8*)(La + (wr * 64 + m * 16 + lo) * BK + g * 8);
#pragma unroll
    for (int n = 0; n < 4; ++n)
      bfr[n] = *(const short8*)(Lb + (wc * 64 + n * 16 + lo) * BK + g * 8);
#pragma unroll
    for (int m = 0; m < 4; ++m)
#pragma unroll
      for (int n = 0; n < 4; ++n) acc[m][n] = MFMA_BF16(af[m], bfr[n], acc[m][n]);
  }
  const int r0 = bm + wr * 64 + g * 4;
  const int c0c = bn + wc * 64 + lo;
  if (EPI == 3) {
    const int hb = bn + wc * 64;
    if (hb >= 2048) {
      // v-slice: write transposed directly into VT; tokens r0+m*16+0..3 contiguous, 4-aligned.
      const int h = (hb - 2048) >> 6;
      const int bq = r0 >> 11;  // batch index (constant over the whole block)
      unsigned short* vtp = VT + (size_t)((bq * 16 + h) * 64) * SEQ;
#pragma unroll
      for (int m = 0; m < 4; ++m) {
        const int tis = (r0 + m * 16) & 2047;  // token within sequence
#pragma unroll
        for (int n = 0; n < 4; ++n) {
          const int d = n * 16 + lo;  // head-dim 0..63
          unsigned lo32 = (unsigned)f2bf(acc[m][n][0]) | ((unsigned)f2bf(acc[m][n][1]) << 16);
          unsigned hi32 = (unsigned)f2bf(acc[m][n][2]) | ((unsigned)f2bf(acc[m][n][3]) << 16);
          unsigned* p = (unsigned*)(vtp + (size_t)d * SEQ + tis);
          p[0] = lo32;
          p[1] = hi32;
        }
      }
    } else {
      // q/k slice: per-head l2norm across the 16 lo-lanes; q also x log2e/T
      const bool isq = hb < 1024;
      const float qs = 1.44269504088896f / Tptr[0];
#pragma unroll
      for (int m = 0; m < 4; ++m)
#pragma unroll
        for (int r = 0; r < 4; ++r) {
          float ss = 0.f;
#pragma unroll
          for (int n = 0; n < 4; ++n) ss += acc[m][n][r] * acc[m][n][r];
          ss += __shfl_xor(ss, 1);
          ss += __shfl_xor(ss, 2);
          ss += __shfl_xor(ss, 4);
          ss += __shfl_xor(ss, 8);  // full head-dim sum across the 16 lo-lanes
          float sc = 1.0f / fmaxf(sqrtf(ss), 1e-12f);
          if (isq) sc *= qs;
#pragma unroll
          for (int n = 0; n < 4; ++n) {
            size_t off = (size_t)(r0 + m * 16 + r) * N + (c0c + n * 16);
            ((unsigned short*)Cout)[off] = f2bf(acc[m][n][r] * sc);
          }
        }
    }
  } else {
#pragma unroll
    for (int m = 0; m < 4; ++m)
#pragma unroll
      for (int n = 0; n < 4; ++n) {
#pragma unroll
        for (int r = 0; r < 4; ++r) {
          size_t off = (size_t)(r0 + m * 16 + r) * N + (c0c + n * 16);
          float v = acc[m][n][r];
          if (EPI == 0) ((unsigned short*)Cout)[off] = f2bf(v);
          else if (EPI == 1) ((float*)Cout)[off] = R[off] + v;
          else if (EPI == 2) ((unsigned short*)Cout)[off] = f2bf(fmaxf(v, 0.f));
          else if (EPI == 4) ((unsigned short*)Cout)[off] = f2bf(R[off] + v);
          else /* EPI == 5 */ ((float*)Cout)[off] = bf2f(((const unsigned short*)R)[off]) + v;
        }
      }
  }
}

// ---------------- flash attention v12: 32x32 MFMA, in-register P, gload_lds K/V staging ----------------
// Same as v9 except K/V staging now uses global_load_lds (linear wave-uniform LDS dest +
// inverse-swizzled per-lane global source; identical final LDS layout): removes the
// reg-staged loads/ds_writes from the compute stream and frees 16 staging VGPRs.
__global__ __launch_bounds__(256) void attn_fwd12(const unsigned short* __restrict__ qkv,
                                                  const unsigned short* __restrict__ vt,
                                                  unsigned short* __restrict__ out,
                                                  const float* __restrict__ temp) {
  __shared__ unsigned short lK[2][64 * 64];
  __shared__ unsigned short lV[2][64 * 64];
  const int blk = blockIdx.x;
  const int bh = blk & 63, qt = blk >> 6;
  const int b = bh >> 4, h = bh & 15;
  const int tid = threadIdx.x, lane = tid & 63, wave = tid >> 6;
  const int l5 = lane >> 5, l31 = lane & 31;
  const int qr0 = qt * 128 + wave * 32;
  const float M0 = 1.05f * 1.44269504088896f / temp[0];  // bound on folded scores
  f32x16 minit;
#pragma unroll
  for (int r = 0; r < 16; ++r) minit[r] = -M0;
  const unsigned short* qrow = qkv + (size_t)(b * SEQ + qr0 + l31) * 3072 + h * 64 + l5 * 8;
  short8 qf[4];
#pragma unroll
  for (int t = 0; t < 4; ++t) qf[t] = *(const short8*)(qrow + t * 16);
  // gload_lds staging: lane l of wave w covers row w*8 + (l>>3) (and +32), LDS linear;
  // global source column inverse-swizzled so LDS[row][c] = G[row][c ^ (row&7)].
  const int srow = tid >> 3;
  const int sslot = (tid & 7) ^ ((tid >> 3) & 7);
  const unsigned short* gK = qkv + (size_t)(b * SEQ + srow) * 3072 + 1024 + h * 64 + sslot * 8;
  const unsigned short* gV = vt + ((size_t)(bh * 64) + srow) * SEQ + sslot * 8;
  unsigned short* dK0 = &lK[0][0] + (wave * 8) * 64;   // wave-uniform dests (buf 0)
  unsigned short* dK1 = &lK[1][0] + (wave * 8) * 64;
  unsigned short* dV0 = &lV[0][0] + (wave * 8) * 64;
  unsigned short* dV1 = &lV[1][0] + (wave * 8) * 64;
  auto stageKV = [&](int buf, int t) {
    const size_t kof = (size_t)t * 64 * 3072;
    const size_t vof = (size_t)t * 64;
    unsigned short* dk = buf ? dK1 : dK0;
    unsigned short* dv = buf ? dV1 : dV0;
    gload16(gK + kof, dk);
    gload16(gK + kof + (size_t)32 * 3072, dk + 32 * 64);
    gload16(gV + vof, dv);
    gload16(gV + vof + (size_t)32 * SEQ, dv + 32 * 64);
  };
  stageKV(0, 0);
  f32x16 o0 = {}, o1 = {};
  float lsum = 0.f;
  constexpr int NT = SEQ / 64;
  for (int t = 0; t < NT; ++t) {
    __syncthreads();  // drains vmcnt: tile t landed; prior reads of the other buffer done
    if (t + 1 < NT) stageKV((t + 1) & 1, t + 1);  // flies under this iteration's compute
    const unsigned short* Kb = &lK[t & 1][0];
    const unsigned short* Vb = &lV[t & 1][0];
#pragma unroll
    for (int tile = 0; tile < 2; ++tile) {
      f32x16 s = minit;
      __builtin_amdgcn_s_setprio(1);
#pragma unroll
      for (int td = 0; td < 4; ++td) {
        const int row = tile * 32 + l31;
        const int sl = ((2 * td + l5) ^ (row & 7)) * 8;
        short8 kf = *(const short8*)(Kb + row * 64 + sl);
        s = MFMA32(kf, qf[td], s);
      }
      __builtin_amdgcn_s_setprio(0);
      float p[16];
#pragma unroll
      for (int r = 0; r < 16; ++r) p[r] = exp2_fast(s[r]);
      float q01 = p[0] + p[1], q23 = p[2] + p[3], q45 = p[4] + p[5], q67 = p[6] + p[7];
      float q89 = p[8] + p[9], qab = p[10] + p[11], qcd = p[12] + p[13], qef = p[14] + p[15];
      lsum += ((q01 + q23) + (q45 + q67)) + ((q89 + qab) + (qcd + qef));
      unsigned a0 = cvt_pk_bf16(p[0], p[1]), a1 = cvt_pk_bf16(p[2], p[3]);
      unsigned a2 = cvt_pk_bf16(p[4], p[5]), a3 = cvt_pk_bf16(p[6], p[7]);
      unsigned c0 = cvt_pk_bf16(p[8], p[9]), c1 = cvt_pk_bf16(p[10], p[11]);
      unsigned c2 = cvt_pk_bf16(p[12], p[13]), c3 = cvt_pk_bf16(p[14], p[15]);
      uint2v w0 = __builtin_amdgcn_permlane32_swap(a0, a2, false, false);
      uint2v w1 = __builtin_amdgcn_permlane32_swap(a1, a3, false, false);
      uint2v w2 = __builtin_amdgcn_permlane32_swap(c0, c2, false, false);
      uint2v w3 = __builtin_amdgcn_permlane32_swap(c1, c3, false, false);
      union { unsigned u[4]; short8 v; } f0, f1;
      f0.u[0] = w0.x; f0.u[1] = w1.x; f0.u[2] = w0.y; f0.u[3] = w1.y;
      f1.u[0] = w2.x; f1.u[1] = w3.x; f1.u[2] = w2.y; f1.u[3] = w3.y;
      __builtin_amdgcn_s_setprio(1);
      {
        const int vrow0 = l31, vrow1 = 32 + l31;
        const int sa = ((2 * (tile * 2) + l5) ^ (vrow0 & 7)) * 8;
        const int sb = ((2 * (tile * 2 + 1) + l5) ^ (vrow0 & 7)) * 8;
        short8 va0 = *(const short8*)(Vb + vrow0 * 64 + sa);
        short8 vb0 = *(const short8*)(Vb + vrow0 * 64 + sb);
        short8 va1 = *(const short8*)(Vb + vrow1 * 64 + sa);
        short8 vb1 = *(const short8*)(Vb + vrow1 * 64 + sb);
        o0 = MFMA32(va0, f0.v, o0);
        o0 = MFMA32(vb0, f1.v, o0);
        o1 = MFMA32(va1, f0.v, o1);
        o1 = MFMA32(vb1, f1.v, o1);
      }
      __builtin_amdgcn_s_setprio(0);
    }
  }
  lsum += __shfl_xor(lsum, 32);
  const float rinv = 1.0f / lsum;
  unsigned short* orow = out + (size_t)(b * SEQ + qr0 + l31) * D_MODEL + h * 64 + l5 * 4;
#pragma unroll
  for (int rq = 0; rq < 4; ++rq)
#pragma unroll
    for (int rr = 0; rr < 4; rr += 2) {
      *(unsigned*)(orow + rq * 8 + rr) =
          cvt_pk_bf16(o0[rq * 4 + rr] * rinv, o0[rq * 4 + rr + 1] * rinv);
      *(unsigned*)(orow + 32 + rq * 8 + rr) =
          cvt_pk_bf16(o1[rq * 4 + rr] * rinv, o1[rq * 4 + rr + 1] * rinv);
    }
}

// ---------------- host launch ----------------
extern "C" void kernel_launch(void* const* d_in, const int* in_sizes, int n_in, void* d_out,
                              int out_size, void* d_ws, size_t ws_size, hipStream_t stream) {
  const float* x = (const float*)d_in[0];
  const float* w_qkv = (const float*)d_in[1];
  const float* w_out = (const float*)d_in[2];
  const float* w_ffn1 = (const float*)d_in[3];
  const float* w_ffn2 = (const float*)d_in[4];
  const float* g1 = (const float*)d_in[5];
  const float* b1 = (const float*)d_in[6];
  const float* g2 = (const float*)d_in[7];
  const float* b2 = (const float*)d_in[8];
  const float* temp = (const float*)d_in[9];
  float* outp = (float*)d_out;

  char* ws = (char*)d_ws;
  size_t off = 0;
  auto alloc = [&](size_t bytes) {
    void* p = ws + off;
    off += (bytes + 255) & ~(size_t)255;
    return p;
  };
  unsigned short* wqkv_bf = (unsigned short*)alloc((size_t)3072 * 1024 * 2);
  unsigned short* wout_bf = (unsigned short*)alloc((size_t)1024 * 1024 * 2);
  unsigned short* wf1_bf = (unsigned short*)alloc((size_t)2048 * 1024 * 2);
  unsigned short* wf2_bf = (unsigned short*)alloc((size_t)1024 * 2048 * 2);
  unsigned short* h_bf = (unsigned short*)alloc((size_t)MTOK * 1024 * 2);   // reused for h2
  unsigned short* qkv_bf = (unsigned short*)alloc((size_t)MTOK * 3072 * 2); // reused for ffn1 out
  unsigned short* vt_bf = (unsigned short*)alloc((size_t)BATCH * NHEADS * DHEAD * SEQ * 2);
  unsigned short* ao_bf = (unsigned short*)alloc((size_t)MTOK * 1024 * 2);
  unsigned short* x2_bf = (unsigned short*)alloc((size_t)MTOK * 1024 * 2);  // bf16 residual

  // LN1 + all weight conversions in one launch (independent memory streams)
  prep0<<<MTOK + 8192, 256, 0, stream>>>(x, g1, b1, h_bf, w_qkv, w_out, w_ffn1, w_ffn2, wqkv_bf,
                                         wout_bf, wf1_bf, wf2_bf);
  // qkv = h @ w_qkv^T; q,k l2-normalized in-epilogue; v written transposed into vt directly
  gemm_bt2<3><<<dim3(3072 / 128, MTOK / 128), 256, 0, stream>>>(h_bf, wqkv_bf, nullptr, temp,
                                                                vt_bf, (void*)qkv_bf, MTOK, 3072,
                                                                1024);
  // attention (32x32 MFMA, in-register P, gload_lds staging, XCD-local mapping)
  attn_fwd12<<<BATCH * NHEADS * (SEQ / 128), 256, 0, stream>>>(qkv_bf, vt_bf, ao_bf, temp);
  // x2 = x + attn_out @ w_out^T  (stored bf16)
  gemm_bt2<4><<<dim3(1024 / 128, MTOK / 128), 256, 0, stream>>>(ao_bf, wout_bf, x, nullptr,
                                                                nullptr, (void*)x2_bf, MTOK, 1024,
                                                                1024);
  // LN2 (bf16 input)
  ln_fwd_b<<<MTOK, 256, 0, stream>>>(x2_bf, g2, b2, h_bf);
  // ffn1 = relu(h2 @ w_ffn1^T)  (reuse qkv buffer)
  gemm_bt2<2><<<dim3(2048 / 128, MTOK / 128), 256, 0, stream>>>(h_bf, wf1_bf, nullptr, nullptr,
                                                                nullptr, (void*)qkv_bf, MTOK, 2048,
                                                                1024);
  // out = x2 + ffn1 @ w_ffn2^T  (bf16 residual read, fp32 out)
  gemm_bt2<5><<<dim3(1024 / 128, MTOK / 128), 256, 0, stream>>>(qkv_bf, wf2_bf,
                                                                (const float*)x2_bf, nullptr,
                                                                nullptr, (void*)outp, MTOK, 1024,
                                                                2048);
}

// Round 20
// 308.611 us; speedup vs baseline: 1.2612x; 1.0006x over previous
//
#include <hip/hip_runtime.h>
#include <cstdint>
#include <cstddef>
#include <math.h>

typedef __attribute__((ext_vector_type(8))) short short8;
typedef __attribute__((ext_vector_type(4))) float f32x4;
typedef __attribute__((ext_vector_type(16))) float f32x16;
typedef __attribute__((ext_vector_type(2))) unsigned uint2v;

#define D_MODEL 1024
#define NHEADS 16
#define DHEAD 64
#define BATCH 4
#define SEQ 2048
#define MTOK (BATCH * SEQ)

__device__ __forceinline__ unsigned short f2bf(float f) {
  union { float f; unsigned u; } v; v.f = f;
  unsigned r = v.u + 0x7fffu + ((v.u >> 16) & 1u);
  return (unsigned short)(r >> 16);
}
__device__ __forceinline__ float bf2f(unsigned short u) {
  union { unsigned u; float f; } v; v.u = ((unsigned)u) << 16;
  return v.f;
}
__device__ __forceinline__ unsigned cvt_pk_bf16(float a, float b) {
  unsigned u;
  asm("v_cvt_pk_bf16_f32 %0, %1, %2" : "=v"(u) : "v"(a), "v"(b));
  return u;
}
// raw v_exp_f32 (2^x). Safe for x in [-126, 127]; our args are in [-62, 0].
__device__ __forceinline__ float exp2_fast(float x) {
  float r;
  asm("v_exp_f32 %0, %1" : "=v"(r) : "v"(x));
  return r;
}

typedef const __attribute__((address_space(1))) unsigned int* gas1_t;
typedef __attribute__((address_space(3))) unsigned int* las3_t;
// async global->LDS, 16B per lane; LDS dest must be wave-uniform base (HW adds lane*16B)
__device__ __forceinline__ void gload16(const unsigned short* g, unsigned short* l) {
  __builtin_amdgcn_global_load_lds((gas1_t)g, (las3_t)l, 16, 0, 0);
}

#define MFMA_BF16(a, b, c) __builtin_amdgcn_mfma_f32_16x16x32_bf16(a, b, c, 0, 0, 0)
#define MFMA32(a, b, c) __builtin_amdgcn_mfma_f32_32x32x16_bf16(a, b, c, 0, 0, 0)

// ---------------- prep0: LN1 (blocks < MTOK) + all 4 weight conversions (blocks >= MTOK) ----------------
__global__ __launch_bounds__(256) void prep0(const float* __restrict__ x, const float* __restrict__ g,
                                             const float* __restrict__ b,
                                             unsigned short* __restrict__ out,
                                             const float* __restrict__ s0, const float* __restrict__ s1,
                                             const float* __restrict__ s2, const float* __restrict__ s3,
                                             unsigned short* __restrict__ d0, unsigned short* __restrict__ d1,
                                             unsigned short* __restrict__ d2, unsigned short* __restrict__ d3) {
  const int blk = blockIdx.x;
  if (blk < MTOK) {
    // ---- LayerNorm row ----
    const int row = blk, t = threadIdx.x;
    float4 v = *(const float4*)(x + (size_t)row * D_MODEL + t * 4);
    float s = v.x + v.y + v.z + v.w;
    float s2 = v.x * v.x + v.y * v.y + v.z * v.z + v.w * v.w;
#pragma unroll
    for (int m = 1; m < 64; m <<= 1) { s += __shfl_xor(s, m); s2 += __shfl_xor(s2, m); }
    __shared__ float red[8];
    int wv = t >> 6;
    if ((t & 63) == 0) { red[wv] = s; red[4 + wv] = s2; }
    __syncthreads();
    s = red[0] + red[1] + red[2] + red[3];
    s2 = red[4] + red[5] + red[6] + red[7];
    float mu = s * (1.f / D_MODEL);
    float var = s2 * (1.f / D_MODEL) - mu * mu;
    float rs = rsqrtf(var + 1e-5f);
    float4 gg = *(const float4*)(g + t * 4);
    float4 bb = *(const float4*)(b + t * 4);
    ushort4 o;
    o.x = f2bf((v.x - mu) * rs * gg.x + bb.x);
    o.y = f2bf((v.y - mu) * rs * gg.y + bb.y);
    o.z = f2bf((v.z - mu) * rs * gg.z + bb.z);
    o.w = f2bf((v.w - mu) * rs * gg.w + bb.w);
    *(ushort4*)(out + (size_t)row * D_MODEL + t * 4) = o;
  } else {
    // ---- weight conversion chunk ----
    int j = (blk - MTOK) * 256 + threadIdx.x;  // float4 index over concatenated ranges
    const float* s;
    unsigned short* d;
    if (j < 786432) { s = s0; d = d0; }
    else if ((j -= 786432) < 262144) { s = s1; d = d1; }
    else if ((j -= 262144) < 524288) { s = s2; d = d2; }
    else { j -= 524288; s = s3; d = d3; }
    float4 v = ((const float4*)s)[j];
    ushort4 o;
    o.x = f2bf(v.x); o.y = f2bf(v.y); o.z = f2bf(v.z); o.w = f2bf(v.w);
    ((ushort4*)d)[j] = o;
  }
}

// ---------------- LayerNorm: bf16 in -> bf16 out ----------------
__global__ __launch_bounds__(256) void ln_fwd_b(const unsigned short* __restrict__ x,
                                                const float* __restrict__ g,
                                                const float* __restrict__ b,
                                                unsigned short* __restrict__ out) {
  const int row = blockIdx.x, t = threadIdx.x;
  ushort4 vi = *(const ushort4*)(x + (size_t)row * D_MODEL + t * 4);
  float f0 = bf2f(vi.x), f1 = bf2f(vi.y), f2 = bf2f(vi.z), f3 = bf2f(vi.w);
  float s = f0 + f1 + f2 + f3;
  float s2 = f0 * f0 + f1 * f1 + f2 * f2 + f3 * f3;
#pragma unroll
  for (int m = 1; m < 64; m <<= 1) { s += __shfl_xor(s, m); s2 += __shfl_xor(s2, m); }
  __shared__ float red[8];
  int wv = t >> 6;
  if ((t & 63) == 0) { red[wv] = s; red[4 + wv] = s2; }
  __syncthreads();
  s = red[0] + red[1] + red[2] + red[3];
  s2 = red[4] + red[5] + red[6] + red[7];
  float mu = s * (1.f / D_MODEL);
  float var = s2 * (1.f / D_MODEL) - mu * mu;
  float rs = rsqrtf(var + 1e-5f);
  float4 gg = *(const float4*)(g + t * 4);
  float4 bb = *(const float4*)(b + t * 4);
  ushort4 o;
  o.x = f2bf((f0 - mu) * rs * gg.x + bb.x);
  o.y = f2bf((f1 - mu) * rs * gg.y + bb.y);
  o.z = f2bf((f2 - mu) * rs * gg.z + bb.z);
  o.w = f2bf((f3 - mu) * rs * gg.w + bb.w);
  *(ushort4*)(out + (size_t)row * D_MODEL + t * 4) = o;
}

// ---------------- GEMM (m97 structure, proven): C[M,N] = A[M,K] * B[N,K]^T ----------------
// XCD-chunked block swizzle. EPI: 0 bf16, 1 fp32 R+acc, 2 bf16 relu(acc),
// 3 qkv-fused: per-head l2norm of q,k (q also x log2e/T); v written TRANSPOSED into VT
//   (vt[(b*16+h)*64 + d][tok]); 4 bf16 (R_f32+acc); 5 fp32 store of (R_bf16 + acc).
template <int EPI>
__global__ __launch_bounds__(256) void gemm_bt2(const unsigned short* __restrict__ A,
                                                const unsigned short* __restrict__ B,
                                                const float* __restrict__ R,
                                                const float* __restrict__ Tptr,
                                                unsigned short* __restrict__ VT,
                                                void* __restrict__ Cout, int M, int N, int K) {
  constexpr int BM = 128, BN = 128, BK = 32;
  __shared__ unsigned short lA[2][BM * BK], lB[2][BN * BK];
  const int tid = threadIdx.x, lane = tid & 63, wave = tid >> 6;
  const int lo = lane & 15, g = lane >> 4;
  const int nbx = gridDim.x;
  const int o = blockIdx.y * nbx + blockIdx.x;
  const int cpx = (nbx * gridDim.y) >> 3;
  const int w = (o & 7) * cpx + (o >> 3);
  const int bx = w % nbx, by = w / nbx;
  const int bm = by * BM, bn = bx * BN;
  const int wr = wave >> 1, wc = wave & 1;
  f32x4 acc[4][4] = {};
  const int c0 = wave * 128 + lane, c1 = c0 + 64;
  const unsigned short* gA0 = A + (size_t)(bm + (c0 >> 2)) * K + (c0 & 3) * 8;
  const unsigned short* gA1 = A + (size_t)(bm + (c1 >> 2)) * K + (c1 & 3) * 8;
  const unsigned short* gB0 = B + (size_t)(bn + (c0 >> 2)) * K + (c0 & 3) * 8;
  const unsigned short* gB1 = B + (size_t)(bn + (c1 >> 2)) * K + (c1 & 3) * 8;
  const int nk = K / BK;
  auto stage = [&](int buf, int kt) {
    const size_t ko = (size_t)kt * BK;
    gload16(gA0 + ko, &lA[buf][(wave * 128) * 8]);
    gload16(gA1 + ko, &lA[buf][(wave * 128 + 64) * 8]);
    gload16(gB0 + ko, &lB[buf][(wave * 128) * 8]);
    gload16(gB1 + ko, &lB[buf][(wave * 128 + 64) * 8]);
  };
  stage(0, 0);
  for (int kt = 0; kt < nk; ++kt) {
    __syncthreads();
    if (kt + 1 < nk) stage((kt + 1) & 1, kt + 1);
    const unsigned short* La = &lA[kt & 1][0];
    const unsigned short* Lb = &lB[kt & 1][0];
    short8 af[4], bfr[4];
#pragma unroll
    for (int m = 0; m < 4; ++m)
      af[m] = *(const short8*)(La + (wr * 64 + m * 16 + lo) * BK + g * 8);
#pragma unroll
    for (int n = 0; n < 4; ++n)
      bfr[n] = *(const short8*)(Lb + (wc * 64 + n * 16 + lo) * BK + g * 8);
#pragma unroll
    for (int m = 0; m < 4; ++m)
#pragma unroll
      for (int n = 0; n < 4; ++n) acc[m][n] = MFMA_BF16(af[m], bfr[n], acc[m][n]);
  }
  const int r0 = bm + wr * 64 + g * 4;
  const int c0c = bn + wc * 64 + lo;
  if (EPI == 3) {
    const int hb = bn + wc * 64;
    if (hb >= 2048) {
      // v-slice: write transposed directly into VT; tokens r0+m*16+0..3 contiguous, 4-aligned.
      const int h = (hb - 2048) >> 6;
      const int bq = r0 >> 11;  // batch index (constant over the whole block)
      unsigned short* vtp = VT + (size_t)((bq * 16 + h) * 64) * SEQ;
#pragma unroll
      for (int m = 0; m < 4; ++m) {
        const int tis = (r0 + m * 16) & 2047;  // token within sequence
#pragma unroll
        for (int n = 0; n < 4; ++n) {
          const int d = n * 16 + lo;  // head-dim 0..63
          unsigned lo32 = (unsigned)f2bf(acc[m][n][0]) | ((unsigned)f2bf(acc[m][n][1]) << 16);
          unsigned hi32 = (unsigned)f2bf(acc[m][n][2]) | ((unsigned)f2bf(acc[m][n][3]) << 16);
          unsigned* p = (unsigned*)(vtp + (size_t)d * SEQ + tis);
          p[0] = lo32;
          p[1] = hi32;
        }
      }
    } else {
      // q/k slice: per-head l2norm across the 16 lo-lanes; q also x log2e/T
      const bool isq = hb < 1024;
      const float qs = 1.44269504088896f / Tptr[0];
#pragma unroll
      for (int m = 0; m < 4; ++m)
#pragma unroll
        for (int r = 0; r < 4; ++r) {
          float ss = 0.f;
#pragma unroll
          for (int n = 0; n < 4; ++n) ss += acc[m][n][r] * acc[m][n][r];
          ss += __shfl_xor(ss, 1);
          ss += __shfl_xor(ss, 2);
          ss += __shfl_xor(ss, 4);
          ss += __shfl_xor(ss, 8);  // full head-dim sum across the 16 lo-lanes
          float sc = 1.0f / fmaxf(sqrtf(ss), 1e-12f);
          if (isq) sc *= qs;
#pragma unroll
          for (int n = 0; n < 4; ++n) {
            size_t off = (size_t)(r0 + m * 16 + r) * N + (c0c + n * 16);
            ((unsigned short*)Cout)[off] = f2bf(acc[m][n][r] * sc);
          }
        }
    }
  } else {
#pragma unroll
    for (int m = 0; m < 4; ++m)
#pragma unroll
      for (int n = 0; n < 4; ++n) {
#pragma unroll
        for (int r = 0; r < 4; ++r) {
          size_t off = (size_t)(r0 + m * 16 + r) * N + (c0c + n * 16);
          float v = acc[m][n][r];
          if (EPI == 0) ((unsigned short*)Cout)[off] = f2bf(v);
          else if (EPI == 1) ((float*)Cout)[off] = R[off] + v;
          else if (EPI == 2) ((unsigned short*)Cout)[off] = f2bf(fmaxf(v, 0.f));
          else if (EPI == 4) ((unsigned short*)Cout)[off] = f2bf(R[off] + v);
          else /* EPI == 5 */ ((float*)Cout)[off] = bf2f(((const unsigned short*)R)[off]) + v;
        }
      }
  }
}

// ---------------- flash attention v12: 32x32 MFMA, in-register P, gload_lds K/V staging ----------------
// Swapped mfma(K,Q): lane holds S[k][q=lane&31]. Static-max via C-init=-M0 (cosine bound).
// P -> bf16 (cvt_pk) -> permlane32_swap builds PV B-frags in registers (no P LDS).
// exp2 via raw v_exp_f32; K/V staged by global_load_lds (linear wave-uniform LDS dest +
// inverse-swizzled per-lane global source).
__global__ __launch_bounds__(256) void attn_fwd12(const unsigned short* __restrict__ qkv,
                                                  const unsigned short* __restrict__ vt,
                                                  unsigned short* __restrict__ out,
                                                  const float* __restrict__ temp) {
  __shared__ unsigned short lK[2][64 * 64];
  __shared__ unsigned short lV[2][64 * 64];
  const int blk = blockIdx.x;
  const int bh = blk & 63, qt = blk >> 6;
  const int b = bh >> 4, h = bh & 15;
  const int tid = threadIdx.x, lane = tid & 63, wave = tid >> 6;
  const int l5 = lane >> 5, l31 = lane & 31;
  const int qr0 = qt * 128 + wave * 32;
  const float M0 = 1.05f * 1.44269504088896f / temp[0];  // bound on folded scores
  f32x16 minit;
#pragma unroll
  for (int r = 0; r < 16; ++r) minit[r] = -M0;
  const unsigned short* qrow = qkv + (size_t)(b * SEQ + qr0 + l31) * 3072 + h * 64 + l5 * 8;
  short8 qf[4];
#pragma unroll
  for (int t = 0; t < 4; ++t) qf[t] = *(const short8*)(qrow + t * 16);
  // gload_lds staging: lane l of wave w covers row w*8 + (l>>3) (and +32), LDS linear;
  // global source column inverse-swizzled so LDS[row][c] = G[row][c ^ (row&7)].
  const int srow = tid >> 3;
  const int sslot = (tid & 7) ^ ((tid >> 3) & 7);
  const unsigned short* gK = qkv + (size_t)(b * SEQ + srow) * 3072 + 1024 + h * 64 + sslot * 8;
  const unsigned short* gV = vt + ((size_t)(bh * 64) + srow) * SEQ + sslot * 8;
  unsigned short* dK0 = &lK[0][0] + (wave * 8) * 64;   // wave-uniform dests (buf 0)
  unsigned short* dK1 = &lK[1][0] + (wave * 8) * 64;
  unsigned short* dV0 = &lV[0][0] + (wave * 8) * 64;
  unsigned short* dV1 = &lV[1][0] + (wave * 8) * 64;
  auto stageKV = [&](int buf, int t) {
    const size_t kof = (size_t)t * 64 * 3072;
    const size_t vof = (size_t)t * 64;
    unsigned short* dk = buf ? dK1 : dK0;
    unsigned short* dv = buf ? dV1 : dV0;
    gload16(gK + kof, dk);
    gload16(gK + kof + (size_t)32 * 3072, dk + 32 * 64);
    gload16(gV + vof, dv);
    gload16(gV + vof + (size_t)32 * SEQ, dv + 32 * 64);
  };
  stageKV(0, 0);
  f32x16 o0 = {}, o1 = {};
  float lsum = 0.f;
  constexpr int NT = SEQ / 64;
  for (int t = 0; t < NT; ++t) {
    __syncthreads();  // drains vmcnt: tile t landed; prior reads of the other buffer done
    if (t + 1 < NT) stageKV((t + 1) & 1, t + 1);  // flies under this iteration's compute
    const unsigned short* Kb = &lK[t & 1][0];
    const unsigned short* Vb = &lV[t & 1][0];
#pragma unroll
    for (int tile = 0; tile < 2; ++tile) {
      f32x16 s = minit;
      __builtin_amdgcn_s_setprio(1);
#pragma unroll
      for (int td = 0; td < 4; ++td) {
        const int row = tile * 32 + l31;
        const int sl = ((2 * td + l5) ^ (row & 7)) * 8;
        short8 kf = *(const short8*)(Kb + row * 64 + sl);
        s = MFMA32(kf, qf[td], s);
      }
      __builtin_amdgcn_s_setprio(0);
      float p[16];
#pragma unroll
      for (int r = 0; r < 16; ++r) p[r] = exp2_fast(s[r]);
      float q01 = p[0] + p[1], q23 = p[2] + p[3], q45 = p[4] + p[5], q67 = p[6] + p[7];
      float q89 = p[8] + p[9], qab = p[10] + p[11], qcd = p[12] + p[13], qef = p[14] + p[15];
      lsum += ((q01 + q23) + (q45 + q67)) + ((q89 + qab) + (qcd + qef));
      unsigned a0 = cvt_pk_bf16(p[0], p[1]), a1 = cvt_pk_bf16(p[2], p[3]);
      unsigned a2 = cvt_pk_bf16(p[4], p[5]), a3 = cvt_pk_bf16(p[6], p[7]);
      unsigned c0 = cvt_pk_bf16(p[8], p[9]), c1 = cvt_pk_bf16(p[10], p[11]);
      unsigned c2 = cvt_pk_bf16(p[12], p[13]), c3 = cvt_pk_bf16(p[14], p[15]);
      uint2v w0 = __builtin_amdgcn_permlane32_swap(a0, a2, false, false);
      uint2v w1 = __builtin_amdgcn_permlane32_swap(a1, a3, false, false);
      uint2v w2 = __builtin_amdgcn_permlane32_swap(c0, c2, false, false);
      uint2v w3 = __builtin_amdgcn_permlane32_swap(c1, c3, false, false);
      union { unsigned u[4]; short8 v; } f0, f1;
      f0.u[0] = w0.x; f0.u[1] = w1.x; f0.u[2] = w0.y; f0.u[3] = w1.y;
      f1.u[0] = w2.x; f1.u[1] = w3.x; f1.u[2] = w2.y; f1.u[3] = w3.y;
      __builtin_amdgcn_s_setprio(1);
      {
        const int vrow0 = l31, vrow1 = 32 + l31;
        const int sa = ((2 * (tile * 2) + l5) ^ (vrow0 & 7)) * 8;
        const int sb = ((2 * (tile * 2 + 1) + l5) ^ (vrow0 & 7)) * 8;
        short8 va0 = *(const short8*)(Vb + vrow0 * 64 + sa);
        short8 vb0 = *(const short8*)(Vb + vrow0 * 64 + sb);
        short8 va1 = *(const short8*)(Vb + vrow1 * 64 + sa);
        short8 vb1 = *(const short8*)(Vb + vrow1 * 64 + sb);
        o0 = MFMA32(va0, f0.v, o0);
        o0 = MFMA32(vb0, f1.v, o0);
        o1 = MFMA32(va1, f0.v, o1);
        o1 = MFMA32(vb1, f1.v, o1);
      }
      __builtin_amdgcn_s_setprio(0);
    }
  }
  lsum += __shfl_xor(lsum, 32);
  const float rinv = 1.0f / lsum;
  unsigned short* orow = out + (size_t)(b * SEQ + qr0 + l31) * D_MODEL + h * 64 + l5 * 4;
#pragma unroll
  for (int rq = 0; rq < 4; ++rq)
#pragma unroll
    for (int rr = 0; rr < 4; rr += 2) {
      *(unsigned*)(orow + rq * 8 + rr) =
          cvt_pk_bf16(o0[rq * 4 + rr] * rinv, o0[rq * 4 + rr + 1] * rinv);
      *(unsigned*)(orow + 32 + rq * 8 + rr) =
          cvt_pk_bf16(o1[rq * 4 + rr] * rinv, o1[rq * 4 + rr + 1] * rinv);
    }
}

// ---------------- host launch ----------------
extern "C" void kernel_launch(void* const* d_in, const int* in_sizes, int n_in, void* d_out,
                              int out_size, void* d_ws, size_t ws_size, hipStream_t stream) {
  const float* x = (const float*)d_in[0];
  const float* w_qkv = (const float*)d_in[1];
  const float* w_out = (const float*)d_in[2];
  const float* w_ffn1 = (const float*)d_in[3];
  const float* w_ffn2 = (const float*)d_in[4];
  const float* g1 = (const float*)d_in[5];
  const float* b1 = (const float*)d_in[6];
  const float* g2 = (const float*)d_in[7];
  const float* b2 = (const float*)d_in[8];
  const float* temp = (const float*)d_in[9];
  float* outp = (float*)d_out;

  char* ws = (char*)d_ws;
  size_t off = 0;
  auto alloc = [&](size_t bytes) {
    void* p = ws + off;
    off += (bytes + 255) & ~(size_t)255;
    return p;
  };
  unsigned short* wqkv_bf = (unsigned short*)alloc((size_t)3072 * 1024 * 2);
  unsigned short* wout_bf = (unsigned short*)alloc((size_t)1024 * 1024 * 2);
  unsigned short* wf1_bf = (unsigned short*)alloc((size_t)2048 * 1024 * 2);
  unsigned short* wf2_bf = (unsigned short*)alloc((size_t)1024 * 2048 * 2);
  unsigned short* h_bf = (unsigned short*)alloc((size_t)MTOK * 1024 * 2);   // reused for h2
  unsigned short* qkv_bf = (unsigned short*)alloc((size_t)MTOK * 3072 * 2); // reused for ffn1 out
  unsigned short* vt_bf = (unsigned short*)alloc((size_t)BATCH * NHEADS * DHEAD * SEQ * 2);
  unsigned short* ao_bf = (unsigned short*)alloc((size_t)MTOK * 1024 * 2);
  unsigned short* x2_bf = (unsigned short*)alloc((size_t)MTOK * 1024 * 2);  // bf16 residual

  // LN1 + all weight conversions in one launch (independent memory streams)
  prep0<<<MTOK + 8192, 256, 0, stream>>>(x, g1, b1, h_bf, w_qkv, w_out, w_ffn1, w_ffn2, wqkv_bf,
                                         wout_bf, wf1_bf, wf2_bf);
  // qkv = h @ w_qkv^T; q,k l2-normalized in-epilogue; v written transposed into vt directly
  gemm_bt2<3><<<dim3(3072 / 128, MTOK / 128), 256, 0, stream>>>(h_bf, wqkv_bf, nullptr, temp,
                                                                vt_bf, (void*)qkv_bf, MTOK, 3072,
                                                                1024);
  // attention (32x32 MFMA, in-register P, gload_lds staging, XCD-local mapping)
  attn_fwd12<<<BATCH * NHEADS * (SEQ / 128), 256, 0, stream>>>(qkv_bf, vt_bf, ao_bf, temp);
  // x2 = x + attn_out @ w_out^T  (stored bf16)
  gemm_bt2<4><<<dim3(1024 / 128, MTOK / 128), 256, 0, stream>>>(ao_bf, wout_bf, x, nullptr,
                                                                nullptr, (void*)x2_bf, MTOK, 1024,
                                                                1024);
  // LN2 (bf16 input)
  ln_fwd_b<<<MTOK, 256, 0, stream>>>(x2_bf, g2, b2, h_bf);
  // ffn1 = relu(h2 @ w_ffn1^T)  (reuse qkv buffer)
  gemm_bt2<2><<<dim3(2048 / 128, MTOK / 128), 256, 0, stream>>>(h_bf, wf1_bf, nullptr, nullptr,
                                                                nullptr, (void*)qkv_bf, MTOK, 2048,
                                                                1024);
  // out = x2 + ffn1 @ w_ffn2^T  (bf16 residual read, fp32 out)
  gemm_bt2<5><<<dim3(1024 / 128, MTOK / 128), 256, 0, stream>>>(qkv_bf, wf2_bf,
                                                                (const float*)x2_bf, nullptr,
                                                                nullptr, (void*)outp, MTOK, 1024,
                                                                2048);
}